// Round 1
// baseline (4533.052 us; speedup 1.0000x reference)
//
#include <hip/hip_runtime.h>
#include <math.h>

#define N_NODES 20000
#define SEQ_T   24
#define EMBD    64
#define HL      128     // H_LSTM
#define OUTF    16
#define NEDGE   640000
#define G4      512     // 4*HL
#define KTOT    192     // EMBD + HL

__device__ __forceinline__ float4 ld4(const float* p){ return *reinterpret_cast<const float4*>(p); }
__device__ __forceinline__ void st4(float* p, float4 v){ *reinterpret_cast<float4*>(p) = v; }
__device__ __forceinline__ float sigm(float x){ return 1.0f/(1.0f + expf(-x)); }

#define FMA4(A,S,B) {(A).x=fmaf((S),(B).x,(A).x);(A).y=fmaf((S),(B).y,(A).y);(A).z=fmaf((S),(B).z,(A).z);(A).w=fmaf((S),(B).w,(A).w);}

// WT[k][g]: k in [0,192): 0..63 = W_ih^T, 64..191 = W_hh^T. WT row-major [192][512].
__global__ __launch_bounds__(256) void build_wt(const float* __restrict__ Wih,
                                                const float* __restrict__ Whh,
                                                float* __restrict__ WT)
{
    int idx = blockIdx.x*256 + threadIdx.x;
    if (idx >= KTOT*G4) return;
    int kk = idx >> 9;          // /512
    int g  = idx & 511;
    WT[idx] = (kk < EMBD) ? Wih[g*EMBD + kk] : Whh[g*HL + (kk - EMBD)];
}

// One LSTM time step, fused embedding-gather + input-proj + recurrent GEMM + gates.
// Block: 32 rows (nodes) x 512 gate-cols. 256 threads; thread = 4 rows x (4 j x 4 gates).
__global__ __launch_bounds__(256) void lstm_step(
    const int* __restrict__ tokens, const int* __restrict__ lengths,
    const float* __restrict__ emb, const float* __restrict__ WT,
    const float* __restrict__ b_ih, const float* __restrict__ b_hh,
    const float* __restrict__ h_in, float* __restrict__ c_st,
    float* __restrict__ h_out, float* __restrict__ h_last, int t)
{
    __shared__ float a_lds[32][KTOT];   // [row][k]  (reads are wave-broadcast)
    __shared__ float b_lds[16][G4];     // [kk][g]
    const int tid = threadIdx.x;
    const int n0 = blockIdx.x * 32;

    // A tile: emb part (k = 0..63)
    #pragma unroll
    for (int i = 0; i < 2; ++i) {
        int f = tid + 256*i;            // 0..511 float4 slots
        int row = f >> 4, part = f & 15;
        int tok = tokens[(n0 + row)*SEQ_T + t];
        float4 v = ld4(emb + (size_t)tok*EMBD + part*4);
        st4(&a_lds[row][part*4], v);
    }
    // A tile: h part (k = 64..191)
    #pragma unroll
    for (int i = 0; i < 4; ++i) {
        int f = tid + 256*i;            // 0..1023 float4 slots
        int row = f >> 5, part = f & 31;
        float4 v = ld4(h_in + (size_t)(n0 + row)*HL + part*4);
        st4(&a_lds[row][EMBD + part*4], v);
    }

    const int jg = tid & 31, rg = tid >> 5;
    const int j0 = jg*4, r0 = rg*4;
    float4 acc[4][4];
    #pragma unroll
    for (int r = 0; r < 4; ++r)
        #pragma unroll
        for (int g = 0; g < 4; ++g)
            acc[r][g] = make_float4(0.f, 0.f, 0.f, 0.f);

    for (int kt = 0; kt < 12; ++kt) {
        __syncthreads();
        #pragma unroll
        for (int i = 0; i < 8; ++i) {
            int f = tid + 256*i;        // 0..2047 float4 slots
            int kk = f >> 7, c4 = f & 127;
            st4(&b_lds[kk][c4*4], ld4(WT + (size_t)(kt*16 + kk)*G4 + c4*4));
        }
        __syncthreads();
        #pragma unroll
        for (int kk = 0; kk < 16; ++kk) {
            float a0 = a_lds[r0+0][kt*16+kk];
            float a1 = a_lds[r0+1][kt*16+kk];
            float a2 = a_lds[r0+2][kt*16+kk];
            float a3 = a_lds[r0+3][kt*16+kk];
            #pragma unroll
            for (int g = 0; g < 4; ++g) {
                float4 b = ld4(&b_lds[kk][g*HL + j0]);
                FMA4(acc[0][g], a0, b);
                FMA4(acc[1][g], a1, b);
                FMA4(acc[2][g], a2, b);
                FMA4(acc[3][g], a3, b);
            }
        }
    }

    float4 bias[4];
    #pragma unroll
    for (int g = 0; g < 4; ++g) {
        float4 bi = ld4(b_ih + g*HL + j0);
        float4 bh = ld4(b_hh + g*HL + j0);
        bias[g] = make_float4(bi.x+bh.x, bi.y+bh.y, bi.z+bh.z, bi.w+bh.w);
    }

    #pragma unroll
    for (int r = 0; r < 4; ++r) {
        int n = n0 + r0 + r;
        int len = lengths[n];
        float4 cold = ld4(c_st + (size_t)n*HL + j0);
        float4 z0 = acc[r][0], z1 = acc[r][1], z2 = acc[r][2], z3 = acc[r][3];
        z0.x += bias[0].x; z0.y += bias[0].y; z0.z += bias[0].z; z0.w += bias[0].w;
        z1.x += bias[1].x; z1.y += bias[1].y; z1.z += bias[1].z; z1.w += bias[1].w;
        z2.x += bias[2].x; z2.y += bias[2].y; z2.z += bias[2].z; z2.w += bias[2].w;
        z3.x += bias[3].x; z3.y += bias[3].y; z3.z += bias[3].z; z3.w += bias[3].w;
        float4 cnew, hnew;
        cnew.x = sigm(z1.x)*cold.x + sigm(z0.x)*tanhf(z2.x);
        cnew.y = sigm(z1.y)*cold.y + sigm(z0.y)*tanhf(z2.y);
        cnew.z = sigm(z1.z)*cold.z + sigm(z0.z)*tanhf(z2.z);
        cnew.w = sigm(z1.w)*cold.w + sigm(z0.w)*tanhf(z2.w);
        hnew.x = sigm(z3.x)*tanhf(cnew.x);
        hnew.y = sigm(z3.y)*tanhf(cnew.y);
        hnew.z = sigm(z3.z)*tanhf(cnew.z);
        hnew.w = sigm(z3.w)*tanhf(cnew.w);
        st4(c_st  + (size_t)n*HL + j0, cnew);
        st4(h_out + (size_t)n*HL + j0, hnew);
        if (t == len - 1) st4(h_last + (size_t)n*HL + j0, hnew);
    }
}

__global__ __launch_bounds__(256) void deg_kernel(const int* __restrict__ dst,
                                                  const float* __restrict__ w,
                                                  float* __restrict__ deg, int E)
{
    int e = blockIdx.x*256 + threadIdx.x;
    if (e < E) atomicAdd(&deg[dst[e]], w[e]);
}

__global__ __launch_bounds__(256) void dinv_kernel(const float* __restrict__ deg,
                                                   float* __restrict__ dinv, int N)
{
    int n = blockIdx.x*256 + threadIdx.x;
    if (n < N) dinv[n] = rsqrtf(deg[n] + 1.0f);
}

// y[N][128] = x[N][128] @ W[128][128]. Block: 64 rows, 256 threads, 8 rows x 4 cols each.
__global__ __launch_bounds__(256) void gemm_nk128(const float* __restrict__ x,
                                                  const float* __restrict__ W,
                                                  float* __restrict__ y, int N)
{
    __shared__ float xs[64][HL];
    const int tid = threadIdx.x;
    const int n0 = blockIdx.x * 64;
    #pragma unroll
    for (int i = 0; i < 8; ++i) {
        int f = tid + 256*i;            // 0..2047 float4 slots
        int row = f >> 5, part = f & 31;
        int n = n0 + row;
        float4 v = make_float4(0.f,0.f,0.f,0.f);
        if (n < N) v = ld4(x + (size_t)n*HL + part*4);
        st4(&xs[row][part*4], v);
    }
    __syncthreads();
    const int jg = tid & 31, rg = tid >> 5;
    const int j0 = jg*4;
    float4 acc[8];
    #pragma unroll
    for (int i = 0; i < 8; ++i) acc[i] = make_float4(0.f,0.f,0.f,0.f);
    #pragma unroll 4
    for (int k = 0; k < HL; ++k) {
        float4 wv = ld4(W + (size_t)k*HL + j0);
        #pragma unroll
        for (int i = 0; i < 8; ++i) {
            float xv = xs[rg + 8*i][k];
            FMA4(acc[i], xv, wv);
        }
    }
    #pragma unroll
    for (int i = 0; i < 8; ++i) {
        int n = n0 + rg + 8*i;
        if (n < N) st4(y + (size_t)n*HL + j0, acc[i]);
    }
}

// agg[n] = y[n] * dinv[n]^2  (self-loop term; also initializes agg)
__global__ __launch_bounds__(256) void selfinit_kernel(const float* __restrict__ y,
                                                       const float* __restrict__ dinv,
                                                       float* __restrict__ agg, int N)
{
    int idx = blockIdx.x*256 + threadIdx.x;   // N*32 threads
    int n = idx >> 5, q = idx & 31;
    if (n >= N) return;
    float di = dinv[n];
    float s = di*di;
    float4 v = ld4(y + (size_t)n*HL + q*4);
    v.x *= s; v.y *= s; v.z *= s; v.w *= s;
    st4(agg + (size_t)n*HL + q*4, v);
}

// agg[dst] += y[src] * (dinv[src]*w*dinv[dst]); 32 lanes per edge, 4 floats/lane.
__global__ __launch_bounds__(256) void scatter_kernel(const int* __restrict__ src,
                                                      const int* __restrict__ dst,
                                                      const float* __restrict__ w,
                                                      const float* __restrict__ dinv,
                                                      const float* __restrict__ y,
                                                      float* __restrict__ agg, int E)
{
    int gt = blockIdx.x*256 + threadIdx.x;
    int e = gt >> 5, lane = gt & 31;
    if (e >= E) return;
    int s = src[e], d = dst[e];
    float norm = dinv[s]*w[e]*dinv[d];
    float4 v = ld4(y + (size_t)s*HL + lane*4);
    float* ap = agg + (size_t)d*HL + lane*4;
    atomicAdd(ap+0, v.x*norm);
    atomicAdd(ap+1, v.y*norm);
    atomicAdd(ap+2, v.z*norm);
    atomicAdd(ap+3, v.w*norm);
}

__global__ __launch_bounds__(256) void bias_relu_kernel(const float* __restrict__ agg,
                                                        const float* __restrict__ b,
                                                        float* __restrict__ out, int N)
{
    int idx = blockIdx.x*256 + threadIdx.x;   // N*32 threads
    int n = idx >> 5, q = idx & 31;
    if (n >= N) return;
    float4 a = ld4(agg + (size_t)n*HL + q*4);
    float4 bb = ld4(b + q*4);
    a.x = fmaxf(a.x + bb.x, 0.f);
    a.y = fmaxf(a.y + bb.y, 0.f);
    a.z = fmaxf(a.z + bb.z, 0.f);
    a.w = fmaxf(a.w + bb.w, 0.f);
    st4(out + (size_t)n*HL + q*4, a);
}

// out[N][16] = x[N][128] @ W[128][16] + b. Block: 64 rows, thread = 4 rows x 1 col.
__global__ __launch_bounds__(256) void fc_kernel(const float* __restrict__ x,
                                                 const float* __restrict__ W,
                                                 const float* __restrict__ b,
                                                 float* __restrict__ out, int N)
{
    __shared__ float xs[64][HL];
    const int tid = threadIdx.x;
    const int n0 = blockIdx.x * 64;
    #pragma unroll
    for (int i = 0; i < 8; ++i) {
        int f = tid + 256*i;
        int row = f >> 5, part = f & 31;
        int n = n0 + row;
        float4 v = make_float4(0.f,0.f,0.f,0.f);
        if (n < N) v = ld4(x + (size_t)n*HL + part*4);
        st4(&xs[row][part*4], v);
    }
    __syncthreads();
    const int o = tid & 15, rg = tid >> 4;   // rg in 0..15
    float acc[4] = {0.f,0.f,0.f,0.f};
    #pragma unroll 4
    for (int k = 0; k < HL; ++k) {
        float wv = W[k*OUTF + o];
        #pragma unroll
        for (int i = 0; i < 4; ++i)
            acc[i] = fmaf(xs[rg + 16*i][k], wv, acc[i]);
    }
    float bb = b[o];
    #pragma unroll
    for (int i = 0; i < 4; ++i) {
        int n = n0 + rg + 16*i;
        if (n < N) out[(size_t)n*OUTF + o] = acc[i] + bb;
    }
}

extern "C" void kernel_launch(void* const* d_in, const int* in_sizes, int n_in,
                              void* d_out, int out_size, void* d_ws, size_t ws_size,
                              hipStream_t stream)
{
    const int*   x_tokens = (const int*)d_in[0];
    const int*   lengths  = (const int*)d_in[1];
    const int*   eidx     = (const int*)d_in[2];
    const float* ew       = (const float*)d_in[3];
    const float* emb      = (const float*)d_in[4];
    const float* W_ih     = (const float*)d_in[5];
    const float* W_hh     = (const float*)d_in[6];
    const float* b_ih     = (const float*)d_in[7];
    const float* b_hh     = (const float*)d_in[8];
    const float* c1W      = (const float*)d_in[9];
    const float* c1b      = (const float*)d_in[10];
    const float* c2W      = (const float*)d_in[11];
    const float* c2b      = (const float*)d_in[12];
    const float* fcW      = (const float*)d_in[13];
    const float* fcb      = (const float*)d_in[14];
    float* out = (float*)d_out;

    const int* esrc = eidx;
    const int* edst = eidx + NEDGE;

    char* ws = (char*)d_ws;
    size_t off = 0;
    auto take = [&](size_t bytes) -> char* {
        char* p = ws + off;
        off = (off + bytes + 255) & ~(size_t)255;
        return p;
    };
    const size_t NH = (size_t)N_NODES * HL * sizeof(float);
    float* WT    = (float*)take((size_t)KTOT * G4 * sizeof(float));
    float* hA    = (float*)take(NH);
    float* hB    = (float*)take(NH);
    float* cS    = (float*)take(NH);
    float* hLst  = (float*)take(NH);
    float* degb  = (float*)take((size_t)N_NODES * sizeof(float));
    float* dinvb = (float*)take((size_t)N_NODES * sizeof(float));
    float* yb    = (float*)take(NH);
    float* aggb  = (float*)take(NH);
    float* x2    = (float*)take(NH);
    float* x3    = (float*)take(NH);

    hipMemsetAsync(hA,   0, NH, stream);
    hipMemsetAsync(cS,   0, NH, stream);
    hipMemsetAsync(degb, 0, (size_t)N_NODES * sizeof(float), stream);

    build_wt<<<(KTOT*G4 + 255)/256, 256, 0, stream>>>(W_ih, W_hh, WT);

    for (int t = 0; t < SEQ_T; ++t) {
        const float* hin = (t & 1) ? hB : hA;
        float*       hout = (t & 1) ? hA : hB;
        lstm_step<<<N_NODES/32, 256, 0, stream>>>(x_tokens, lengths, emb, WT,
                                                  b_ih, b_hh, hin, cS, hout, hLst, t);
    }

    deg_kernel<<<NEDGE/256, 256, 0, stream>>>(edst, ew, degb, NEDGE);
    dinv_kernel<<<(N_NODES + 255)/256, 256, 0, stream>>>(degb, dinvb, N_NODES);

    const int gemmBlocks = (N_NODES + 63)/64;
    const int nk32Blocks = (N_NODES*32)/256;
    const int scatBlocks = (NEDGE*32)/256;

    // conv1
    gemm_nk128<<<gemmBlocks, 256, 0, stream>>>(hLst, c1W, yb, N_NODES);
    selfinit_kernel<<<nk32Blocks, 256, 0, stream>>>(yb, dinvb, aggb, N_NODES);
    scatter_kernel<<<scatBlocks, 256, 0, stream>>>(esrc, edst, ew, dinvb, yb, aggb, NEDGE);
    bias_relu_kernel<<<nk32Blocks, 256, 0, stream>>>(aggb, c1b, x2, N_NODES);
    // conv2
    gemm_nk128<<<gemmBlocks, 256, 0, stream>>>(x2, c2W, yb, N_NODES);
    selfinit_kernel<<<nk32Blocks, 256, 0, stream>>>(yb, dinvb, aggb, N_NODES);
    scatter_kernel<<<scatBlocks, 256, 0, stream>>>(esrc, edst, ew, dinvb, yb, aggb, NEDGE);
    bias_relu_kernel<<<nk32Blocks, 256, 0, stream>>>(aggb, c2b, x3, N_NODES);
    // fc
    fc_kernel<<<gemmBlocks, 256, 0, stream>>>(x3, fcW, fcb, out, N_NODES);
}

// Round 2
// 2480.897 us; speedup vs baseline: 1.8272x; 1.8272x over previous
//
#include <hip/hip_runtime.h>
#include <math.h>

#define N_NODES 20000
#define SEQ_T   24
#define EMBD    64
#define HL      128     // H_LSTM
#define OUTF    16
#define NEDGE   640000
#define G4      512     // 4*HL
#define KTOT    192     // EMBD + HL

__device__ __forceinline__ float4 ld4(const float* p){ return *reinterpret_cast<const float4*>(p); }
__device__ __forceinline__ void st4(float* p, float4 v){ *reinterpret_cast<float4*>(p) = v; }
__device__ __forceinline__ float2 ld2(const float* p){ return *reinterpret_cast<const float2*>(p); }
__device__ __forceinline__ float sigm(float x){ return 1.0f/(1.0f + expf(-x)); }

#define FMA4(A,S,B) {(A).x=fmaf((S),(B).x,(A).x);(A).y=fmaf((S),(B).y,(A).y);(A).z=fmaf((S),(B).z,(A).z);(A).w=fmaf((S),(B).w,(A).w);}

// WT[k][g]: k in [0,192): 0..63 = W_ih^T, 64..191 = W_hh^T. WT row-major [192][512].
__global__ __launch_bounds__(256) void build_wt(const float* __restrict__ Wih,
                                                const float* __restrict__ Whh,
                                                float* __restrict__ WT)
{
    int idx = blockIdx.x*256 + threadIdx.x;
    if (idx >= KTOT*G4) return;
    int kk = idx >> 9;          // /512
    int g  = idx & 511;
    WT[idx] = (kk < EMBD) ? Wih[g*EMBD + kk] : Whh[g*HL + (kk - EMBD)];
}

// One LSTM time step, fused embedding-gather + input-proj + recurrent GEMM + gates.
__global__ __launch_bounds__(256) void lstm_step(
    const int* __restrict__ tokens, const int* __restrict__ lengths,
    const float* __restrict__ emb, const float* __restrict__ WT,
    const float* __restrict__ b_ih, const float* __restrict__ b_hh,
    const float* __restrict__ h_in, float* __restrict__ c_st,
    float* __restrict__ h_out, float* __restrict__ h_last, int t)
{
    __shared__ float a_lds[32][KTOT];   // [row][k]
    __shared__ float b_lds[16][G4];     // [kk][g]
    const int tid = threadIdx.x;
    const int n0 = blockIdx.x * 32;

    #pragma unroll
    for (int i = 0; i < 2; ++i) {
        int f = tid + 256*i;
        int row = f >> 4, part = f & 15;
        int tok = tokens[(n0 + row)*SEQ_T + t];
        float4 v = ld4(emb + (size_t)tok*EMBD + part*4);
        st4(&a_lds[row][part*4], v);
    }
    #pragma unroll
    for (int i = 0; i < 4; ++i) {
        int f = tid + 256*i;
        int row = f >> 5, part = f & 31;
        float4 v = ld4(h_in + (size_t)(n0 + row)*HL + part*4);
        st4(&a_lds[row][EMBD + part*4], v);
    }

    const int jg = tid & 31, rg = tid >> 5;
    const int j0 = jg*4, r0 = rg*4;
    float4 acc[4][4];
    #pragma unroll
    for (int r = 0; r < 4; ++r)
        #pragma unroll
        for (int g = 0; g < 4; ++g)
            acc[r][g] = make_float4(0.f, 0.f, 0.f, 0.f);

    for (int kt = 0; kt < 12; ++kt) {
        __syncthreads();
        #pragma unroll
        for (int i = 0; i < 8; ++i) {
            int f = tid + 256*i;
            int kk = f >> 7, c4 = f & 127;
            st4(&b_lds[kk][c4*4], ld4(WT + (size_t)(kt*16 + kk)*G4 + c4*4));
        }
        __syncthreads();
        #pragma unroll
        for (int kk = 0; kk < 16; ++kk) {
            float a0 = a_lds[r0+0][kt*16+kk];
            float a1 = a_lds[r0+1][kt*16+kk];
            float a2 = a_lds[r0+2][kt*16+kk];
            float a3 = a_lds[r0+3][kt*16+kk];
            #pragma unroll
            for (int g = 0; g < 4; ++g) {
                float4 b = ld4(&b_lds[kk][g*HL + j0]);
                FMA4(acc[0][g], a0, b);
                FMA4(acc[1][g], a1, b);
                FMA4(acc[2][g], a2, b);
                FMA4(acc[3][g], a3, b);
            }
        }
    }

    float4 bias[4];
    #pragma unroll
    for (int g = 0; g < 4; ++g) {
        float4 bi = ld4(b_ih + g*HL + j0);
        float4 bh = ld4(b_hh + g*HL + j0);
        bias[g] = make_float4(bi.x+bh.x, bi.y+bh.y, bi.z+bh.z, bi.w+bh.w);
    }

    #pragma unroll
    for (int r = 0; r < 4; ++r) {
        int n = n0 + r0 + r;
        int len = lengths[n];
        float4 cold = ld4(c_st + (size_t)n*HL + j0);
        float4 z0 = acc[r][0], z1 = acc[r][1], z2 = acc[r][2], z3 = acc[r][3];
        z0.x += bias[0].x; z0.y += bias[0].y; z0.z += bias[0].z; z0.w += bias[0].w;
        z1.x += bias[1].x; z1.y += bias[1].y; z1.z += bias[1].z; z1.w += bias[1].w;
        z2.x += bias[2].x; z2.y += bias[2].y; z2.z += bias[2].z; z2.w += bias[2].w;
        z3.x += bias[3].x; z3.y += bias[3].y; z3.z += bias[3].z; z3.w += bias[3].w;
        float4 cnew, hnew;
        cnew.x = sigm(z1.x)*cold.x + sigm(z0.x)*tanhf(z2.x);
        cnew.y = sigm(z1.y)*cold.y + sigm(z0.y)*tanhf(z2.y);
        cnew.z = sigm(z1.z)*cold.z + sigm(z0.z)*tanhf(z2.z);
        cnew.w = sigm(z1.w)*cold.w + sigm(z0.w)*tanhf(z2.w);
        hnew.x = sigm(z3.x)*tanhf(cnew.x);
        hnew.y = sigm(z3.y)*tanhf(cnew.y);
        hnew.z = sigm(z3.z)*tanhf(cnew.z);
        hnew.w = sigm(z3.w)*tanhf(cnew.w);
        st4(c_st  + (size_t)n*HL + j0, cnew);
        st4(h_out + (size_t)n*HL + j0, hnew);
        if (t == len - 1) st4(h_last + (size_t)n*HL + j0, hnew);
    }
}

// CSR pass 1: per-dst edge count + weighted degree.
__global__ __launch_bounds__(256) void count_deg(const int* __restrict__ dst,
                                                 const float* __restrict__ w,
                                                 int* __restrict__ cnt,
                                                 float* __restrict__ deg, int E)
{
    int e = blockIdx.x*256 + threadIdx.x;
    if (e < E) {
        int d = dst[e];
        atomicAdd(&cnt[d], 1);
        atomicAdd(&deg[d], w[e]);
    }
}

__global__ __launch_bounds__(256) void dinv_kernel(const float* __restrict__ deg,
                                                   float* __restrict__ dinv, int N)
{
    int n = blockIdx.x*256 + threadIdx.x;
    if (n < N) dinv[n] = rsqrtf(deg[n] + 1.0f);
}

// Single-block exclusive prefix sum over cnt[0..N), writes row_start[0..N].
__global__ __launch_bounds__(1024) void scan_kernel(const int* __restrict__ cnt,
                                                    int* __restrict__ row_start)
{
    __shared__ int part[1024];
    const int t = threadIdx.x;
    const int CH = (N_NODES + 1023) / 1024;   // 20
    int beg = t*CH, end = min(beg + CH, N_NODES);
    int s = 0;
    for (int i = beg; i < end; ++i) s += cnt[i];
    part[t] = s;
    __syncthreads();
    for (int off = 1; off < 1024; off <<= 1) {
        int v = (t >= off) ? part[t - off] : 0;
        __syncthreads();
        part[t] += v;
        __syncthreads();
    }
    int base = (t == 0) ? 0 : part[t - 1];
    for (int i = beg; i < end; ++i) { row_start[i] = base; base += cnt[i]; }
    if (t == 1023) row_start[N_NODES] = part[1023];
}

// CSR fill: reordered src + precomputed norm per edge.
__global__ __launch_bounds__(256) void fill_csr(const int* __restrict__ src,
                                                const int* __restrict__ dst,
                                                const float* __restrict__ w,
                                                const float* __restrict__ dinv,
                                                const int* __restrict__ row_start,
                                                int* __restrict__ cursor,
                                                int* __restrict__ src_s,
                                                float* __restrict__ norm_s, int E)
{
    int e = blockIdx.x*256 + threadIdx.x;
    if (e >= E) return;
    int d = dst[e];
    int pos = row_start[d] + atomicAdd(&cursor[d], 1);
    int s = src[e];
    src_s[pos]  = s;
    norm_s[pos] = dinv[s] * w[e] * dinv[d];
}

// y[N][128] = x[N][128] @ W[128][128]. Block: 64 rows, 256 threads.
__global__ __launch_bounds__(256) void gemm_nk128(const float* __restrict__ x,
                                                  const float* __restrict__ W,
                                                  float* __restrict__ y, int N)
{
    __shared__ float xs[64][HL];
    const int tid = threadIdx.x;
    const int n0 = blockIdx.x * 64;
    #pragma unroll
    for (int i = 0; i < 8; ++i) {
        int f = tid + 256*i;
        int row = f >> 5, part = f & 31;
        int n = n0 + row;
        float4 v = make_float4(0.f,0.f,0.f,0.f);
        if (n < N) v = ld4(x + (size_t)n*HL + part*4);
        st4(&xs[row][part*4], v);
    }
    __syncthreads();
    const int jg = tid & 31, rg = tid >> 5;
    const int j0 = jg*4;
    float4 acc[8];
    #pragma unroll
    for (int i = 0; i < 8; ++i) acc[i] = make_float4(0.f,0.f,0.f,0.f);
    #pragma unroll 4
    for (int k = 0; k < HL; ++k) {
        float4 wv = ld4(W + (size_t)k*HL + j0);
        #pragma unroll
        for (int i = 0; i < 8; ++i) {
            float xv = xs[rg + 8*i][k];
            FMA4(acc[i], xv, wv);
        }
    }
    #pragma unroll
    for (int i = 0; i < 8; ++i) {
        int n = n0 + rg + 8*i;
        if (n < N) st4(y + (size_t)n*HL + j0, acc[i]);
    }
}

// Fused GCN aggregation: out[n] = relu( y[n]*dinv[n]^2 + sum_e norm*y[src] + b ).
// One wave (64 lanes) per node; lane handles 2 of 128 cols.
__global__ __launch_bounds__(256) void gcn_gather(const int* __restrict__ row_start,
                                                  const int* __restrict__ src_s,
                                                  const float* __restrict__ norm_s,
                                                  const float* __restrict__ dinv,
                                                  const float* __restrict__ y,
                                                  const float* __restrict__ b,
                                                  float* __restrict__ out, int N)
{
    int gt = blockIdx.x*256 + threadIdx.x;
    int n = gt >> 6, lane = gt & 63;
    if (n >= N) return;
    const int beg = row_start[n], end = row_start[n+1];
    float2 acc = make_float2(0.f, 0.f);
    for (int p = beg; p < end; ++p) {
        int s = src_s[p];
        float nrm = norm_s[p];
        float2 v = ld2(y + (size_t)s*HL + lane*2);
        acc.x = fmaf(nrm, v.x, acc.x);
        acc.y = fmaf(nrm, v.y, acc.y);
    }
    float di = dinv[n];
    float sl = di*di;
    float2 vs = ld2(y + (size_t)n*HL + lane*2);
    acc.x = fmaf(sl, vs.x, acc.x);
    acc.y = fmaf(sl, vs.y, acc.y);
    float2 bb = ld2(b + lane*2);
    acc.x = fmaxf(acc.x + bb.x, 0.f);
    acc.y = fmaxf(acc.y + bb.y, 0.f);
    *(float2*)(out + (size_t)n*HL + lane*2) = acc;
}

// out[N][16] = x[N][128] @ W[128][16] + b.
__global__ __launch_bounds__(256) void fc_kernel(const float* __restrict__ x,
                                                 const float* __restrict__ W,
                                                 const float* __restrict__ b,
                                                 float* __restrict__ out, int N)
{
    __shared__ float xs[64][HL];
    const int tid = threadIdx.x;
    const int n0 = blockIdx.x * 64;
    #pragma unroll
    for (int i = 0; i < 8; ++i) {
        int f = tid + 256*i;
        int row = f >> 5, part = f & 31;
        int n = n0 + row;
        float4 v = make_float4(0.f,0.f,0.f,0.f);
        if (n < N) v = ld4(x + (size_t)n*HL + part*4);
        st4(&xs[row][part*4], v);
    }
    __syncthreads();
    const int o = tid & 15, rg = tid >> 4;
    float acc[4] = {0.f,0.f,0.f,0.f};
    #pragma unroll 4
    for (int k = 0; k < HL; ++k) {
        float wv = W[k*OUTF + o];
        #pragma unroll
        for (int i = 0; i < 4; ++i)
            acc[i] = fmaf(xs[rg + 16*i][k], wv, acc[i]);
    }
    float bb = b[o];
    #pragma unroll
    for (int i = 0; i < 4; ++i) {
        int n = n0 + rg + 16*i;
        if (n < N) out[(size_t)n*OUTF + o] = acc[i] + bb;
    }
}

extern "C" void kernel_launch(void* const* d_in, const int* in_sizes, int n_in,
                              void* d_out, int out_size, void* d_ws, size_t ws_size,
                              hipStream_t stream)
{
    const int*   x_tokens = (const int*)d_in[0];
    const int*   lengths  = (const int*)d_in[1];
    const int*   eidx     = (const int*)d_in[2];
    const float* ew       = (const float*)d_in[3];
    const float* emb      = (const float*)d_in[4];
    const float* W_ih     = (const float*)d_in[5];
    const float* W_hh     = (const float*)d_in[6];
    const float* b_ih     = (const float*)d_in[7];
    const float* b_hh     = (const float*)d_in[8];
    const float* c1W      = (const float*)d_in[9];
    const float* c1b      = (const float*)d_in[10];
    const float* c2W      = (const float*)d_in[11];
    const float* c2b      = (const float*)d_in[12];
    const float* fcW      = (const float*)d_in[13];
    const float* fcb      = (const float*)d_in[14];
    float* out = (float*)d_out;

    const int* esrc = eidx;
    const int* edst = eidx + NEDGE;

    char* ws = (char*)d_ws;
    size_t off = 0;
    auto take = [&](size_t bytes) -> char* {
        char* p = ws + off;
        off = (off + bytes + 255) & ~(size_t)255;
        return p;
    };
    const size_t NH = (size_t)N_NODES * HL * sizeof(float);
    float* WT    = (float*)take((size_t)KTOT * G4 * sizeof(float));
    float* hA    = (float*)take(NH);            // h ping ; later y buffer
    float* hB    = (float*)take(NH);            // h pong ; later x2
    float* cS    = (float*)take(NH);            // c state; later x3
    float* hLst  = (float*)take(NH);
    float* degb  = (float*)take((size_t)N_NODES * sizeof(float));
    float* dinvb = (float*)take((size_t)N_NODES * sizeof(float));
    int*   cntb  = (int*)  take((size_t)N_NODES * sizeof(int));
    int*   rowst = (int*)  take((size_t)(N_NODES + 1) * sizeof(int));
    int*   curs  = (int*)  take((size_t)N_NODES * sizeof(int));
    int*   srcS  = (int*)  take((size_t)NEDGE * sizeof(int));
    float* nrmS  = (float*)take((size_t)NEDGE * sizeof(float));

    hipMemsetAsync(hA,   0, NH, stream);
    hipMemsetAsync(cS,   0, NH, stream);
    hipMemsetAsync(degb, 0, (size_t)N_NODES * sizeof(float), stream);
    hipMemsetAsync(cntb, 0, (size_t)N_NODES * sizeof(int), stream);
    hipMemsetAsync(curs, 0, (size_t)N_NODES * sizeof(int), stream);

    build_wt<<<(KTOT*G4 + 255)/256, 256, 0, stream>>>(W_ih, W_hh, WT);

    // CSR build (independent of LSTM chain)
    count_deg<<<NEDGE/256, 256, 0, stream>>>(edst, ew, cntb, degb, NEDGE);
    dinv_kernel<<<(N_NODES + 255)/256, 256, 0, stream>>>(degb, dinvb, N_NODES);
    scan_kernel<<<1, 1024, 0, stream>>>(cntb, rowst);
    fill_csr<<<NEDGE/256, 256, 0, stream>>>(esrc, edst, ew, dinvb, rowst, curs,
                                            srcS, nrmS, NEDGE);

    for (int t = 0; t < SEQ_T; ++t) {
        const float* hin  = (t & 1) ? hB : hA;
        float*       hout = (t & 1) ? hA : hB;
        lstm_step<<<N_NODES/32, 256, 0, stream>>>(x_tokens, lengths, emb, WT,
                                                  b_ih, b_hh, hin, cS, hout, hLst, t);
    }

    const int gemmBlocks = (N_NODES + 63)/64;
    const int gathBlocks = (N_NODES*64 + 255)/256;

    float* yb = hA;   // LSTM ping-pong buffers are free now
    float* x2 = hB;
    float* x3 = cS;

    // conv1: GEMM then fused gather(+self+bias+relu)
    gemm_nk128<<<gemmBlocks, 256, 0, stream>>>(hLst, c1W, yb, N_NODES);
    gcn_gather<<<gathBlocks, 256, 0, stream>>>(rowst, srcS, nrmS, dinvb, yb, c1b, x2, N_NODES);
    // conv2
    gemm_nk128<<<gemmBlocks, 256, 0, stream>>>(x2, c2W, yb, N_NODES);
    gcn_gather<<<gathBlocks, 256, 0, stream>>>(rowst, srcS, nrmS, dinvb, yb, c2b, x3, N_NODES);
    // fc
    fc_kernel<<<gemmBlocks, 256, 0, stream>>>(x3, fcW, fcb, out, N_NODES);
}

// Round 3
// 770.885 us; speedup vs baseline: 5.8803x; 3.2182x over previous
//
#include <hip/hip_runtime.h>
#include <math.h>

#define N_NODES 20000
#define SEQ_T   24
#define EMBD    64
#define HL      128     // H_LSTM
#define OUTF    16
#define NEDGE   640000
#define G4      512     // 4*HL
#define KTOT    192     // EMBD + HL
#define ROWS    48      // rows per LSTM block
#define LDA     232     // padded A-tile leading dim (bf16 elems), 464B = 29*16 -> 16B aligned rows
#define NBLSTM  417     // ceil(20000/48)

typedef __bf16 bf16x8 __attribute__((ext_vector_type(8)));
typedef float  f32x4  __attribute__((ext_vector_type(4)));

__device__ __forceinline__ float4 ld4(const float* p){ return *reinterpret_cast<const float4*>(p); }
__device__ __forceinline__ void st4(float* p, float4 v){ *reinterpret_cast<float4*>(p) = v; }
__device__ __forceinline__ float2 ld2(const float* p){ return *reinterpret_cast<const float2*>(p); }
__device__ __forceinline__ float sigm(float x){ return 1.0f/(1.0f + expf(-x)); }

#define FMA4(A,S,B) {(A).x=fmaf((S),(B).x,(A).x);(A).y=fmaf((S),(B).y,(A).y);(A).z=fmaf((S),(B).z,(A).z);(A).w=fmaf((S),(B).w,(A).w);}

// ---------------- prep kernels ----------------

// emb (fp32, [20001][64]) -> bf16
__global__ __launch_bounds__(256) void prep_embb(const float* __restrict__ emb,
                                                 __bf16* __restrict__ embb)
{
    int i = blockIdx.x*256 + threadIdx.x;
    int i4 = i*4;
    const int TOT = (N_NODES + 1) * EMBD;   // N_CAT+1 == 20001 rows
    if (i4 >= TOT) return;
    float4 v = ld4(emb + i4);
    embb[i4+0] = (__bf16)v.x;
    embb[i4+1] = (__bf16)v.y;
    embb[i4+2] = (__bf16)v.z;
    embb[i4+3] = (__bf16)v.w;
}

// Pack combined weights into MFMA B-fragment layout:
// WTp[((kc*512 + g)*32 + ko)] = bf16( kk<64 ? W_ih[g][kk] : W_hh[g][kk-64] ), kk = kc*32+ko.
// Lane l reads 16B at ko = (l>>4)*8 for col g = colbase + (l&15).
__global__ __launch_bounds__(256) void prep_wtp(const float* __restrict__ Wih,
                                                const float* __restrict__ Whh,
                                                __bf16* __restrict__ WTp)
{
    int idx = blockIdx.x*256 + threadIdx.x;
    if (idx >= KTOT*G4) return;
    int ko = idx & 31;
    int g  = (idx >> 5) & 511;
    int kc = idx >> 14;           // 512*32 = 16384
    int kk = kc*32 + ko;
    float v = (kk < EMBD) ? Wih[g*EMBD + kk] : Whh[g*HL + (kk - EMBD)];
    WTp[idx] = (__bf16)v;
}

__global__ __launch_bounds__(256) void prep_bias(const float* __restrict__ bi,
                                                 const float* __restrict__ bh,
                                                 float* __restrict__ bs)
{
    int i = blockIdx.x*256 + threadIdx.x;
    if (i < G4) bs[i] = bi[i] + bh[i];
}

// ---------------- fused LSTM (all 24 steps, MFMA bf16) ----------------
// Block: 48 rows x 512 gate-cols, 256 threads (4 waves).
// Wave w cols: j in [w*32, w*32+32) for ALL 4 gates (so c/h update is wave-local).
// A-tile [48][232] bf16 in LDS: cols 0..63 emb(t), 64..191 h(t-1) (written in-place by epilogue).
// c-state lives in registers. No global h/c traffic at all; only h_last is stored.
__global__ __launch_bounds__(256, 2) void lstm_fused(
    const int* __restrict__ tokens, const int* __restrict__ lengths,
    const __bf16* __restrict__ embb, const __bf16* __restrict__ WTp,
    const float* __restrict__ bsum, float* __restrict__ hlast)
{
    __shared__ __bf16 a_lds[ROWS][LDA];
    __shared__ int tok_lds[ROWS*SEQ_T];
    __shared__ int len_lds[ROWS];

    const int tid = threadIdx.x;
    const int n0  = blockIdx.x * ROWS;
    const int w   = tid >> 6;
    const int l   = tid & 63;
    const int l15 = l & 15, l4 = l >> 4;

    // stage tokens (coalesced; pad rows -> token 0 = zero embedding row)
    const int lim = ((N_NODES - n0 < ROWS) ? (N_NODES - n0) : ROWS) * SEQ_T;
    #pragma unroll
    for (int i = 0; i < 5; ++i) {
        int idx = tid + 256*i;
        if (idx < ROWS*SEQ_T) tok_lds[idx] = (idx < lim) ? tokens[n0*SEQ_T + idx] : 0;
    }
    if (tid < ROWS) len_lds[tid] = (n0 + tid < N_NODES) ? lengths[n0 + tid] : 0;

    // zero h region (cols 64..191)
    #pragma unroll
    for (int i = 0; i < 3; ++i) {
        int idx = tid + 256*i;
        if (idx < ROWS*16) {
            int row = idx >> 4, s = idx & 15;
            *reinterpret_cast<uint4*>(&a_lds[row][EMBD + s*8]) = make_uint4(0,0,0,0);
        }
    }

    float bias_v[4][2];
    #pragma unroll
    for (int gt = 0; gt < 4; ++gt)
        #pragma unroll
        for (int q = 0; q < 2; ++q)
            bias_v[gt][q] = bsum[gt*HL + w*32 + q*16 + l15];

    f32x4 acc[3][4][2];
    float c_reg[3][2][4];
    {
        f32x4 zz = {0.f,0.f,0.f,0.f};
        #pragma unroll
        for (int rf = 0; rf < 3; ++rf)
            #pragma unroll
            for (int gt = 0; gt < 4; ++gt)
                #pragma unroll
                for (int q = 0; q < 2; ++q) acc[rf][gt][q] = zz;
        #pragma unroll
        for (int rf = 0; rf < 3; ++rf)
            #pragma unroll
            for (int q = 0; q < 2; ++q)
                #pragma unroll
                for (int r = 0; r < 4; ++r) c_reg[rf][q][r] = 0.f;
    }

    for (int t = 0; t < SEQ_T; ++t) {
        // stage emb(t) into cols 0..63 (disjoint from h region; prev k-loop reads fenced
        // by the post-k-loop barrier of the previous iteration)
        #pragma unroll
        for (int i = 0; i < 2; ++i) {
            int idx = tid + 256*i;
            if (idx < ROWS*8) {
                int row = idx >> 3, sl = idx & 7;
                int tok = tok_lds[row*SEQ_T + t];
                *reinterpret_cast<uint4*>(&a_lds[row][sl*8]) =
                    *reinterpret_cast<const uint4*>(&embb[(size_t)tok*EMBD + sl*8]);
            }
        }
        __syncthreads();   // emb(t) + h(t-1) ready

        #pragma unroll
        for (int kc = 0; kc < 6; ++kc) {
            bf16x8 af[3];
            #pragma unroll
            for (int rf = 0; rf < 3; ++rf)
                af[rf] = *reinterpret_cast<const bf16x8*>(&a_lds[rf*16 + l15][kc*32 + l4*8]);
            #pragma unroll
            for (int gt = 0; gt < 4; ++gt)
                #pragma unroll
                for (int q = 0; q < 2; ++q) {
                    int col = gt*HL + w*32 + q*16 + l15;
                    bf16x8 bfv = *reinterpret_cast<const bf16x8*>(
                        &WTp[(size_t)(kc*G4 + col)*32 + l4*8]);
                    acc[0][gt][q] = __builtin_amdgcn_mfma_f32_16x16x32_bf16(af[0], bfv, acc[0][gt][q], 0, 0, 0);
                    acc[1][gt][q] = __builtin_amdgcn_mfma_f32_16x16x32_bf16(af[1], bfv, acc[1][gt][q], 0, 0, 0);
                    acc[2][gt][q] = __builtin_amdgcn_mfma_f32_16x16x32_bf16(af[2], bfv, acc[2][gt][q], 0, 0, 0);
                }
        }
        __syncthreads();   // all a_lds reads of step t complete

        // epilogue: gates in fp32, c in regs, h -> bf16 into a_lds h region
        #pragma unroll
        for (int rf = 0; rf < 3; ++rf)
            #pragma unroll
            for (int q = 0; q < 2; ++q) {
                f32x4 zi4 = acc[rf][0][q], zf4 = acc[rf][1][q];
                f32x4 zg4 = acc[rf][2][q], zo4 = acc[rf][3][q];
                #pragma unroll
                for (int r = 0; r < 4; ++r) {
                    int row = rf*16 + l4*4 + r;
                    float zi = zi4[r] + bias_v[0][q];
                    float zf = zf4[r] + bias_v[1][q];
                    float zg = zg4[r] + bias_v[2][q];
                    float zo = zo4[r] + bias_v[3][q];
                    float cc = sigm(zf)*c_reg[rf][q][r] + sigm(zi)*tanhf(zg);
                    c_reg[rf][q][r] = cc;
                    float h = sigm(zo)*tanhf(cc);
                    int j = w*32 + q*16 + l15;
                    a_lds[row][EMBD + j] = (__bf16)h;
                    int n = n0 + row;
                    if (t == len_lds[row] - 1 && n < N_NODES)
                        hlast[(size_t)n*HL + j] = h;
                }
                f32x4 zz = {0.f,0.f,0.f,0.f};
                acc[rf][0][q] = zz; acc[rf][1][q] = zz;
                acc[rf][2][q] = zz; acc[rf][3][q] = zz;
            }
        // no barrier needed here: next emb stage writes cols 0..63 only; ordering vs
        // this step's reads was established by the post-k-loop barrier, and the next
        // pre-k-loop barrier publishes the h writes.
    }
}

// ---------------- CSR build ----------------

__global__ __launch_bounds__(256) void count_deg(const int* __restrict__ dst,
                                                 const float* __restrict__ w,
                                                 int* __restrict__ cnt,
                                                 float* __restrict__ deg, int E)
{
    int e = blockIdx.x*256 + threadIdx.x;
    if (e < E) {
        int d = dst[e];
        atomicAdd(&cnt[d], 1);
        atomicAdd(&deg[d], w[e]);
    }
}

__global__ __launch_bounds__(256) void dinv_kernel(const float* __restrict__ deg,
                                                   float* __restrict__ dinv, int N)
{
    int n = blockIdx.x*256 + threadIdx.x;
    if (n < N) dinv[n] = rsqrtf(deg[n] + 1.0f);
}

__global__ __launch_bounds__(1024) void scan_kernel(const int* __restrict__ cnt,
                                                    int* __restrict__ row_start)
{
    __shared__ int part[1024];
    const int t = threadIdx.x;
    const int CH = (N_NODES + 1023) / 1024;   // 20
    int beg = t*CH, end = min(beg + CH, N_NODES);
    int s = 0;
    for (int i = beg; i < end; ++i) s += cnt[i];
    part[t] = s;
    __syncthreads();
    for (int off = 1; off < 1024; off <<= 1) {
        int v = (t >= off) ? part[t - off] : 0;
        __syncthreads();
        part[t] += v;
        __syncthreads();
    }
    int base = (t == 0) ? 0 : part[t - 1];
    for (int i = beg; i < end; ++i) { row_start[i] = base; base += cnt[i]; }
    if (t == 1023) row_start[N_NODES] = part[1023];
}

__global__ __launch_bounds__(256) void fill_csr(const int* __restrict__ src,
                                                const int* __restrict__ dst,
                                                const float* __restrict__ w,
                                                const float* __restrict__ dinv,
                                                const int* __restrict__ row_start,
                                                int* __restrict__ cursor,
                                                int* __restrict__ src_s,
                                                float* __restrict__ norm_s, int E)
{
    int e = blockIdx.x*256 + threadIdx.x;
    if (e >= E) return;
    int d = dst[e];
    int pos = row_start[d] + atomicAdd(&cursor[d], 1);
    int s = src[e];
    src_s[pos]  = s;
    norm_s[pos] = dinv[s] * w[e] * dinv[d];
}

// ---------------- GCN ----------------

__global__ __launch_bounds__(256) void gemm_nk128(const float* __restrict__ x,
                                                  const float* __restrict__ W,
                                                  float* __restrict__ y, int N)
{
    __shared__ float xs[64][HL];
    const int tid = threadIdx.x;
    const int n0 = blockIdx.x * 64;
    #pragma unroll
    for (int i = 0; i < 8; ++i) {
        int f = tid + 256*i;
        int row = f >> 5, part = f & 31;
        int n = n0 + row;
        float4 v = make_float4(0.f,0.f,0.f,0.f);
        if (n < N) v = ld4(x + (size_t)n*HL + part*4);
        st4(&xs[row][part*4], v);
    }
    __syncthreads();
    const int jg = tid & 31, rg = tid >> 5;
    const int j0 = jg*4;
    float4 acc[8];
    #pragma unroll
    for (int i = 0; i < 8; ++i) acc[i] = make_float4(0.f,0.f,0.f,0.f);
    #pragma unroll 4
    for (int k = 0; k < HL; ++k) {
        float4 wv = ld4(W + (size_t)k*HL + j0);
        #pragma unroll
        for (int i = 0; i < 8; ++i) {
            float xv = xs[rg + 8*i][k];
            FMA4(acc[i], xv, wv);
        }
    }
    #pragma unroll
    for (int i = 0; i < 8; ++i) {
        int n = n0 + rg + 8*i;
        if (n < N) st4(y + (size_t)n*HL + j0, acc[i]);
    }
}

__global__ __launch_bounds__(256) void gcn_gather(const int* __restrict__ row_start,
                                                  const int* __restrict__ src_s,
                                                  const float* __restrict__ norm_s,
                                                  const float* __restrict__ dinv,
                                                  const float* __restrict__ y,
                                                  const float* __restrict__ b,
                                                  float* __restrict__ out, int N)
{
    int gt = blockIdx.x*256 + threadIdx.x;
    int n = gt >> 6, lane = gt & 63;
    if (n >= N) return;
    const int beg = row_start[n], end = row_start[n+1];
    float2 acc = make_float2(0.f, 0.f);
    for (int p = beg; p < end; ++p) {
        int s = src_s[p];
        float nrm = norm_s[p];
        float2 v = ld2(y + (size_t)s*HL + lane*2);
        acc.x = fmaf(nrm, v.x, acc.x);
        acc.y = fmaf(nrm, v.y, acc.y);
    }
    float di = dinv[n];
    float sl = di*di;
    float2 vs = ld2(y + (size_t)n*HL + lane*2);
    acc.x = fmaf(sl, vs.x, acc.x);
    acc.y = fmaf(sl, vs.y, acc.y);
    float2 bb = ld2(b + lane*2);
    acc.x = fmaxf(acc.x + bb.x, 0.f);
    acc.y = fmaxf(acc.y + bb.y, 0.f);
    *(float2*)(out + (size_t)n*HL + lane*2) = acc;
}

__global__ __launch_bounds__(256) void fc_kernel(const float* __restrict__ x,
                                                 const float* __restrict__ W,
                                                 const float* __restrict__ b,
                                                 float* __restrict__ out, int N)
{
    __shared__ float xs[64][HL];
    const int tid = threadIdx.x;
    const int n0 = blockIdx.x * 64;
    #pragma unroll
    for (int i = 0; i < 8; ++i) {
        int f = tid + 256*i;
        int row = f >> 5, part = f & 31;
        int n = n0 + row;
        float4 v = make_float4(0.f,0.f,0.f,0.f);
        if (n < N) v = ld4(x + (size_t)n*HL + part*4);
        st4(&xs[row][part*4], v);
    }
    __syncthreads();
    const int o = tid & 15, rg = tid >> 4;
    float acc[4] = {0.f,0.f,0.f,0.f};
    #pragma unroll 4
    for (int k = 0; k < HL; ++k) {
        float wv = W[k*OUTF + o];
        #pragma unroll
        for (int i = 0; i < 4; ++i)
            acc[i] = fmaf(xs[rg + 16*i][k], wv, acc[i]);
    }
    float bb = b[o];
    #pragma unroll
    for (int i = 0; i < 4; ++i) {
        int n = n0 + rg + 16*i;
        if (n < N) out[(size_t)n*OUTF + o] = acc[i] + bb;
    }
}

extern "C" void kernel_launch(void* const* d_in, const int* in_sizes, int n_in,
                              void* d_out, int out_size, void* d_ws, size_t ws_size,
                              hipStream_t stream)
{
    const int*   x_tokens = (const int*)d_in[0];
    const int*   lengths  = (const int*)d_in[1];
    const int*   eidx     = (const int*)d_in[2];
    const float* ew       = (const float*)d_in[3];
    const float* emb      = (const float*)d_in[4];
    const float* W_ih     = (const float*)d_in[5];
    const float* W_hh     = (const float*)d_in[6];
    const float* b_ih     = (const float*)d_in[7];
    const float* b_hh     = (const float*)d_in[8];
    const float* c1W      = (const float*)d_in[9];
    const float* c1b      = (const float*)d_in[10];
    const float* c2W      = (const float*)d_in[11];
    const float* c2b      = (const float*)d_in[12];
    const float* fcW      = (const float*)d_in[13];
    const float* fcb      = (const float*)d_in[14];
    float* out = (float*)d_out;

    const int* esrc = eidx;
    const int* edst = eidx + NEDGE;

    char* ws = (char*)d_ws;
    size_t off = 0;
    auto take = [&](size_t bytes) -> char* {
        char* p = ws + off;
        off = (off + bytes + 255) & ~(size_t)255;
        return p;
    };
    const size_t NH = (size_t)N_NODES * HL * sizeof(float);
    __bf16* embb = (__bf16*)take((size_t)(N_NODES + 1) * EMBD * sizeof(__bf16));
    __bf16* WTp  = (__bf16*)take((size_t)KTOT * G4 * sizeof(__bf16));
    float* bsum  = (float*)take((size_t)G4 * sizeof(float));
    float* hLst  = (float*)take(NH);
    float* yb    = (float*)take(NH);
    float* x2    = (float*)take(NH);
    float* x3    = (float*)take(NH);
    float* degb  = (float*)take((size_t)N_NODES * sizeof(float));
    float* dinvb = (float*)take((size_t)N_NODES * sizeof(float));
    int*   cntb  = (int*)  take((size_t)N_NODES * sizeof(int));
    int*   rowst = (int*)  take((size_t)(N_NODES + 1) * sizeof(int));
    int*   curs  = (int*)  take((size_t)N_NODES * sizeof(int));
    int*   srcS  = (int*)  take((size_t)NEDGE * sizeof(int));
    float* nrmS  = (float*)take((size_t)NEDGE * sizeof(float));

    hipMemsetAsync(degb, 0, (size_t)N_NODES * sizeof(float), stream);
    hipMemsetAsync(cntb, 0, (size_t)N_NODES * sizeof(int), stream);
    hipMemsetAsync(curs, 0, (size_t)N_NODES * sizeof(int), stream);

    // prep
    prep_embb<<<(((N_NODES+1)*EMBD/4) + 255)/256, 256, 0, stream>>>(emb, embb);
    prep_wtp<<<(KTOT*G4 + 255)/256, 256, 0, stream>>>(W_ih, W_hh, WTp);
    prep_bias<<<2, 256, 0, stream>>>(b_ih, b_hh, bsum);

    // CSR build (independent of LSTM chain)
    count_deg<<<NEDGE/256, 256, 0, stream>>>(edst, ew, cntb, degb, NEDGE);
    dinv_kernel<<<(N_NODES + 255)/256, 256, 0, stream>>>(degb, dinvb, N_NODES);
    scan_kernel<<<1, 1024, 0, stream>>>(cntb, rowst);
    fill_csr<<<NEDGE/256, 256, 0, stream>>>(esrc, edst, ew, dinvb, rowst, curs,
                                            srcS, nrmS, NEDGE);

    // fused LSTM: all 24 steps in one launch
    lstm_fused<<<NBLSTM, 256, 0, stream>>>(x_tokens, lengths, embb, WTp, bsum, hLst);

    const int gemmBlocks = (N_NODES + 63)/64;
    const int gathBlocks = (N_NODES*64 + 255)/256;

    // conv1
    gemm_nk128<<<gemmBlocks, 256, 0, stream>>>(hLst, c1W, yb, N_NODES);
    gcn_gather<<<gathBlocks, 256, 0, stream>>>(rowst, srcS, nrmS, dinvb, yb, c1b, x2, N_NODES);
    // conv2
    gemm_nk128<<<gemmBlocks, 256, 0, stream>>>(x2, c2W, yb, N_NODES);
    gcn_gather<<<gathBlocks, 256, 0, stream>>>(rowst, srcS, nrmS, dinvb, yb, c2b, x3, N_NODES);
    // fc
    fc_kernel<<<gemmBlocks, 256, 0, stream>>>(x3, fcW, fcb, out, N_NODES);
}

// Round 4
// 694.297 us; speedup vs baseline: 6.5290x; 1.1103x over previous
//
#include <hip/hip_runtime.h>
#include <math.h>

#define N_NODES 20000
#define SEQ_T   24
#define EMBD    64
#define HL      128     // H_LSTM
#define OUTF    16
#define NEDGE   640000
#define G4      512     // 4*HL
#define KTOT    192     // EMBD + HL
#define ROWS    48      // rows per LSTM block
#define LDA     232     // padded A-tile leading dim (bf16 elems); 464B rows, 16B-aligned
#define NBLSTM  417     // ceil(20000/48)
#define WSTRIDE 24576   // per-wave contiguous weight chunk, elems (48 KB)

typedef __bf16 bf16x8 __attribute__((ext_vector_type(8)));
typedef float  f32x4  __attribute__((ext_vector_type(4)));

__device__ __forceinline__ float4 ld4(const float* p){ return *reinterpret_cast<const float4*>(p); }
__device__ __forceinline__ void st4(float* p, float4 v){ *reinterpret_cast<float4*>(p) = v; }
__device__ __forceinline__ float2 ld2(const float* p){ return *reinterpret_cast<const float2*>(p); }
__device__ __forceinline__ float sigm(float x){ return 1.0f/(1.0f + expf(-x)); }

// fast gate math: v_exp_f32 computes 2^x; v_rcp_f32. Branch-free, ~1e-7 rel err.
#define LOG2E 1.44269504f
__device__ __forceinline__ float fsigm(float x){
    return __builtin_amdgcn_rcpf(1.0f + __builtin_amdgcn_exp2f(-LOG2E*x));
}
__device__ __forceinline__ float ftanh(float x){
    return 1.0f - 2.0f*__builtin_amdgcn_rcpf(1.0f + __builtin_amdgcn_exp2f(2.0f*LOG2E*x));
}

#define FMA4(A,S,B) {(A).x=fmaf((S),(B).x,(A).x);(A).y=fmaf((S),(B).y,(A).y);(A).z=fmaf((S),(B).z,(A).z);(A).w=fmaf((S),(B).w,(A).w);}

// ---------------- prep kernels ----------------

// emb (fp32, [20001][64]) -> bf16
__global__ __launch_bounds__(256) void prep_embb(const float* __restrict__ emb,
                                                 __bf16* __restrict__ embb)
{
    int i = blockIdx.x*256 + threadIdx.x;
    int i4 = i*4;
    const int TOT = (N_NODES + 1) * EMBD;
    if (i4 >= TOT) return;
    float4 v = ld4(emb + i4);
    embb[i4+0] = (__bf16)v.x;
    embb[i4+1] = (__bf16)v.y;
    embb[i4+2] = (__bf16)v.z;
    embb[i4+3] = (__bf16)v.w;
}

// Pack combined weights into per-wave-contiguous MFMA B-fragment layout:
// idx = ((((w*6 + kc)*4 + gt)*2 + q)*16 + c)*32 + ko
//   -> col g = gt*128 + w*32 + q*16 + c, k = kc*32 + ko
// Wave w streams a contiguous 48 KB chunk per step.
__global__ __launch_bounds__(256) void prep_wtp(const float* __restrict__ Wih,
                                                const float* __restrict__ Whh,
                                                __bf16* __restrict__ WTp)
{
    int idx = blockIdx.x*256 + threadIdx.x;
    if (idx >= KTOT*G4) return;
    int ko = idx & 31;
    int c  = (idx >> 5) & 15;
    int q  = (idx >> 9) & 1;
    int gt = (idx >> 10) & 3;
    int kc = (idx >> 12) % 6;
    int w  = idx / WSTRIDE;
    int g  = gt*HL + w*32 + q*16 + c;
    int kk = kc*32 + ko;
    float v = (kk < EMBD) ? Wih[g*EMBD + kk] : Whh[g*HL + (kk - EMBD)];
    WTp[idx] = (__bf16)v;
}

__global__ __launch_bounds__(256) void prep_bias(const float* __restrict__ bi,
                                                 const float* __restrict__ bh,
                                                 float* __restrict__ bs)
{
    int i = blockIdx.x*256 + threadIdx.x;
    if (i < G4) bs[i] = bi[i] + bh[i];
}

// ---------------- fused LSTM (all 24 steps, MFMA bf16) ----------------
__global__ __launch_bounds__(256, 2) void lstm_fused(
    const int* __restrict__ tokens, const int* __restrict__ lengths,
    const __bf16* __restrict__ embb, const __bf16* __restrict__ WTp,
    const float* __restrict__ bsum, float* __restrict__ hlast)
{
    __shared__ __bf16 a_lds[ROWS][LDA];
    __shared__ int tok_lds[ROWS*SEQ_T];
    __shared__ int len_lds[ROWS];

    const int tid = threadIdx.x;
    const int n0  = blockIdx.x * ROWS;
    const int w   = tid >> 6;
    const int l   = tid & 63;
    const int l15 = l & 15, l4 = l >> 4;

    const int lim = ((N_NODES - n0 < ROWS) ? (N_NODES - n0) : ROWS) * SEQ_T;
    #pragma unroll
    for (int i = 0; i < 5; ++i) {
        int idx = tid + 256*i;
        if (idx < ROWS*SEQ_T) tok_lds[idx] = (idx < lim) ? tokens[n0*SEQ_T + idx] : 0;
    }
    if (tid < ROWS) len_lds[tid] = (n0 + tid < N_NODES) ? lengths[n0 + tid] : 0;

    #pragma unroll
    for (int i = 0; i < 3; ++i) {
        int idx = tid + 256*i;
        if (idx < ROWS*16) {
            int row = idx >> 4, s = idx & 15;
            *reinterpret_cast<uint4*>(&a_lds[row][EMBD + s*8]) = make_uint4(0,0,0,0);
        }
    }

    float bias_v[4][2];
    #pragma unroll
    for (int gt = 0; gt < 4; ++gt)
        #pragma unroll
        for (int q = 0; q < 2; ++q)
            bias_v[gt][q] = bsum[gt*HL + w*32 + q*16 + l15];

    const __bf16* wbase = WTp + (size_t)w * WSTRIDE;

    f32x4 acc[3][4][2];
    float c_reg[3][2][4];
    {
        f32x4 zz = {0.f,0.f,0.f,0.f};
        #pragma unroll
        for (int rf = 0; rf < 3; ++rf)
            #pragma unroll
            for (int gt = 0; gt < 4; ++gt)
                #pragma unroll
                for (int q = 0; q < 2; ++q) acc[rf][gt][q] = zz;
        #pragma unroll
        for (int rf = 0; rf < 3; ++rf)
            #pragma unroll
            for (int q = 0; q < 2; ++q)
                #pragma unroll
                for (int r = 0; r < 4; ++r) c_reg[rf][q][r] = 0.f;
    }

    for (int t = 0; t < SEQ_T; ++t) {
        #pragma unroll
        for (int i = 0; i < 2; ++i) {
            int idx = tid + 256*i;
            if (idx < ROWS*8) {
                int row = idx >> 3, sl = idx & 7;
                int tok = tok_lds[row*SEQ_T + t];
                *reinterpret_cast<uint4*>(&a_lds[row][sl*8]) =
                    *reinterpret_cast<const uint4*>(&embb[(size_t)tok*EMBD + sl*8]);
            }
        }
        __syncthreads();   // emb(t) + h(t-1) ready

        #pragma unroll
        for (int kc = 0; kc < 6; ++kc) {
            bf16x8 af[3];
            #pragma unroll
            for (int rf = 0; rf < 3; ++rf)
                af[rf] = *reinterpret_cast<const bf16x8*>(&a_lds[rf*16 + l15][kc*32 + l4*8]);
            #pragma unroll
            for (int gt = 0; gt < 4; ++gt)
                #pragma unroll
                for (int q = 0; q < 2; ++q) {
                    bf16x8 bfv = *reinterpret_cast<const bf16x8*>(
                        &wbase[(size_t)(((kc*4 + gt)*2 + q)*16)*32 + l15*32 + l4*8]);
                    acc[0][gt][q] = __builtin_amdgcn_mfma_f32_16x16x32_bf16(af[0], bfv, acc[0][gt][q], 0, 0, 0);
                    acc[1][gt][q] = __builtin_amdgcn_mfma_f32_16x16x32_bf16(af[1], bfv, acc[1][gt][q], 0, 0, 0);
                    acc[2][gt][q] = __builtin_amdgcn_mfma_f32_16x16x32_bf16(af[2], bfv, acc[2][gt][q], 0, 0, 0);
                }
        }
        __syncthreads();   // all a_lds reads of step t complete

        // epilogue: branch-free fast gates in fp32; c in regs; h -> bf16 into a_lds
        #pragma unroll
        for (int rf = 0; rf < 3; ++rf)
            #pragma unroll
            for (int q = 0; q < 2; ++q) {
                f32x4 zi4 = acc[rf][0][q], zf4 = acc[rf][1][q];
                f32x4 zg4 = acc[rf][2][q], zo4 = acc[rf][3][q];
                #pragma unroll
                for (int r = 0; r < 4; ++r) {
                    int row = rf*16 + l4*4 + r;
                    float zi = zi4[r] + bias_v[0][q];
                    float zf = zf4[r] + bias_v[1][q];
                    float zg = zg4[r] + bias_v[2][q];
                    float zo = zo4[r] + bias_v[3][q];
                    float cc = fsigm(zf)*c_reg[rf][q][r] + fsigm(zi)*ftanh(zg);
                    c_reg[rf][q][r] = cc;
                    float h = fsigm(zo)*ftanh(cc);
                    int j = w*32 + q*16 + l15;
                    a_lds[row][EMBD + j] = (__bf16)h;
                    int n = n0 + row;
                    if (t == len_lds[row] - 1 && n < N_NODES)
                        __builtin_nontemporal_store(h, &hlast[(size_t)n*HL + j]);
                }
                f32x4 zz = {0.f,0.f,0.f,0.f};
                acc[rf][0][q] = zz; acc[rf][1][q] = zz;
                acc[rf][2][q] = zz; acc[rf][3][q] = zz;
            }
    }
}

// ---------------- CSR build ----------------

__global__ __launch_bounds__(256) void count_deg(const int* __restrict__ dst,
                                                 const float* __restrict__ w,
                                                 int* __restrict__ cnt,
                                                 float* __restrict__ deg, int E)
{
    int e = blockIdx.x*256 + threadIdx.x;
    if (e < E) {
        int d = dst[e];
        atomicAdd(&cnt[d], 1);
        atomicAdd(&deg[d], w[e]);
    }
}

__global__ __launch_bounds__(256) void dinv_kernel(const float* __restrict__ deg,
                                                   float* __restrict__ dinv, int N)
{
    int n = blockIdx.x*256 + threadIdx.x;
    if (n < N) dinv[n] = rsqrtf(deg[n] + 1.0f);
}

__global__ __launch_bounds__(1024) void scan_kernel(const int* __restrict__ cnt,
                                                    int* __restrict__ row_start)
{
    __shared__ int part[1024];
    const int t = threadIdx.x;
    const int CH = (N_NODES + 1023) / 1024;   // 20
    int beg = t*CH, end = min(beg + CH, N_NODES);
    int s = 0;
    for (int i = beg; i < end; ++i) s += cnt[i];
    part[t] = s;
    __syncthreads();
    for (int off = 1; off < 1024; off <<= 1) {
        int v = (t >= off) ? part[t - off] : 0;
        __syncthreads();
        part[t] += v;
        __syncthreads();
    }
    int base = (t == 0) ? 0 : part[t - 1];
    for (int i = beg; i < end; ++i) { row_start[i] = base; base += cnt[i]; }
    if (t == 1023) row_start[N_NODES] = part[1023];
}

__global__ __launch_bounds__(256) void fill_csr(const int* __restrict__ src,
                                                const int* __restrict__ dst,
                                                const float* __restrict__ w,
                                                const float* __restrict__ dinv,
                                                const int* __restrict__ row_start,
                                                int* __restrict__ cursor,
                                                int* __restrict__ src_s,
                                                float* __restrict__ norm_s, int E)
{
    int e = blockIdx.x*256 + threadIdx.x;
    if (e >= E) return;
    int d = dst[e];
    int pos = row_start[d] + atomicAdd(&cursor[d], 1);
    int s = src[e];
    src_s[pos]  = s;
    norm_s[pos] = dinv[s] * w[e] * dinv[d];
}

// ---------------- GCN ----------------

__global__ __launch_bounds__(256) void gemm_nk128(const float* __restrict__ x,
                                                  const float* __restrict__ W,
                                                  float* __restrict__ y, int N)
{
    __shared__ float xs[64][HL];
    const int tid = threadIdx.x;
    const int n0 = blockIdx.x * 64;
    #pragma unroll
    for (int i = 0; i < 8; ++i) {
        int f = tid + 256*i;
        int row = f >> 5, part = f & 31;
        int n = n0 + row;
        float4 v = make_float4(0.f,0.f,0.f,0.f);
        if (n < N) v = ld4(x + (size_t)n*HL + part*4);
        st4(&xs[row][part*4], v);
    }
    __syncthreads();
    const int jg = tid & 31, rg = tid >> 5;
    const int j0 = jg*4;
    float4 acc[8];
    #pragma unroll
    for (int i = 0; i < 8; ++i) acc[i] = make_float4(0.f,0.f,0.f,0.f);
    #pragma unroll 4
    for (int k = 0; k < HL; ++k) {
        float4 wv = ld4(W + (size_t)k*HL + j0);
        #pragma unroll
        for (int i = 0; i < 8; ++i) {
            float xv = xs[rg + 8*i][k];
            FMA4(acc[i], xv, wv);
        }
    }
    #pragma unroll
    for (int i = 0; i < 8; ++i) {
        int n = n0 + rg + 8*i;
        if (n < N) st4(y + (size_t)n*HL + j0, acc[i]);
    }
}

__global__ __launch_bounds__(256) void gcn_gather(const int* __restrict__ row_start,
                                                  const int* __restrict__ src_s,
                                                  const float* __restrict__ norm_s,
                                                  const float* __restrict__ dinv,
                                                  const float* __restrict__ y,
                                                  const float* __restrict__ b,
                                                  float* __restrict__ out, int N)
{
    int gt = blockIdx.x*256 + threadIdx.x;
    int n = gt >> 6, lane = gt & 63;
    if (n >= N) return;
    const int beg = row_start[n], end = row_start[n+1];
    float2 acc = make_float2(0.f, 0.f);
    for (int p = beg; p < end; ++p) {
        int s = src_s[p];
        float nrm = norm_s[p];
        float2 v = ld2(y + (size_t)s*HL + lane*2);
        acc.x = fmaf(nrm, v.x, acc.x);
        acc.y = fmaf(nrm, v.y, acc.y);
    }
    float di = dinv[n];
    float sl = di*di;
    float2 vs = ld2(y + (size_t)n*HL + lane*2);
    acc.x = fmaf(sl, vs.x, acc.x);
    acc.y = fmaf(sl, vs.y, acc.y);
    float2 bb = ld2(b + lane*2);
    acc.x = fmaxf(acc.x + bb.x, 0.f);
    acc.y = fmaxf(acc.y + bb.y, 0.f);
    *(float2*)(out + (size_t)n*HL + lane*2) = acc;
}

__global__ __launch_bounds__(256) void fc_kernel(const float* __restrict__ x,
                                                 const float* __restrict__ W,
                                                 const float* __restrict__ b,
                                                 float* __restrict__ out, int N)
{
    __shared__ float xs[64][HL];
    const int tid = threadIdx.x;
    const int n0 = blockIdx.x * 64;
    #pragma unroll
    for (int i = 0; i < 8; ++i) {
        int f = tid + 256*i;
        int row = f >> 5, part = f & 31;
        int n = n0 + row;
        float4 v = make_float4(0.f,0.f,0.f,0.f);
        if (n < N) v = ld4(x + (size_t)n*HL + part*4);
        st4(&xs[row][part*4], v);
    }
    __syncthreads();
    const int o = tid & 15, rg = tid >> 4;
    float acc[4] = {0.f,0.f,0.f,0.f};
    #pragma unroll 4
    for (int k = 0; k < HL; ++k) {
        float wv = W[k*OUTF + o];
        #pragma unroll
        for (int i = 0; i < 4; ++i)
            acc[i] = fmaf(xs[rg + 16*i][k], wv, acc[i]);
    }
    float bb = b[o];
    #pragma unroll
    for (int i = 0; i < 4; ++i) {
        int n = n0 + rg + 16*i;
        if (n < N) out[(size_t)n*OUTF + o] = acc[i] + bb;
    }
}

extern "C" void kernel_launch(void* const* d_in, const int* in_sizes, int n_in,
                              void* d_out, int out_size, void* d_ws, size_t ws_size,
                              hipStream_t stream)
{
    const int*   x_tokens = (const int*)d_in[0];
    const int*   lengths  = (const int*)d_in[1];
    const int*   eidx     = (const int*)d_in[2];
    const float* ew       = (const float*)d_in[3];
    const float* emb      = (const float*)d_in[4];
    const float* W_ih     = (const float*)d_in[5];
    const float* W_hh     = (const float*)d_in[6];
    const float* b_ih     = (const float*)d_in[7];
    const float* b_hh     = (const float*)d_in[8];
    const float* c1W      = (const float*)d_in[9];
    const float* c1b      = (const float*)d_in[10];
    const float* c2W      = (const float*)d_in[11];
    const float* c2b      = (const float*)d_in[12];
    const float* fcW      = (const float*)d_in[13];
    const float* fcb      = (const float*)d_in[14];
    float* out = (float*)d_out;

    const int* esrc = eidx;
    const int* edst = eidx + NEDGE;

    char* ws = (char*)d_ws;
    size_t off = 0;
    auto take = [&](size_t bytes) -> char* {
        char* p = ws + off;
        off = (off + bytes + 255) & ~(size_t)255;
        return p;
    };
    const size_t NH = (size_t)N_NODES * HL * sizeof(float);
    __bf16* embb = (__bf16*)take((size_t)(N_NODES + 1) * EMBD * sizeof(__bf16));
    __bf16* WTp  = (__bf16*)take((size_t)KTOT * G4 * sizeof(__bf16));
    float* bsum  = (float*)take((size_t)G4 * sizeof(float));
    float* hLst  = (float*)take(NH);
    float* yb    = (float*)take(NH);
    float* x2    = (float*)take(NH);
    float* x3    = (float*)take(NH);
    float* degb  = (float*)take((size_t)N_NODES * sizeof(float));
    float* dinvb = (float*)take((size_t)N_NODES * sizeof(float));
    int*   cntb  = (int*)  take((size_t)N_NODES * sizeof(int));
    int*   rowst = (int*)  take((size_t)(N_NODES + 1) * sizeof(int));
    int*   curs  = (int*)  take((size_t)N_NODES * sizeof(int));
    int*   srcS  = (int*)  take((size_t)NEDGE * sizeof(int));
    float* nrmS  = (float*)take((size_t)NEDGE * sizeof(float));

    hipMemsetAsync(degb, 0, (size_t)N_NODES * sizeof(float), stream);
    hipMemsetAsync(cntb, 0, (size_t)N_NODES * sizeof(int), stream);
    hipMemsetAsync(curs, 0, (size_t)N_NODES * sizeof(int), stream);

    prep_embb<<<(((N_NODES+1)*EMBD/4) + 255)/256, 256, 0, stream>>>(emb, embb);
    prep_wtp<<<(KTOT*G4 + 255)/256, 256, 0, stream>>>(W_ih, W_hh, WTp);
    prep_bias<<<2, 256, 0, stream>>>(b_ih, b_hh, bsum);

    count_deg<<<NEDGE/256, 256, 0, stream>>>(edst, ew, cntb, degb, NEDGE);
    dinv_kernel<<<(N_NODES + 255)/256, 256, 0, stream>>>(degb, dinvb, N_NODES);
    scan_kernel<<<1, 1024, 0, stream>>>(cntb, rowst);
    fill_csr<<<NEDGE/256, 256, 0, stream>>>(esrc, edst, ew, dinvb, rowst, curs,
                                            srcS, nrmS, NEDGE);

    lstm_fused<<<NBLSTM, 256, 0, stream>>>(x_tokens, lengths, embb, WTp, bsum, hLst);

    const int gemmBlocks = (N_NODES + 63)/64;
    const int gathBlocks = (N_NODES*64 + 255)/256;

    gemm_nk128<<<gemmBlocks, 256, 0, stream>>>(hLst, c1W, yb, N_NODES);
    gcn_gather<<<gathBlocks, 256, 0, stream>>>(rowst, srcS, nrmS, dinvb, yb, c1b, x2, N_NODES);
    gemm_nk128<<<gemmBlocks, 256, 0, stream>>>(x2, c2W, yb, N_NODES);
    gcn_gather<<<gathBlocks, 256, 0, stream>>>(rowst, srcS, nrmS, dinvb, yb, c2b, x3, N_NODES);
    fc_kernel<<<gemmBlocks, 256, 0, stream>>>(x3, fcW, fcb, out, N_NODES);
}

// Round 5
// 517.393 us; speedup vs baseline: 8.7613x; 1.3419x over previous
//
#include <hip/hip_runtime.h>
#include <math.h>

#define N_NODES 20000
#define SEQ_T   24
#define EMBD    64
#define HL      128     // H_LSTM
#define OUTF    16
#define NEDGE   640000
#define G4      512     // 4*HL
#define KTOT    192     // EMBD + HL
#define ROWS    80      // rows per LSTM block (250 * 80 = 20000 exactly)
#define RF      5       // ROWS/16 row-fragments
#define LDA     232     // padded A-tile leading dim (bf16 elems); 464B rows, 16B-aligned
#define NBLSTM  250
#define WSTRIDE 12288   // per-wave weight chunk, elems: 6 kc * 4 gt * 16 c * 32 ko (24 KB)

typedef __bf16 bf16x8 __attribute__((ext_vector_type(8)));
typedef float  f32x4  __attribute__((ext_vector_type(4)));

__device__ __forceinline__ float4 ld4(const float* p){ return *reinterpret_cast<const float4*>(p); }
__device__ __forceinline__ void st4(float* p, float4 v){ *reinterpret_cast<float4*>(p) = v; }
__device__ __forceinline__ float2 ld2(const float* p){ return *reinterpret_cast<const float2*>(p); }

// fast gate math: v_exp_f32 computes 2^x; v_rcp_f32. Branch-free, ~1e-7 rel err.
#define LOG2E 1.44269504f
__device__ __forceinline__ float fsigm(float x){
    return __builtin_amdgcn_rcpf(1.0f + __builtin_amdgcn_exp2f(-LOG2E*x));
}
__device__ __forceinline__ float ftanh(float x){
    return 1.0f - 2.0f*__builtin_amdgcn_rcpf(1.0f + __builtin_amdgcn_exp2f(2.0f*LOG2E*x));
}

#define FMA4(A,S,B) {(A).x=fmaf((S),(B).x,(A).x);(A).y=fmaf((S),(B).y,(A).y);(A).z=fmaf((S),(B).z,(A).z);(A).w=fmaf((S),(B).w,(A).w);}

// ---------------- prep kernels ----------------

// emb (fp32, [20001][64]) -> bf16
__global__ __launch_bounds__(256) void prep_embb(const float* __restrict__ emb,
                                                 __bf16* __restrict__ embb)
{
    int i = blockIdx.x*256 + threadIdx.x;
    int i4 = i*4;
    const int TOT = (N_NODES + 1) * EMBD;
    if (i4 >= TOT) return;
    float4 v = ld4(emb + i4);
    embb[i4+0] = (__bf16)v.x;
    embb[i4+1] = (__bf16)v.y;
    embb[i4+2] = (__bf16)v.z;
    embb[i4+3] = (__bf16)v.w;
}

// Pack combined weights into per-wave MFMA B-fragment layout:
// idx = ((((w*6 + kc)*4 + gt)*16 + c)*32 + ko
//   -> col g = gt*128 + w*16 + c, k = kc*32 + ko  (w in 0..7)
__global__ __launch_bounds__(256) void prep_wtp(const float* __restrict__ Wih,
                                                const float* __restrict__ Whh,
                                                __bf16* __restrict__ WTp)
{
    int idx = blockIdx.x*256 + threadIdx.x;
    if (idx >= KTOT*G4) return;
    int ko = idx & 31;
    int c  = (idx >> 5) & 15;
    int gt = (idx >> 9) & 3;
    int kc = (idx >> 11) % 6;
    int w  = idx / WSTRIDE;
    int g  = gt*HL + w*16 + c;
    int kk = kc*32 + ko;
    float v = (kk < EMBD) ? Wih[g*EMBD + kk] : Whh[g*HL + (kk - EMBD)];
    WTp[idx] = (__bf16)v;
}

__global__ __launch_bounds__(256) void prep_bias(const float* __restrict__ bi,
                                                 const float* __restrict__ bh,
                                                 float* __restrict__ bs)
{
    int i = blockIdx.x*256 + threadIdx.x;
    if (i < G4) bs[i] = bi[i] + bh[i];
}

// ---------------- fused LSTM (all 24 steps, MFMA bf16, register-resident weights) ----------------
// Block: 512 threads = 8 waves; wave w owns cols j in [w*16, w*16+16) for all 4 gates.
// Weights live in 96 VGPRs per lane, loaded ONCE. Per-step: LDS A-reads + MFMA + gates.
__global__ __launch_bounds__(512, 2) void lstm_fused(
    const int* __restrict__ tokens, const int* __restrict__ lengths,
    const __bf16* __restrict__ embb, const __bf16* __restrict__ WTp,
    const float* __restrict__ bsum, float* __restrict__ hlast)
{
    __shared__ __bf16 a_lds[ROWS][LDA];
    __shared__ int tok_lds[ROWS*SEQ_T];
    __shared__ int len_lds[ROWS];

    const int tid = threadIdx.x;
    const int n0  = blockIdx.x * ROWS;
    const int w   = tid >> 6;       // 0..7
    const int l   = tid & 63;
    const int l15 = l & 15, l4 = l >> 4;

    // stage tokens (coalesced; grid covers N_NODES exactly)
    #pragma unroll
    for (int i = 0; i < 4; ++i) {
        int idx = tid + 512*i;
        if (idx < ROWS*SEQ_T) tok_lds[idx] = tokens[n0*SEQ_T + idx];
    }
    if (tid < ROWS) len_lds[tid] = lengths[n0 + tid];

    // zero h region (cols 64..191)
    #pragma unroll
    for (int i = 0; i < 3; ++i) {
        int idx = tid + 512*i;
        if (idx < ROWS*16) {
            int row = idx >> 4, s = idx & 15;
            *reinterpret_cast<uint4*>(&a_lds[row][EMBD + s*8]) = make_uint4(0,0,0,0);
        }
    }

    float bias_v[4];
    #pragma unroll
    for (int gt = 0; gt < 4; ++gt)
        bias_v[gt] = bsum[gt*HL + w*16 + l15];

    // weights -> registers, once (24 KB per wave = 96 VGPRs per lane)
    bf16x8 wreg[6][4];
    {
        const __bf16* wbase = WTp + (size_t)w * WSTRIDE;
        #pragma unroll
        for (int kc = 0; kc < 6; ++kc)
            #pragma unroll
            for (int gt = 0; gt < 4; ++gt)
                wreg[kc][gt] = *reinterpret_cast<const bf16x8*>(
                    &wbase[(size_t)(((kc*4 + gt)*16 + l15)*32) + l4*8]);
    }

    f32x4 acc[RF][4];
    float c_reg[RF][4];
    {
        f32x4 zz = {0.f,0.f,0.f,0.f};
        #pragma unroll
        for (int rf = 0; rf < RF; ++rf) {
            #pragma unroll
            for (int gt = 0; gt < 4; ++gt) acc[rf][gt] = zz;
            #pragma unroll
            for (int r = 0; r < 4; ++r) c_reg[rf][r] = 0.f;
        }
    }

    for (int t = 0; t < SEQ_T; ++t) {
        // stage emb(t) into cols 0..63 (disjoint from h region)
        #pragma unroll
        for (int i = 0; i < 2; ++i) {
            int idx = tid + 512*i;
            if (idx < ROWS*8) {
                int row = idx >> 3, sl = idx & 7;
                int tok = tok_lds[row*SEQ_T + t];
                *reinterpret_cast<uint4*>(&a_lds[row][sl*8]) =
                    *reinterpret_cast<const uint4*>(&embb[(size_t)tok*EMBD + sl*8]);
            }
        }
        __syncthreads();   // emb(t) + h(t-1) ready

        #pragma unroll
        for (int kc = 0; kc < 6; ++kc)
            #pragma unroll
            for (int rf = 0; rf < RF; ++rf) {
                bf16x8 af = *reinterpret_cast<const bf16x8*>(
                    &a_lds[rf*16 + l15][kc*32 + l4*8]);
                #pragma unroll
                for (int gt = 0; gt < 4; ++gt)
                    acc[rf][gt] = __builtin_amdgcn_mfma_f32_16x16x32_bf16(
                        af, wreg[kc][gt], acc[rf][gt], 0, 0, 0);
            }
        __syncthreads();   // all a_lds reads of step t complete

        // epilogue: branch-free fast gates in fp32; c in regs; h -> bf16 into a_lds
        #pragma unroll
        for (int rf = 0; rf < RF; ++rf) {
            f32x4 zi4 = acc[rf][0], zf4 = acc[rf][1];
            f32x4 zg4 = acc[rf][2], zo4 = acc[rf][3];
            #pragma unroll
            for (int r = 0; r < 4; ++r) {
                int row = rf*16 + l4*4 + r;
                float zi = zi4[r] + bias_v[0];
                float zf = zf4[r] + bias_v[1];
                float zg = zg4[r] + bias_v[2];
                float zo = zo4[r] + bias_v[3];
                float cc = fsigm(zf)*c_reg[rf][r] + fsigm(zi)*ftanh(zg);
                c_reg[rf][r] = cc;
                float h = fsigm(zo)*ftanh(cc);
                int j = w*16 + l15;
                a_lds[row][EMBD + j] = (__bf16)h;
                if (t == len_lds[row] - 1)
                    __builtin_nontemporal_store(h, &hlast[(size_t)(n0 + row)*HL + j]);
            }
            f32x4 zz = {0.f,0.f,0.f,0.f};
            acc[rf][0] = zz; acc[rf][1] = zz; acc[rf][2] = zz; acc[rf][3] = zz;
        }
        // no barrier needed: next emb stage writes cols 0..63 only (fenced by the
        // post-k-loop barrier); next pre-k-loop barrier publishes the h writes.
    }
}

// ---------------- CSR build ----------------

__global__ __launch_bounds__(256) void count_deg(const int* __restrict__ dst,
                                                 const float* __restrict__ w,
                                                 int* __restrict__ cnt,
                                                 float* __restrict__ deg, int E)
{
    int e = blockIdx.x*256 + threadIdx.x;
    if (e < E) {
        int d = dst[e];
        atomicAdd(&cnt[d], 1);
        atomicAdd(&deg[d], w[e]);
    }
}

__global__ __launch_bounds__(256) void dinv_kernel(const float* __restrict__ deg,
                                                   float* __restrict__ dinv, int N)
{
    int n = blockIdx.x*256 + threadIdx.x;
    if (n < N) dinv[n] = rsqrtf(deg[n] + 1.0f);
}

__global__ __launch_bounds__(1024) void scan_kernel(const int* __restrict__ cnt,
                                                    int* __restrict__ row_start)
{
    __shared__ int part[1024];
    const int t = threadIdx.x;
    const int CH = (N_NODES + 1023) / 1024;   // 20
    int beg = t*CH, end = min(beg + CH, N_NODES);
    int s = 0;
    for (int i = beg; i < end; ++i) s += cnt[i];
    part[t] = s;
    __syncthreads();
    for (int off = 1; off < 1024; off <<= 1) {
        int v = (t >= off) ? part[t - off] : 0;
        __syncthreads();
        part[t] += v;
        __syncthreads();
    }
    int base = (t == 0) ? 0 : part[t - 1];
    for (int i = beg; i < end; ++i) { row_start[i] = base; base += cnt[i]; }
    if (t == 1023) row_start[N_NODES] = part[1023];
}

__global__ __launch_bounds__(256) void fill_csr(const int* __restrict__ src,
                                                const int* __restrict__ dst,
                                                const float* __restrict__ w,
                                                const float* __restrict__ dinv,
                                                const int* __restrict__ row_start,
                                                int* __restrict__ cursor,
                                                int* __restrict__ src_s,
                                                float* __restrict__ norm_s, int E)
{
    int e = blockIdx.x*256 + threadIdx.x;
    if (e >= E) return;
    int d = dst[e];
    int pos = row_start[d] + atomicAdd(&cursor[d], 1);
    int s = src[e];
    src_s[pos]  = s;
    norm_s[pos] = dinv[s] * w[e] * dinv[d];
}

// ---------------- GCN ----------------

__global__ __launch_bounds__(256) void gemm_nk128(const float* __restrict__ x,
                                                  const float* __restrict__ W,
                                                  float* __restrict__ y, int N)
{
    __shared__ float xs[64][HL];
    const int tid = threadIdx.x;
    const int n0 = blockIdx.x * 64;
    #pragma unroll
    for (int i = 0; i < 8; ++i) {
        int f = tid + 256*i;
        int row = f >> 5, part = f & 31;
        int n = n0 + row;
        float4 v = make_float4(0.f,0.f,0.f,0.f);
        if (n < N) v = ld4(x + (size_t)n*HL + part*4);
        st4(&xs[row][part*4], v);
    }
    __syncthreads();
    const int jg = tid & 31, rg = tid >> 5;
    const int j0 = jg*4;
    float4 acc[8];
    #pragma unroll
    for (int i = 0; i < 8; ++i) acc[i] = make_float4(0.f,0.f,0.f,0.f);
    #pragma unroll 4
    for (int k = 0; k < HL; ++k) {
        float4 wv = ld4(W + (size_t)k*HL + j0);
        #pragma unroll
        for (int i = 0; i < 8; ++i) {
            float xv = xs[rg + 8*i][k];
            FMA4(acc[i], xv, wv);
        }
    }
    #pragma unroll
    for (int i = 0; i < 8; ++i) {
        int n = n0 + rg + 8*i;
        if (n < N) st4(y + (size_t)n*HL + j0, acc[i]);
    }
}

__global__ __launch_bounds__(256) void gcn_gather(const int* __restrict__ row_start,
                                                  const int* __restrict__ src_s,
                                                  const float* __restrict__ norm_s,
                                                  const float* __restrict__ dinv,
                                                  const float* __restrict__ y,
                                                  const float* __restrict__ b,
                                                  float* __restrict__ out, int N)
{
    int gt = blockIdx.x*256 + threadIdx.x;
    int n = gt >> 6, lane = gt & 63;
    if (n >= N) return;
    const int beg = row_start[n], end = row_start[n+1];
    float2 acc = make_float2(0.f, 0.f);
    for (int p = beg; p < end; ++p) {
        int s = src_s[p];
        float nrm = norm_s[p];
        float2 v = ld2(y + (size_t)s*HL + lane*2);
        acc.x = fmaf(nrm, v.x, acc.x);
        acc.y = fmaf(nrm, v.y, acc.y);
    }
    float di = dinv[n];
    float sl = di*di;
    float2 vs = ld2(y + (size_t)n*HL + lane*2);
    acc.x = fmaf(sl, vs.x, acc.x);
    acc.y = fmaf(sl, vs.y, acc.y);
    float2 bb = ld2(b + lane*2);
    acc.x = fmaxf(acc.x + bb.x, 0.f);
    acc.y = fmaxf(acc.y + bb.y, 0.f);
    *(float2*)(out + (size_t)n*HL + lane*2) = acc;
}

__global__ __launch_bounds__(256) void fc_kernel(const float* __restrict__ x,
                                                 const float* __restrict__ W,
                                                 const float* __restrict__ b,
                                                 float* __restrict__ out, int N)
{
    __shared__ float xs[64][HL];
    const int tid = threadIdx.x;
    const int n0 = blockIdx.x * 64;
    #pragma unroll
    for (int i = 0; i < 8; ++i) {
        int f = tid + 256*i;
        int row = f >> 5, part = f & 31;
        int n = n0 + row;
        float4 v = make_float4(0.f,0.f,0.f,0.f);
        if (n < N) v = ld4(x + (size_t)n*HL + part*4);
        st4(&xs[row][part*4], v);
    }
    __syncthreads();
    const int o = tid & 15, rg = tid >> 4;
    float acc[4] = {0.f,0.f,0.f,0.f};
    #pragma unroll 4
    for (int k = 0; k < HL; ++k) {
        float wv = W[k*OUTF + o];
        #pragma unroll
        for (int i = 0; i < 4; ++i)
            acc[i] = fmaf(xs[rg + 16*i][k], wv, acc[i]);
    }
    float bb = b[o];
    #pragma unroll
    for (int i = 0; i < 4; ++i) {
        int n = n0 + rg + 16*i;
        if (n < N) out[(size_t)n*OUTF + o] = acc[i] + bb;
    }
}

extern "C" void kernel_launch(void* const* d_in, const int* in_sizes, int n_in,
                              void* d_out, int out_size, void* d_ws, size_t ws_size,
                              hipStream_t stream)
{
    const int*   x_tokens = (const int*)d_in[0];
    const int*   lengths  = (const int*)d_in[1];
    const int*   eidx     = (const int*)d_in[2];
    const float* ew       = (const float*)d_in[3];
    const float* emb      = (const float*)d_in[4];
    const float* W_ih     = (const float*)d_in[5];
    const float* W_hh     = (const float*)d_in[6];
    const float* b_ih     = (const float*)d_in[7];
    const float* b_hh     = (const float*)d_in[8];
    const float* c1W      = (const float*)d_in[9];
    const float* c1b      = (const float*)d_in[10];
    const float* c2W      = (const float*)d_in[11];
    const float* c2b      = (const float*)d_in[12];
    const float* fcW      = (const float*)d_in[13];
    const float* fcb      = (const float*)d_in[14];
    float* out = (float*)d_out;

    const int* esrc = eidx;
    const int* edst = eidx + NEDGE;

    char* ws = (char*)d_ws;
    size_t off = 0;
    auto take = [&](size_t bytes) -> char* {
        char* p = ws + off;
        off = (off + bytes + 255) & ~(size_t)255;
        return p;
    };
    const size_t NH = (size_t)N_NODES * HL * sizeof(float);
    __bf16* embb = (__bf16*)take((size_t)(N_NODES + 1) * EMBD * sizeof(__bf16));
    __bf16* WTp  = (__bf16*)take((size_t)KTOT * G4 * sizeof(__bf16));
    float* bsum  = (float*)take((size_t)G4 * sizeof(float));
    float* hLst  = (float*)take(NH);
    float* yb    = (float*)take(NH);
    float* x2    = (float*)take(NH);
    float* x3    = (float*)take(NH);
    float* degb  = (float*)take((size_t)N_NODES * sizeof(float));
    float* dinvb = (float*)take((size_t)N_NODES * sizeof(float));
    int*   cntb  = (int*)  take((size_t)N_NODES * sizeof(int));
    int*   rowst = (int*)  take((size_t)(N_NODES + 1) * sizeof(int));
    int*   curs  = (int*)  take((size_t)N_NODES * sizeof(int));
    int*   srcS  = (int*)  take((size_t)NEDGE * sizeof(int));
    float* nrmS  = (float*)take((size_t)NEDGE * sizeof(float));

    hipMemsetAsync(degb, 0, (size_t)N_NODES * sizeof(float), stream);
    hipMemsetAsync(cntb, 0, (size_t)N_NODES * sizeof(int), stream);
    hipMemsetAsync(curs, 0, (size_t)N_NODES * sizeof(int), stream);

    prep_embb<<<(((N_NODES+1)*EMBD/4) + 255)/256, 256, 0, stream>>>(emb, embb);
    prep_wtp<<<(KTOT*G4 + 255)/256, 256, 0, stream>>>(W_ih, W_hh, WTp);
    prep_bias<<<2, 256, 0, stream>>>(b_ih, b_hh, bsum);

    count_deg<<<NEDGE/256, 256, 0, stream>>>(edst, ew, cntb, degb, NEDGE);
    dinv_kernel<<<(N_NODES + 255)/256, 256, 0, stream>>>(degb, dinvb, N_NODES);
    scan_kernel<<<1, 1024, 0, stream>>>(cntb, rowst);
    fill_csr<<<NEDGE/256, 256, 0, stream>>>(esrc, edst, ew, dinvb, rowst, curs,
                                            srcS, nrmS, NEDGE);

    lstm_fused<<<NBLSTM, 512, 0, stream>>>(x_tokens, lengths, embb, WTp, bsum, hLst);

    const int gemmBlocks = (N_NODES + 63)/64;
    const int gathBlocks = (N_NODES*64 + 255)/256;

    gemm_nk128<<<gemmBlocks, 256, 0, stream>>>(hLst, c1W, yb, N_NODES);
    gcn_gather<<<gathBlocks, 256, 0, stream>>>(rowst, srcS, nrmS, dinvb, yb, c1b, x2, N_NODES);
    gemm_nk128<<<gemmBlocks, 256, 0, stream>>>(x2, c2W, yb, N_NODES);
    gcn_gather<<<gathBlocks, 256, 0, stream>>>(rowst, srcS, nrmS, dinvb, yb, c2b, x3, N_NODES);
    fc_kernel<<<gemmBlocks, 256, 0, stream>>>(x3, fcW, fcb, out, N_NODES);
}

// Round 6
// 479.587 us; speedup vs baseline: 9.4520x; 1.0788x over previous
//
#include <hip/hip_runtime.h>
#include <math.h>

#define N_NODES 20000
#define SEQ_T   24
#define EMBD    64
#define HL      128     // H_LSTM
#define OUTF    16
#define NEDGE   640000
#define G4      512     // 4*HL
#define KTOT    192     // EMBD + HL
#define ROWS    80      // rows per LSTM block (250 * 80 = 20000 exactly)
#define RF      5       // ROWS/16 row-fragments
#define NBLSTM  250
#define EPAD    72      // ebuf row stride (144B = 9*16 -> conflict-free, 16B-aligned)
#define HPAD    136     // hbuf row stride (272B = 17*16 -> conflict-free, 16B-aligned)
#define WSTRIDE 12288   // per-wave weight chunk, elems: 6 kc * 4 gt * 16 c * 32 ko (24 KB)

typedef __bf16 bf16x8 __attribute__((ext_vector_type(8)));
typedef float  f32x4  __attribute__((ext_vector_type(4)));

__device__ __forceinline__ float4 ld4(const float* p){ return *reinterpret_cast<const float4*>(p); }
__device__ __forceinline__ void st4(float* p, float4 v){ *reinterpret_cast<float4*>(p) = v; }
__device__ __forceinline__ float2 ld2(const float* p){ return *reinterpret_cast<const float2*>(p); }

// fast gate math: v_exp_f32 computes 2^x; v_rcp_f32. Branch-free, ~1e-7 rel err.
#define LOG2E 1.44269504f
__device__ __forceinline__ float fsigm(float x){
    return __builtin_amdgcn_rcpf(1.0f + __builtin_amdgcn_exp2f(-LOG2E*x));
}
__device__ __forceinline__ float ftanh(float x){
    return 1.0f - 2.0f*__builtin_amdgcn_rcpf(1.0f + __builtin_amdgcn_exp2f(2.0f*LOG2E*x));
}

#define FMA4(A,S,B) {(A).x=fmaf((S),(B).x,(A).x);(A).y=fmaf((S),(B).y,(A).y);(A).z=fmaf((S),(B).z,(A).z);(A).w=fmaf((S),(B).w,(A).w);}

// ---------------- prep kernels ----------------

// emb (fp32, [20001][64]) -> bf16
__global__ __launch_bounds__(256) void prep_embb(const float* __restrict__ emb,
                                                 __bf16* __restrict__ embb)
{
    int i = blockIdx.x*256 + threadIdx.x;
    int i4 = i*4;
    const int TOT = (N_NODES + 1) * EMBD;
    if (i4 >= TOT) return;
    float4 v = ld4(emb + i4);
    embb[i4+0] = (__bf16)v.x;
    embb[i4+1] = (__bf16)v.y;
    embb[i4+2] = (__bf16)v.z;
    embb[i4+3] = (__bf16)v.w;
}

// Pack combined weights into per-wave MFMA B-fragment layout:
// idx = (((w*6 + kc)*4 + gt)*16 + c)*32 + ko
//   -> col g = gt*128 + w*16 + c, k = kc*32 + ko  (w in 0..7)
__global__ __launch_bounds__(256) void prep_wtp(const float* __restrict__ Wih,
                                                const float* __restrict__ Whh,
                                                __bf16* __restrict__ WTp)
{
    int idx = blockIdx.x*256 + threadIdx.x;
    if (idx >= KTOT*G4) return;
    int ko = idx & 31;
    int c  = (idx >> 5) & 15;
    int gt = (idx >> 9) & 3;
    int kc = (idx >> 11) % 6;
    int w  = idx / WSTRIDE;
    int g  = gt*HL + w*16 + c;
    int kk = kc*32 + ko;
    float v = (kk < EMBD) ? Wih[g*EMBD + kk] : Whh[g*HL + (kk - EMBD)];
    WTp[idx] = (__bf16)v;
}

__global__ __launch_bounds__(256) void prep_bias(const float* __restrict__ bi,
                                                 const float* __restrict__ bh,
                                                 float* __restrict__ bs)
{
    int i = blockIdx.x*256 + threadIdx.x;
    if (i < G4) bs[i] = bi[i] + bh[i];
}

// ---------------- fused LSTM: software-pipelined, 1 barrier/step ----------------
// 512 thr = 8 waves; wave w owns cols [w*16, w*16+16) of all 4 gates; weights in regs.
// Per step t: issue emb(t+1) gathers -> {per-rf: epilogue(t-1) || emb-MFMA(t)} ->
// stage-write emb(t+1) -> barrier -> h-MFMA(t). ebuf/hbuf padded conflict-free.

__device__ __forceinline__ void lstm_epilogue(
    int rf, int tmatch, __bf16 (* __restrict__ hb)[HPAD],
    const f32x4* accrf, float* crf, const float* bias_v,
    const int* len_lds, float* __restrict__ hlast,
    int n0, int w, int l15, int l4)
{
    f32x4 zi4 = accrf[0], zf4 = accrf[1], zg4 = accrf[2], zo4 = accrf[3];
    #pragma unroll
    for (int r = 0; r < 4; ++r) {
        int row = rf*16 + l4*4 + r;
        float zi = zi4[r] + bias_v[0];
        float zf = zf4[r] + bias_v[1];
        float zg = zg4[r] + bias_v[2];
        float zo = zo4[r] + bias_v[3];
        float cc = fsigm(zf)*crf[r] + fsigm(zi)*ftanh(zg);
        crf[r] = cc;
        float h = fsigm(zo)*ftanh(cc);
        int j = w*16 + l15;
        hb[row][j] = (__bf16)h;
        if (len_lds[row] == tmatch)
            __builtin_nontemporal_store(h, &hlast[(size_t)(n0 + row)*HL + j]);
    }
}

__global__ __launch_bounds__(512, 2) void lstm_fused(
    const int* __restrict__ tokens, const int* __restrict__ lengths,
    const __bf16* __restrict__ embb, const __bf16* __restrict__ WTp,
    const float* __restrict__ bsum, float* __restrict__ hlast)
{
    __shared__ __align__(16) __bf16 ebuf[2][ROWS][EPAD];
    __shared__ __align__(16) __bf16 hbuf[2][ROWS][HPAD];
    __shared__ int tok_lds[ROWS*SEQ_T];
    __shared__ int len_lds[ROWS];

    const int tid = threadIdx.x;
    const int n0  = blockIdx.x * ROWS;
    const int w   = tid >> 6;       // 0..7
    const int l   = tid & 63;
    const int l15 = l & 15, l4 = l >> 4;

    // stage tokens + lengths (coalesced)
    #pragma unroll
    for (int i = 0; i < 4; ++i) {
        int idx = tid + 512*i;
        if (idx < ROWS*SEQ_T) tok_lds[idx] = tokens[n0*SEQ_T + idx];
    }
    if (tid < ROWS) len_lds[tid] = lengths[n0 + tid];

    // zero hbuf[1] (h(-1) = 0), as uint4
    {
        uint4* hz = reinterpret_cast<uint4*>(&hbuf[1][0][0]);
        const int NZ = ROWS*HPAD*2/16;   // 1360
        #pragma unroll
        for (int i = 0; i < 3; ++i) {
            int idx = tid + 512*i;
            if (idx < NZ) hz[idx] = make_uint4(0,0,0,0);
        }
    }

    float bias_v[4];
    #pragma unroll
    for (int gt = 0; gt < 4; ++gt)
        bias_v[gt] = bsum[gt*HL + w*16 + l15];

    // weights -> registers, once (24 KB per wave = 96 VGPRs per lane)
    bf16x8 wreg[6][4];
    {
        const __bf16* wbase = WTp + (size_t)w * WSTRIDE;
        #pragma unroll
        for (int kc = 0; kc < 6; ++kc)
            #pragma unroll
            for (int gt = 0; gt < 4; ++gt)
                wreg[kc][gt] = *reinterpret_cast<const bf16x8*>(
                    &wbase[(size_t)(((kc*4 + gt)*16 + l15)*32) + l4*8]);
    }

    f32x4 acc[RF][4];
    float c_reg[RF][4];
    #pragma unroll
    for (int rf = 0; rf < RF; ++rf)
        #pragma unroll
        for (int r = 0; r < 4; ++r) c_reg[rf][r] = 0.f;

    // emb-stage thread mapping: slot = row*8 + sl (640 slots)
    const int row0 = tid >> 3, sl0 = tid & 7;                 // slots 0..511
    const int idx1 = tid + 512, row1 = idx1 >> 3, sl1 = idx1 & 7;
    const bool v1 = (idx1 < ROWS*8);                          // tid < 128

    __syncthreads();   // tok_lds/len_lds ready

    // stage emb(0) -> ebuf[0]
    {
        int tk0 = tok_lds[row0*SEQ_T + 0];
        *reinterpret_cast<uint4*>(&ebuf[0][row0][sl0*8]) =
            *reinterpret_cast<const uint4*>(&embb[(size_t)tk0*EMBD + sl0*8]);
        if (v1) {
            int tk1 = tok_lds[row1*SEQ_T + 0];
            *reinterpret_cast<uint4*>(&ebuf[0][row1][sl1*8]) =
                *reinterpret_cast<const uint4*>(&embb[(size_t)tk1*EMBD + sl1*8]);
        }
    }
    __syncthreads();   // ebuf[0] + hbuf[1] ready

    const f32x4 zero4 = {0.f, 0.f, 0.f, 0.f};

    for (int t = 0; t < SEQ_T; ++t) {
        const int cur = t & 1, nxt = cur ^ 1;

        // A: issue emb(t+1) gathers (latency hides under B)
        uint4 ev0, ev1;
        const bool has = (t + 1 < SEQ_T);
        if (has) {
            int tk0 = tok_lds[row0*SEQ_T + t + 1];
            ev0 = *reinterpret_cast<const uint4*>(&embb[(size_t)tk0*EMBD + sl0*8]);
            if (v1) {
                int tk1 = tok_lds[row1*SEQ_T + t + 1];
                ev1 = *reinterpret_cast<const uint4*>(&embb[(size_t)tk1*EMBD + sl1*8]);
            }
        }

        // B: per-rf {epilogue(t-1) [trans] || emb-MFMA(t)} — independent registers
        #pragma unroll
        for (int rf = 0; rf < RF; ++rf) {
            if (t > 0)
                lstm_epilogue(rf, t, hbuf[nxt], acc[rf], c_reg[rf], bias_v,
                              len_lds, hlast, n0, w, l15, l4);
            bf16x8 af0 = *reinterpret_cast<const bf16x8*>(&ebuf[cur][rf*16 + l15][l4*8]);
            bf16x8 af1 = *reinterpret_cast<const bf16x8*>(&ebuf[cur][rf*16 + l15][32 + l4*8]);
            #pragma unroll
            for (int gt = 0; gt < 4; ++gt) {
                acc[rf][gt] = __builtin_amdgcn_mfma_f32_16x16x32_bf16(af0, wreg[0][gt], zero4, 0, 0, 0);
                acc[rf][gt] = __builtin_amdgcn_mfma_f32_16x16x32_bf16(af1, wreg[1][gt], acc[rf][gt], 0, 0, 0);
            }
        }

        // C: stage-write emb(t+1) -> ebuf[nxt]
        if (has) {
            *reinterpret_cast<uint4*>(&ebuf[nxt][row0][sl0*8]) = ev0;
            if (v1) *reinterpret_cast<uint4*>(&ebuf[nxt][row1][sl1*8]) = ev1;
        }

        __syncthreads();   // publishes h(t-1) (from B) and ebuf[nxt]

        // E: h-MFMA(t) on hbuf[nxt] = h(t-1)
        #pragma unroll
        for (int kc = 0; kc < 4; ++kc)
            #pragma unroll
            for (int rf = 0; rf < RF; ++rf) {
                bf16x8 af = *reinterpret_cast<const bf16x8*>(
                    &hbuf[nxt][rf*16 + l15][kc*32 + l4*8]);
                #pragma unroll
                for (int gt = 0; gt < 4; ++gt)
                    acc[rf][gt] = __builtin_amdgcn_mfma_f32_16x16x32_bf16(
                        af, wreg[kc + 2][gt], acc[rf][gt], 0, 0, 0);
            }
    }

    // final epilogue (t = 23): hbuf[1] is safe (last read at E(22), fenced by D(23))
    #pragma unroll
    for (int rf = 0; rf < RF; ++rf)
        lstm_epilogue(rf, SEQ_T, hbuf[1], acc[rf], c_reg[rf], bias_v,
                      len_lds, hlast, n0, w, l15, l4);
}

// ---------------- CSR build ----------------

__global__ __launch_bounds__(256) void count_deg(const int* __restrict__ dst,
                                                 const float* __restrict__ w,
                                                 int* __restrict__ cnt,
                                                 float* __restrict__ deg, int E)
{
    int e = blockIdx.x*256 + threadIdx.x;
    if (e < E) {
        int d = dst[e];
        atomicAdd(&cnt[d], 1);
        atomicAdd(&deg[d], w[e]);
    }
}

__global__ __launch_bounds__(256) void dinv_kernel(const float* __restrict__ deg,
                                                   float* __restrict__ dinv, int N)
{
    int n = blockIdx.x*256 + threadIdx.x;
    if (n < N) dinv[n] = rsqrtf(deg[n] + 1.0f);
}

__global__ __launch_bounds__(1024) void scan_kernel(const int* __restrict__ cnt,
                                                    int* __restrict__ row_start)
{
    __shared__ int part[1024];
    const int t = threadIdx.x;
    const int CH = (N_NODES + 1023) / 1024;   // 20
    int beg = t*CH, end = min(beg + CH, N_NODES);
    int s = 0;
    for (int i = beg; i < end; ++i) s += cnt[i];
    part[t] = s;
    __syncthreads();
    for (int off = 1; off < 1024; off <<= 1) {
        int v = (t >= off) ? part[t - off] : 0;
        __syncthreads();
        part[t] += v;
        __syncthreads();
    }
    int base = (t == 0) ? 0 : part[t - 1];
    for (int i = beg; i < end; ++i) { row_start[i] = base; base += cnt[i]; }
    if (t == 1023) row_start[N_NODES] = part[1023];
}

__global__ __launch_bounds__(256) void fill_csr(const int* __restrict__ src,
                                                const int* __restrict__ dst,
                                                const float* __restrict__ w,
                                                const float* __restrict__ dinv,
                                                const int* __restrict__ row_start,
                                                int* __restrict__ cursor,
                                                int* __restrict__ src_s,
                                                float* __restrict__ norm_s, int E)
{
    int e = blockIdx.x*256 + threadIdx.x;
    if (e >= E) return;
    int d = dst[e];
    int pos = row_start[d] + atomicAdd(&cursor[d], 1);
    int s = src[e];
    src_s[pos]  = s;
    norm_s[pos] = dinv[s] * w[e] * dinv[d];
}

// ---------------- GCN ----------------

__global__ __launch_bounds__(256) void gemm_nk128(const float* __restrict__ x,
                                                  const float* __restrict__ W,
                                                  float* __restrict__ y, int N)
{
    __shared__ float xs[64][HL];
    const int tid = threadIdx.x;
    const int n0 = blockIdx.x * 64;
    #pragma unroll
    for (int i = 0; i < 8; ++i) {
        int f = tid + 256*i;
        int row = f >> 5, part = f & 31;
        int n = n0 + row;
        float4 v = make_float4(0.f,0.f,0.f,0.f);
        if (n < N) v = ld4(x + (size_t)n*HL + part*4);
        st4(&xs[row][part*4], v);
    }
    __syncthreads();
    const int jg = tid & 31, rg = tid >> 5;
    const int j0 = jg*4;
    float4 acc[8];
    #pragma unroll
    for (int i = 0; i < 8; ++i) acc[i] = make_float4(0.f,0.f,0.f,0.f);
    #pragma unroll 4
    for (int k = 0; k < HL; ++k) {
        float4 wv = ld4(W + (size_t)k*HL + j0);
        #pragma unroll
        for (int i = 0; i < 8; ++i) {
            float xv = xs[rg + 8*i][k];
            FMA4(acc[i], xv, wv);
        }
    }
    #pragma unroll
    for (int i = 0; i < 8; ++i) {
        int n = n0 + rg + 8*i;
        if (n < N) st4(y + (size_t)n*HL + j0, acc[i]);
    }
}

// Fused GCN aggregation, 4-deep unrolled gather for memory-level parallelism.
__global__ __launch_bounds__(256) void gcn_gather(const int* __restrict__ row_start,
                                                  const int* __restrict__ src_s,
                                                  const float* __restrict__ norm_s,
                                                  const float* __restrict__ dinv,
                                                  const float* __restrict__ y,
                                                  const float* __restrict__ b,
                                                  float* __restrict__ out, int N)
{
    int gt = blockIdx.x*256 + threadIdx.x;
    int n = gt >> 6, lane = gt & 63;
    if (n >= N) return;
    const int beg = row_start[n], end = row_start[n+1];
    float2 acc = make_float2(0.f, 0.f);
    int p = beg;
    for (; p + 4 <= end; p += 4) {
        int   s0 = src_s[p+0], s1 = src_s[p+1], s2 = src_s[p+2], s3 = src_s[p+3];
        float w0 = norm_s[p+0], w1 = norm_s[p+1], w2 = norm_s[p+2], w3 = norm_s[p+3];
        float2 v0 = ld2(y + (size_t)s0*HL + lane*2);
        float2 v1 = ld2(y + (size_t)s1*HL + lane*2);
        float2 v2 = ld2(y + (size_t)s2*HL + lane*2);
        float2 v3 = ld2(y + (size_t)s3*HL + lane*2);
        acc.x = fmaf(w0, v0.x, acc.x); acc.y = fmaf(w0, v0.y, acc.y);
        acc.x = fmaf(w1, v1.x, acc.x); acc.y = fmaf(w1, v1.y, acc.y);
        acc.x = fmaf(w2, v2.x, acc.x); acc.y = fmaf(w2, v2.y, acc.y);
        acc.x = fmaf(w3, v3.x, acc.x); acc.y = fmaf(w3, v3.y, acc.y);
    }
    for (; p < end; ++p) {
        int s = src_s[p];
        float nrm = norm_s[p];
        float2 v = ld2(y + (size_t)s*HL + lane*2);
        acc.x = fmaf(nrm, v.x, acc.x);
        acc.y = fmaf(nrm, v.y, acc.y);
    }
    float di = dinv[n];
    float sl = di*di;
    float2 vs = ld2(y + (size_t)n*HL + lane*2);
    acc.x = fmaf(sl, vs.x, acc.x);
    acc.y = fmaf(sl, vs.y, acc.y);
    float2 bb = ld2(b + lane*2);
    acc.x = fmaxf(acc.x + bb.x, 0.f);
    acc.y = fmaxf(acc.y + bb.y, 0.f);
    *(float2*)(out + (size_t)n*HL + lane*2) = acc;
}

__global__ __launch_bounds__(256) void fc_kernel(const float* __restrict__ x,
                                                 const float* __restrict__ W,
                                                 const float* __restrict__ b,
                                                 float* __restrict__ out, int N)
{
    __shared__ float xs[64][HL];
    const int tid = threadIdx.x;
    const int n0 = blockIdx.x * 64;
    #pragma unroll
    for (int i = 0; i < 8; ++i) {
        int f = tid + 256*i;
        int row = f >> 5, part = f & 31;
        int n = n0 + row;
        float4 v = make_float4(0.f,0.f,0.f,0.f);
        if (n < N) v = ld4(x + (size_t)n*HL + part*4);
        st4(&xs[row][part*4], v);
    }
    __syncthreads();
    const int o = tid & 15, rg = tid >> 4;
    float acc[4] = {0.f,0.f,0.f,0.f};
    #pragma unroll 4
    for (int k = 0; k < HL; ++k) {
        float wv = W[k*OUTF + o];
        #pragma unroll
        for (int i = 0; i < 4; ++i)
            acc[i] = fmaf(xs[rg + 16*i][k], wv, acc[i]);
    }
    float bb = b[o];
    #pragma unroll
    for (int i = 0; i < 4; ++i) {
        int n = n0 + rg + 16*i;
        if (n < N) out[(size_t)n*OUTF + o] = acc[i] + bb;
    }
}

extern "C" void kernel_launch(void* const* d_in, const int* in_sizes, int n_in,
                              void* d_out, int out_size, void* d_ws, size_t ws_size,
                              hipStream_t stream)
{
    const int*   x_tokens = (const int*)d_in[0];
    const int*   lengths  = (const int*)d_in[1];
    const int*   eidx     = (const int*)d_in[2];
    const float* ew       = (const float*)d_in[3];
    const float* emb      = (const float*)d_in[4];
    const float* W_ih     = (const float*)d_in[5];
    const float* W_hh     = (const float*)d_in[6];
    const float* b_ih     = (const float*)d_in[7];
    const float* b_hh     = (const float*)d_in[8];
    const float* c1W      = (const float*)d_in[9];
    const float* c1b      = (const float*)d_in[10];
    const float* c2W      = (const float*)d_in[11];
    const float* c2b      = (const float*)d_in[12];
    const float* fcW      = (const float*)d_in[13];
    const float* fcb      = (const float*)d_in[14];
    float* out = (float*)d_out;

    const int* esrc = eidx;
    const int* edst = eidx + NEDGE;

    char* ws = (char*)d_ws;
    size_t off = 0;
    auto take = [&](size_t bytes) -> char* {
        char* p = ws + off;
        off = (off + bytes + 255) & ~(size_t)255;
        return p;
    };
    const size_t NH = (size_t)N_NODES * HL * sizeof(float);
    __bf16* embb = (__bf16*)take((size_t)(N_NODES + 1) * EMBD * sizeof(__bf16));
    __bf16* WTp  = (__bf16*)take((size_t)KTOT * G4 * sizeof(__bf16));
    float* bsum  = (float*)take((size_t)G4 * sizeof(float));
    float* hLst  = (float*)take(NH);
    float* yb    = (float*)take(NH);
    float* x2    = (float*)take(NH);
    float* x3    = (float*)take(NH);
    float* degb  = (float*)take((size_t)N_NODES * sizeof(float));
    float* dinvb = (float*)take((size_t)N_NODES * sizeof(float));
    int*   cntb  = (int*)  take((size_t)N_NODES * sizeof(int));
    int*   rowst = (int*)  take((size_t)(N_NODES + 1) * sizeof(int));
    int*   curs  = (int*)  take((size_t)N_NODES * sizeof(int));
    int*   srcS  = (int*)  take((size_t)NEDGE * sizeof(int));
    float* nrmS  = (float*)take((size_t)NEDGE * sizeof(float));

    hipMemsetAsync(degb, 0, (size_t)N_NODES * sizeof(float), stream);
    hipMemsetAsync(cntb, 0, (size_t)N_NODES * sizeof(int), stream);
    hipMemsetAsync(curs, 0, (size_t)N_NODES * sizeof(int), stream);

    prep_embb<<<(((N_NODES+1)*EMBD/4) + 255)/256, 256, 0, stream>>>(emb, embb);
    prep_wtp<<<(KTOT*G4 + 255)/256, 256, 0, stream>>>(W_ih, W_hh, WTp);
    prep_bias<<<2, 256, 0, stream>>>(b_ih, b_hh, bsum);

    count_deg<<<NEDGE/256, 256, 0, stream>>>(edst, ew, cntb, degb, NEDGE);
    dinv_kernel<<<(N_NODES + 255)/256, 256, 0, stream>>>(degb, dinvb, N_NODES);
    scan_kernel<<<1, 1024, 0, stream>>>(cntb, rowst);
    fill_csr<<<NEDGE/256, 256, 0, stream>>>(esrc, edst, ew, dinvb, rowst, curs,
                                            srcS, nrmS, NEDGE);

    lstm_fused<<<NBLSTM, 512, 0, stream>>>(x_tokens, lengths, embb, WTp, bsum, hLst);

    const int gemmBlocks = (N_NODES + 63)/64;
    const int gathBlocks = (N_NODES*64 + 255)/256;

    gemm_nk128<<<gemmBlocks, 256, 0, stream>>>(hLst, c1W, yb, N_NODES);
    gcn_gather<<<gathBlocks, 256, 0, stream>>>(rowst, srcS, nrmS, dinvb, yb, c1b, x2, N_NODES);
    gemm_nk128<<<gemmBlocks, 256, 0, stream>>>(x2, c2W, yb, N_NODES);
    gcn_gather<<<gathBlocks, 256, 0, stream>>>(rowst, srcS, nrmS, dinvb, yb, c2b, x3, N_NODES);
    fc_kernel<<<gemmBlocks, 256, 0, stream>>>(x3, fcW, fcb, out, N_NODES);
}

// Round 7
// 468.480 us; speedup vs baseline: 9.6761x; 1.0237x over previous
//
#include <hip/hip_runtime.h>
#include <math.h>

#define N_NODES 20000
#define SEQ_T   24
#define EMBD    64
#define HL      128     // H_LSTM
#define OUTF    16
#define NEDGE   640000
#define G4      512     // 4*HL
#define KTOT    192     // EMBD + HL
#define ROWS    80      // rows per LSTM block (250 * 80 = 20000 exactly, 1 block/CU)
#define RF      5       // ROWS/16 row-fragments
#define NBLSTM  250
#define EPAD    72      // ebuf row stride (144B: row r starts at bank 4r mod 32 -> 8-lane groups tile banks)
#define HPAD    136     // hbuf row stride (272B: same property)
#define WSTRIDE 12288   // per-wave weight chunk, elems: 6 kc * 4 gt * 16 c * 32 ko (24 KB)

typedef __bf16 bf16x8 __attribute__((ext_vector_type(8)));
typedef float  f32x4  __attribute__((ext_vector_type(4)));

__device__ __forceinline__ float4 ld4(const float* p){ return *reinterpret_cast<const float4*>(p); }
__device__ __forceinline__ void st4(float* p, float4 v){ *reinterpret_cast<float4*>(p) = v; }
__device__ __forceinline__ float2 ld2(const float* p){ return *reinterpret_cast<const float2*>(p); }

#define LOG2E 1.44269504f

#define FMA4(A,S,B) {(A).x=fmaf((S),(B).x,(A).x);(A).y=fmaf((S),(B).y,(A).y);(A).z=fmaf((S),(B).z,(A).z);(A).w=fmaf((S),(B).w,(A).w);}

// ---------------- prep kernels ----------------

// emb (fp32, [20001][64]) -> bf16
__global__ __launch_bounds__(256) void prep_embb(const float* __restrict__ emb,
                                                 __bf16* __restrict__ embb)
{
    int i = blockIdx.x*256 + threadIdx.x;
    int i4 = i*4;
    const int TOT = (N_NODES + 1) * EMBD;
    if (i4 >= TOT) return;
    float4 v = ld4(emb + i4);
    embb[i4+0] = (__bf16)v.x;
    embb[i4+1] = (__bf16)v.y;
    embb[i4+2] = (__bf16)v.z;
    embb[i4+3] = (__bf16)v.w;
}

// Pack combined weights into per-wave MFMA B-fragment layout:
// idx = (((w*6 + kc)*4 + gt)*16 + c)*32 + ko
//   -> col g = gt*128 + w*16 + c, k = kc*32 + ko  (w in 0..7)
__global__ __launch_bounds__(256) void prep_wtp(const float* __restrict__ Wih,
                                                const float* __restrict__ Whh,
                                                __bf16* __restrict__ WTp)
{
    int idx = blockIdx.x*256 + threadIdx.x;
    if (idx >= KTOT*G4) return;
    int ko = idx & 31;
    int c  = (idx >> 5) & 15;
    int gt = (idx >> 9) & 3;
    int kc = (idx >> 11) % 6;
    int w  = idx / WSTRIDE;
    int g  = gt*HL + w*16 + c;
    int kk = kc*32 + ko;
    float v = (kk < EMBD) ? Wih[g*EMBD + kk] : Whh[g*HL + (kk - EMBD)];
    WTp[idx] = (__bf16)v;
}

__global__ __launch_bounds__(256) void prep_bias(const float* __restrict__ bi,
                                                 const float* __restrict__ bh,
                                                 float* __restrict__ bs)
{
    int i = blockIdx.x*256 + threadIdx.x;
    if (i < G4) bs[i] = bi[i] + bh[i];
}

// ---------------- fused LSTM: per-rf phase pipeline, 6 barriers/step ----------------
// 512 thr = 8 waves; wave w owns cols [w*16, w*16+16) of all 4 gates; weights in regs.
// Phase rf: h-MFMA(t,rf) [matrix pipe] runs concurrently with epilogue(t-1,rf+1)
// [trans pipe] + emb-MFMA(t,rf+1). Epilogue writes h rows (rf+1)*16.. while h-MFMA
// reads rows rf*16.. (disjoint); per-phase barrier publishes.

// 8-trans epilogue: sig(a)*tanh(b) = (e^{2b}-1) * rcp((1+e^{-a})(e^{2b}+1))
__device__ __forceinline__ void lstm_epilogue(
    int rf, int tmatch, __bf16 (* __restrict__ hb)[HPAD],
    const f32x4* accrf, float* crf, const float* bias_v,
    const int* len_lds, float* __restrict__ hlast,
    int n0, int w, int l15, int l4)
{
    f32x4 zi4 = accrf[0], zf4 = accrf[1], zg4 = accrf[2], zo4 = accrf[3];
    #pragma unroll
    for (int r = 0; r < 4; ++r) {
        int row = rf*16 + l4*4 + r;
        float zi = zi4[r] + bias_v[0];
        float zf = zf4[r] + bias_v[1];
        float zg = zg4[r] + bias_v[2];
        float zo = zo4[r] + bias_v[3];
        float ef = __builtin_amdgcn_exp2f(-LOG2E*zf);
        float ei = __builtin_amdgcn_exp2f(-LOG2E*zi);
        float eg = __builtin_amdgcn_exp2f(2.0f*LOG2E*zg);
        float sf  = __builtin_amdgcn_rcpf(1.0f + ef);
        float rig = __builtin_amdgcn_rcpf((1.0f + ei)*(eg + 1.0f));
        float cc = sf*crf[r] + (eg - 1.0f)*rig;
        crf[r] = cc;
        float eo = __builtin_amdgcn_exp2f(-LOG2E*zo);
        float ec = __builtin_amdgcn_exp2f(2.0f*LOG2E*cc);
        float rh = __builtin_amdgcn_rcpf((1.0f + eo)*(ec + 1.0f));
        float h = (ec - 1.0f)*rh;
        int j = w*16 + l15;
        hb[row][j] = (__bf16)h;
        if (len_lds[row] == tmatch)
            __builtin_nontemporal_store(h, &hlast[(size_t)(n0 + row)*HL + j]);
    }
}

__global__ __launch_bounds__(512, 2) void lstm_fused(
    const int* __restrict__ tokens, const int* __restrict__ lengths,
    const __bf16* __restrict__ embb, const __bf16* __restrict__ WTp,
    const float* __restrict__ bsum, float* __restrict__ hlast)
{
    __shared__ __align__(16) __bf16 ebuf[2][ROWS][EPAD];
    __shared__ __align__(16) __bf16 hbuf[2][ROWS][HPAD];
    __shared__ int tok_lds[ROWS*SEQ_T];
    __shared__ int len_lds[ROWS];

    const int tid = threadIdx.x;
    const int n0  = blockIdx.x * ROWS;
    const int w   = tid >> 6;       // 0..7
    const int l   = tid & 63;
    const int l15 = l & 15, l4 = l >> 4;

    // stage tokens + lengths (coalesced)
    #pragma unroll
    for (int i = 0; i < 4; ++i) {
        int idx = tid + 512*i;
        if (idx < ROWS*SEQ_T) tok_lds[idx] = tokens[n0*SEQ_T + idx];
    }
    if (tid < ROWS) len_lds[tid] = lengths[n0 + tid];

    // zero hbuf[1] (h(-1) = 0)
    {
        uint4* hz = reinterpret_cast<uint4*>(&hbuf[1][0][0]);
        const int NZ = ROWS*HPAD*2/16;   // 1360
        #pragma unroll
        for (int i = 0; i < 3; ++i) {
            int idx = tid + 512*i;
            if (idx < NZ) hz[idx] = make_uint4(0,0,0,0);
        }
    }

    float bias_v[4];
    #pragma unroll
    for (int gt = 0; gt < 4; ++gt)
        bias_v[gt] = bsum[gt*HL + w*16 + l15];

    // weights -> registers, once (24 KB per wave = 96 VGPRs per lane)
    bf16x8 wreg[6][4];
    {
        const __bf16* wbase = WTp + (size_t)w * WSTRIDE;
        #pragma unroll
        for (int kc = 0; kc < 6; ++kc)
            #pragma unroll
            for (int gt = 0; gt < 4; ++gt)
                wreg[kc][gt] = *reinterpret_cast<const bf16x8*>(
                    &wbase[(size_t)(((kc*4 + gt)*16 + l15)*32) + l4*8]);
    }

    f32x4 acc[RF][4];
    float c_reg[RF][4];
    #pragma unroll
    for (int rf = 0; rf < RF; ++rf)
        #pragma unroll
        for (int r = 0; r < 4; ++r) c_reg[rf][r] = 0.f;

    // emb-stage thread mapping: slot = row*8 + sl (640 slots)
    const int row0 = tid >> 3, sl0 = tid & 7;                 // slots 0..511
    const int idx1 = tid + 512, row1 = idx1 >> 3, sl1 = idx1 & 7;
    const bool v1 = (idx1 < ROWS*8);                          // tid < 128

    __syncthreads();   // tok_lds/len_lds ready

    // stage emb(0) -> ebuf[0]
    {
        int tk0 = tok_lds[row0*SEQ_T + 0];
        *reinterpret_cast<uint4*>(&ebuf[0][row0][sl0*8]) =
            *reinterpret_cast<const uint4*>(&embb[(size_t)tk0*EMBD + sl0*8]);
        if (v1) {
            int tk1 = tok_lds[row1*SEQ_T + 0];
            *reinterpret_cast<uint4*>(&ebuf[0][row1][sl1*8]) =
                *reinterpret_cast<const uint4*>(&embb[(size_t)tk1*EMBD + sl1*8]);
        }
    }
    __syncthreads();   // ebuf[0] + hbuf[1] ready

    const f32x4 zero4 = {0.f, 0.f, 0.f, 0.f};

    for (int t = 0; t < SEQ_T; ++t) {
        const int cur = t & 1, nxt = cur ^ 1;
        const bool has = (t + 1 < SEQ_T);

        // issue emb(t+1) gathers (latency hides under the whole step)
        uint4 ev0, ev1;
        if (has) {
            int tk0 = tok_lds[row0*SEQ_T + t + 1];
            ev0 = *reinterpret_cast<const uint4*>(&embb[(size_t)tk0*EMBD + sl0*8]);
            if (v1) {
                int tk1 = tok_lds[row1*SEQ_T + t + 1];
                ev1 = *reinterpret_cast<const uint4*>(&embb[(size_t)tk1*EMBD + sl1*8]);
            }
        }

        // ---- P0: ep(t-1, rf=0) [trans] || emb-MFMA(t, rf=0)
        {
            bf16x8 af0 = *reinterpret_cast<const bf16x8*>(&ebuf[cur][l15][l4*8]);
            bf16x8 af1 = *reinterpret_cast<const bf16x8*>(&ebuf[cur][l15][32 + l4*8]);
            if (t > 0)
                lstm_epilogue(0, t, hbuf[nxt], acc[0], c_reg[0], bias_v,
                              len_lds, hlast, n0, w, l15, l4);
            #pragma unroll
            for (int gt = 0; gt < 4; ++gt) {
                acc[0][gt] = __builtin_amdgcn_mfma_f32_16x16x32_bf16(af0, wreg[0][gt], zero4, 0, 0, 0);
                acc[0][gt] = __builtin_amdgcn_mfma_f32_16x16x32_bf16(af1, wreg[1][gt], acc[0][gt], 0, 0, 0);
            }
        }
        __syncthreads();   // publishes h rows 0-15 (ep0)

        // ---- phases rf = 0..4: h-MFMA(rf) || { ep(rf+1) + emb-MFMA(rf+1) }
        #pragma unroll
        for (int rf = 0; rf < RF; ++rf) {
            bf16x8 hf[4];
            #pragma unroll
            for (int kc = 0; kc < 4; ++kc)
                hf[kc] = *reinterpret_cast<const bf16x8*>(
                    &hbuf[nxt][rf*16 + l15][kc*32 + l4*8]);

            if (rf + 1 < RF) {
                bf16x8 af0 = *reinterpret_cast<const bf16x8*>(&ebuf[cur][(rf+1)*16 + l15][l4*8]);
                bf16x8 af1 = *reinterpret_cast<const bf16x8*>(&ebuf[cur][(rf+1)*16 + l15][32 + l4*8]);
                if (t > 0)
                    lstm_epilogue(rf + 1, t, hbuf[nxt], acc[rf+1], c_reg[rf+1], bias_v,
                                  len_lds, hlast, n0, w, l15, l4);
                // h-MFMA(rf): independent of the epilogue -> overlaps trans chain
                #pragma unroll
                for (int kc = 0; kc < 4; ++kc)
                    #pragma unroll
                    for (int gt = 0; gt < 4; ++gt)
                        acc[rf][gt] = __builtin_amdgcn_mfma_f32_16x16x32_bf16(
                            hf[kc], wreg[kc + 2][gt], acc[rf][gt], 0, 0, 0);
                // emb-MFMA(rf+1) re-initializes acc[rf+1] (C=0) after ep consumed it
                #pragma unroll
                for (int gt = 0; gt < 4; ++gt) {
                    acc[rf+1][gt] = __builtin_amdgcn_mfma_f32_16x16x32_bf16(af0, wreg[0][gt], zero4, 0, 0, 0);
                    acc[rf+1][gt] = __builtin_amdgcn_mfma_f32_16x16x32_bf16(af1, wreg[1][gt], acc[rf+1][gt], 0, 0, 0);
                }
            } else {
                #pragma unroll
                for (int kc = 0; kc < 4; ++kc)
                    #pragma unroll
                    for (int gt = 0; gt < 4; ++gt)
                        acc[rf][gt] = __builtin_amdgcn_mfma_f32_16x16x32_bf16(
                            hf[kc], wreg[kc + 2][gt], acc[rf][gt], 0, 0, 0);
                // stage-write emb(t+1) -> ebuf[nxt] (readers fenced by end-of-step barrier)
                if (has) {
                    *reinterpret_cast<uint4*>(&ebuf[nxt][row0][sl0*8]) = ev0;
                    if (v1) *reinterpret_cast<uint4*>(&ebuf[nxt][row1][sl1*8]) = ev1;
                }
            }
            __syncthreads();
        }
    }

    // final epilogue (t = 23): cur(23)=1 -> nxt=0; hbuf[0] rows are dead, safe target
    #pragma unroll
    for (int rf = 0; rf < RF; ++rf)
        lstm_epilogue(rf, SEQ_T, hbuf[0], acc[rf], c_reg[rf], bias_v,
                      len_lds, hlast, n0, w, l15, l4);
}

// ---------------- CSR build ----------------

__global__ __launch_bounds__(256) void count_deg(const int* __restrict__ dst,
                                                 const float* __restrict__ w,
                                                 int* __restrict__ cnt,
                                                 float* __restrict__ deg, int E)
{
    int e = blockIdx.x*256 + threadIdx.x;
    if (e < E) {
        int d = dst[e];
        atomicAdd(&cnt[d], 1);
        atomicAdd(&deg[d], w[e]);
    }
}

__global__ __launch_bounds__(256) void dinv_kernel(const float* __restrict__ deg,
                                                   float* __restrict__ dinv, int N)
{
    int n = blockIdx.x*256 + threadIdx.x;
    if (n < N) dinv[n] = rsqrtf(deg[n] + 1.0f);
}

__global__ __launch_bounds__(1024) void scan_kernel(const int* __restrict__ cnt,
                                                    int* __restrict__ row_start)
{
    __shared__ int part[1024];
    const int t = threadIdx.x;
    const int CH = (N_NODES + 1023) / 1024;   // 20
    int beg = t*CH, end = min(beg + CH, N_NODES);
    int s = 0;
    for (int i = beg; i < end; ++i) s += cnt[i];
    part[t] = s;
    __syncthreads();
    for (int off = 1; off < 1024; off <<= 1) {
        int v = (t >= off) ? part[t - off] : 0;
        __syncthreads();
        part[t] += v;
        __syncthreads();
    }
    int base = (t == 0) ? 0 : part[t - 1];
    for (int i = beg; i < end; ++i) { row_start[i] = base; base += cnt[i]; }
    if (t == 1023) row_start[N_NODES] = part[1023];
}

__global__ __launch_bounds__(256) void fill_csr(const int* __restrict__ src,
                                                const int* __restrict__ dst,
                                                const float* __restrict__ w,
                                                const float* __restrict__ dinv,
                                                const int* __restrict__ row_start,
                                                int* __restrict__ cursor,
                                                int* __restrict__ src_s,
                                                float* __restrict__ norm_s, int E)
{
    int e = blockIdx.x*256 + threadIdx.x;
    if (e >= E) return;
    int d = dst[e];
    int pos = row_start[d] + atomicAdd(&cursor[d], 1);
    int s = src[e];
    src_s[pos]  = s;
    norm_s[pos] = dinv[s] * w[e] * dinv[d];
}

// ---------------- GCN ----------------

__global__ __launch_bounds__(256) void gemm_nk128(const float* __restrict__ x,
                                                  const float* __restrict__ W,
                                                  float* __restrict__ y, int N)
{
    __shared__ float xs[64][HL];
    const int tid = threadIdx.x;
    const int n0 = blockIdx.x * 64;
    #pragma unroll
    for (int i = 0; i < 8; ++i) {
        int f = tid + 256*i;
        int row = f >> 5, part = f & 31;
        int n = n0 + row;
        float4 v = make_float4(0.f,0.f,0.f,0.f);
        if (n < N) v = ld4(x + (size_t)n*HL + part*4);
        st4(&xs[row][part*4], v);
    }
    __syncthreads();
    const int jg = tid & 31, rg = tid >> 5;
    const int j0 = jg*4;
    float4 acc[8];
    #pragma unroll
    for (int i = 0; i < 8; ++i) acc[i] = make_float4(0.f,0.f,0.f,0.f);
    #pragma unroll 4
    for (int k = 0; k < HL; ++k) {
        float4 wv = ld4(W + (size_t)k*HL + j0);
        #pragma unroll
        for (int i = 0; i < 8; ++i) {
            float xv = xs[rg + 8*i][k];
            FMA4(acc[i], xv, wv);
        }
    }
    #pragma unroll
    for (int i = 0; i < 8; ++i) {
        int n = n0 + rg + 8*i;
        if (n < N) st4(y + (size_t)n*HL + j0, acc[i]);
    }
}

// Fused GCN aggregation, 4-deep unrolled gather for memory-level parallelism.
__global__ __launch_bounds__(256) void gcn_gather(const int* __restrict__ row_start,
                                                  const int* __restrict__ src_s,
                                                  const float* __restrict__ norm_s,
                                                  const float* __restrict__ dinv,
                                                  const float* __restrict__ y,
                                                  const float* __restrict__ b,
                                                  float* __restrict__ out, int N)
{
    int gt = blockIdx.x*256 + threadIdx.x;
    int n = gt >> 6, lane = gt & 63;
    if (n >= N) return;
    const int beg = row_start[n], end = row_start[n+1];
    float2 acc = make_float2(0.f, 0.f);
    int p = beg;
    for (; p + 4 <= end; p += 4) {
        int   s0 = src_s[p+0], s1 = src_s[p+1], s2 = src_s[p+2], s3 = src_s[p+3];
        float w0 = norm_s[p+0], w1 = norm_s[p+1], w2 = norm_s[p+2], w3 = norm_s[p+3];
        float2 v0 = ld2(y + (size_t)s0*HL + lane*2);
        float2 v1 = ld2(y + (size_t)s1*HL + lane*2);
        float2 v2 = ld2(y + (size_t)s2*HL + lane*2);
        float2 v3 = ld2(y + (size_t)s3*HL + lane*2);
        acc.x = fmaf(w0, v0.x, acc.x); acc.y = fmaf(w0, v0.y, acc.y);
        acc.x = fmaf(w1, v1.x, acc.x); acc.y = fmaf(w1, v1.y, acc.y);
        acc.x = fmaf(w2, v2.x, acc.x); acc.y = fmaf(w2, v2.y, acc.y);
        acc.x = fmaf(w3, v3.x, acc.x); acc.y = fmaf(w3, v3.y, acc.y);
    }
    for (; p < end; ++p) {
        int s = src_s[p];
        float nrm = norm_s[p];
        float2 v = ld2(y + (size_t)s*HL + lane*2);
        acc.x = fmaf(nrm, v.x, acc.x);
        acc.y = fmaf(nrm, v.y, acc.y);
    }
    float di = dinv[n];
    float sl = di*di;
    float2 vs = ld2(y + (size_t)n*HL + lane*2);
    acc.x = fmaf(sl, vs.x, acc.x);
    acc.y = fmaf(sl, vs.y, acc.y);
    float2 bb = ld2(b + lane*2);
    acc.x = fmaxf(acc.x + bb.x, 0.f);
    acc.y = fmaxf(acc.y + bb.y, 0.f);
    *(float2*)(out + (size_t)n*HL + lane*2) = acc;
}

__global__ __launch_bounds__(256) void fc_kernel(const float* __restrict__ x,
                                                 const float* __restrict__ W,
                                                 const float* __restrict__ b,
                                                 float* __restrict__ out, int N)
{
    __shared__ float xs[64][HL];
    const int tid = threadIdx.x;
    const int n0 = blockIdx.x * 64;
    #pragma unroll
    for (int i = 0; i < 8; ++i) {
        int f = tid + 256*i;
        int row = f >> 5, part = f & 31;
        int n = n0 + row;
        float4 v = make_float4(0.f,0.f,0.f,0.f);
        if (n < N) v = ld4(x + (size_t)n*HL + part*4);
        st4(&xs[row][part*4], v);
    }
    __syncthreads();
    const int o = tid & 15, rg = tid >> 4;
    float acc[4] = {0.f,0.f,0.f,0.f};
    #pragma unroll 4
    for (int k = 0; k < HL; ++k) {
        float wv = W[k*OUTF + o];
        #pragma unroll
        for (int i = 0; i < 4; ++i)
            acc[i] = fmaf(xs[rg + 16*i][k], wv, acc[i]);
    }
    float bb = b[o];
    #pragma unroll
    for (int i = 0; i < 4; ++i) {
        int n = n0 + rg + 16*i;
        if (n < N) out[(size_t)n*OUTF + o] = acc[i] + bb;
    }
}

extern "C" void kernel_launch(void* const* d_in, const int* in_sizes, int n_in,
                              void* d_out, int out_size, void* d_ws, size_t ws_size,
                              hipStream_t stream)
{
    const int*   x_tokens = (const int*)d_in[0];
    const int*   lengths  = (const int*)d_in[1];
    const int*   eidx     = (const int*)d_in[2];
    const float* ew       = (const float*)d_in[3];
    const float* emb      = (const float*)d_in[4];
    const float* W_ih     = (const float*)d_in[5];
    const float* W_hh     = (const float*)d_in[6];
    const float* b_ih     = (const float*)d_in[7];
    const float* b_hh     = (const float*)d_in[8];
    const float* c1W      = (const float*)d_in[9];
    const float* c1b      = (const float*)d_in[10];
    const float* c2W      = (const float*)d_in[11];
    const float* c2b      = (const float*)d_in[12];
    const float* fcW      = (const float*)d_in[13];
    const float* fcb      = (const float*)d_in[14];
    float* out = (float*)d_out;

    const int* esrc = eidx;
    const int* edst = eidx + NEDGE;

    char* ws = (char*)d_ws;
    size_t off = 0;
    auto take = [&](size_t bytes) -> char* {
        char* p = ws + off;
        off = (off + bytes + 255) & ~(size_t)255;
        return p;
    };
    const size_t NH = (size_t)N_NODES * HL * sizeof(float);
    __bf16* embb = (__bf16*)take((size_t)(N_NODES + 1) * EMBD * sizeof(__bf16));
    __bf16* WTp  = (__bf16*)take((size_t)KTOT * G4 * sizeof(__bf16));
    float* bsum  = (float*)take((size_t)G4 * sizeof(float));
    float* hLst  = (float*)take(NH);
    float* yb    = (float*)take(NH);
    float* x2    = (float*)take(NH);
    float* x3    = (float*)take(NH);
    float* degb  = (float*)take((size_t)N_NODES * sizeof(float));
    float* dinvb = (float*)take((size_t)N_NODES * sizeof(float));
    int*   cntb  = (int*)  take((size_t)N_NODES * sizeof(int));
    int*   rowst = (int*)  take((size_t)(N_NODES + 1) * sizeof(int));
    int*   curs  = (int*)  take((size_t)N_NODES * sizeof(int));
    int*   srcS  = (int*)  take((size_t)NEDGE * sizeof(int));
    float* nrmS  = (float*)take((size_t)NEDGE * sizeof(float));

    hipMemsetAsync(degb, 0, (size_t)N_NODES * sizeof(float), stream);
    hipMemsetAsync(cntb, 0, (size_t)N_NODES * sizeof(int), stream);
    hipMemsetAsync(curs, 0, (size_t)N_NODES * sizeof(int), stream);

    prep_embb<<<(((N_NODES+1)*EMBD/4) + 255)/256, 256, 0, stream>>>(emb, embb);
    prep_wtp<<<(KTOT*G4 + 255)/256, 256, 0, stream>>>(W_ih, W_hh, WTp);
    prep_bias<<<2, 256, 0, stream>>>(b_ih, b_hh, bsum);

    count_deg<<<NEDGE/256, 256, 0, stream>>>(edst, ew, cntb, degb, NEDGE);
    dinv_kernel<<<(N_NODES + 255)/256, 256, 0, stream>>>(degb, dinvb, N_NODES);
    scan_kernel<<<1, 1024, 0, stream>>>(cntb, rowst);
    fill_csr<<<NEDGE/256, 256, 0, stream>>>(esrc, edst, ew, dinvb, rowst, curs,
                                            srcS, nrmS, NEDGE);

    lstm_fused<<<NBLSTM, 512, 0, stream>>>(x_tokens, lengths, embb, WTp, bsum, hLst);

    const int gemmBlocks = (N_NODES + 63)/64;
    const int gathBlocks = (N_NODES*64 + 255)/256;

    gemm_nk128<<<gemmBlocks, 256, 0, stream>>>(hLst, c1W, yb, N_NODES);
    gcn_gather<<<gathBlocks, 256, 0, stream>>>(rowst, srcS, nrmS, dinvb, yb, c1b, x2, N_NODES);
    gemm_nk128<<<gemmBlocks, 256, 0, stream>>>(x2, c2W, yb, N_NODES);
    gcn_gather<<<gathBlocks, 256, 0, stream>>>(rowst, srcS, nrmS, dinvb, yb, c2b, x3, N_NODES);
    fc_kernel<<<gemmBlocks, 256, 0, stream>>>(x3, fcW, fcb, out, N_NODES);
}

// Round 8
// 403.643 us; speedup vs baseline: 11.2303x; 1.1606x over previous
//
#include <hip/hip_runtime.h>
#include <math.h>

#define N_NODES 20000
#define SEQ_T   24
#define EMBD    64
#define HL      128     // H_LSTM
#define OUTF    16
#define NEDGE   640000
#define G4      512     // 4*HL
#define KTOT    192     // EMBD + HL
#define ROWS    80      // rows per LSTM block (250 * 80 = 20000 exactly, 1 block/CU)
#define RF      5       // ROWS/16 row-fragments
#define NBLSTM  250
#define LDA     232     // LSTM A-tile leading dim (bf16), r5-measured-best layout
#define WSTRIDE 12288   // per-wave LSTM weight chunk (24 KB)

// conv GEMM tiling
#define CROWS   64
#define CRF     4
#define NCBLK   313     // ceil(20000/64)
#define CPAD    136     // conv A-tile leading dim

typedef __bf16 bf16x8 __attribute__((ext_vector_type(8)));
typedef __bf16 bf16x2 __attribute__((ext_vector_type(2)));
typedef float  f32x4  __attribute__((ext_vector_type(4)));

__device__ __forceinline__ float4 ld4(const float* p){ return *reinterpret_cast<const float4*>(p); }
__device__ __forceinline__ void st4(float* p, float4 v){ *reinterpret_cast<float4*>(p) = v; }

#define LOG2E 1.44269504f

#define FMA4(A,S,B) {(A).x=fmaf((S),(B).x,(A).x);(A).y=fmaf((S),(B).y,(A).y);(A).z=fmaf((S),(B).z,(A).z);(A).w=fmaf((S),(B).w,(A).w);}

// ---------------- fused prep: embb + WTp + conv1/conv2 packs + bias ----------------
#define S_EMB   320016                  // (20001*64)/4 threads, 4 elems each
#define S_WTP   (S_EMB + KTOT*G4)       // + 98304
#define S_C1    (S_WTP + 16384)
#define S_C2    (S_C1 + 16384)
#define S_BIAS  (S_C2 + G4)
#define PREPBLK ((S_BIAS + 255)/256)

__global__ __launch_bounds__(256) void prep_all(
    const float* __restrict__ emb,  __bf16* __restrict__ embb,
    const float* __restrict__ Wih,  const float* __restrict__ Whh,
    __bf16* __restrict__ WTp,
    const float* __restrict__ c1W,  __bf16* __restrict__ wc1b,
    const float* __restrict__ c2W,  __bf16* __restrict__ wc2b,
    const float* __restrict__ bi,   const float* __restrict__ bh,
    float* __restrict__ bs)
{
    int gid = blockIdx.x*256 + threadIdx.x;
    if (gid < S_EMB) {
        int i4 = gid*4;
        float4 v = ld4(emb + i4);
        embb[i4+0] = (__bf16)v.x;
        embb[i4+1] = (__bf16)v.y;
        embb[i4+2] = (__bf16)v.z;
        embb[i4+3] = (__bf16)v.w;
    } else if (gid < S_WTP) {
        int idx = gid - S_EMB;
        int ko = idx & 31;
        int c  = (idx >> 5) & 15;
        int gt = (idx >> 9) & 3;
        int kc = (idx >> 11) % 6;
        int w  = idx / WSTRIDE;
        int g  = gt*HL + w*16 + c;
        int kk = kc*32 + ko;
        float v = (kk < EMBD) ? Wih[g*EMBD + kk] : Whh[g*HL + (kk - EMBD)];
        WTp[idx] = (__bf16)v;
    } else if (gid < S_C2) {
        bool c2 = (gid >= S_C1);
        int idx = gid - (c2 ? S_C1 : S_WTP);
        const float* W = c2 ? c2W : c1W;
        __bf16* dst = c2 ? wc2b : wc1b;
        int ko = idx & 31;
        int c  = (idx >> 5) & 15;
        int kc = (idx >> 9) & 3;
        int w  = idx >> 11;
        int g  = w*16 + c;
        int k  = kc*32 + ko;
        dst[idx] = (__bf16)W[k*HL + g];
    } else if (gid < S_BIAS) {
        int i = gid - S_C2;
        bs[i] = bi[i] + bh[i];
    }
}

// ---------------- fused LSTM (r5 structure, 8-trans epilogue) ----------------
// 512 thr = 8 waves; wave w owns cols [w*16, w*16+16) of all 4 gates; weights in regs
// (96 VGPR/lane). A-tile [80][232] bf16: cols 0..63 emb(t), 64..191 h(t-1) in place.
__global__ __launch_bounds__(512, 2) void lstm_fused(
    const int* __restrict__ tokens, const int* __restrict__ lengths,
    const __bf16* __restrict__ embb, const __bf16* __restrict__ WTp,
    const float* __restrict__ bsum, float* __restrict__ hlast)
{
    __shared__ __align__(16) __bf16 a_lds[ROWS][LDA];
    __shared__ int tok_lds[ROWS*SEQ_T];
    __shared__ int len_lds[ROWS];

    const int tid = threadIdx.x;
    const int n0  = blockIdx.x * ROWS;
    const int w   = tid >> 6;       // 0..7
    const int l   = tid & 63;
    const int l15 = l & 15, l4 = l >> 4;

    #pragma unroll
    for (int i = 0; i < 4; ++i) {
        int idx = tid + 512*i;
        if (idx < ROWS*SEQ_T) tok_lds[idx] = tokens[n0*SEQ_T + idx];
    }
    if (tid < ROWS) len_lds[tid] = lengths[n0 + tid];

    // zero h region (cols 64..191)
    #pragma unroll
    for (int i = 0; i < 3; ++i) {
        int idx = tid + 512*i;
        if (idx < ROWS*16) {
            int row = idx >> 4, s = idx & 15;
            *reinterpret_cast<uint4*>(&a_lds[row][EMBD + s*8]) = make_uint4(0,0,0,0);
        }
    }

    float bias_v[4];
    #pragma unroll
    for (int gt = 0; gt < 4; ++gt)
        bias_v[gt] = bsum[gt*HL + w*16 + l15];

    bf16x8 wreg[6][4];
    {
        const __bf16* wbase = WTp + (size_t)w * WSTRIDE;
        #pragma unroll
        for (int kc = 0; kc < 6; ++kc)
            #pragma unroll
            for (int gt = 0; gt < 4; ++gt)
                wreg[kc][gt] = *reinterpret_cast<const bf16x8*>(
                    &wbase[(size_t)(((kc*4 + gt)*16 + l15)*32) + l4*8]);
    }

    f32x4 acc[RF][4];
    float c_reg[RF][4];
    {
        f32x4 zz = {0.f,0.f,0.f,0.f};
        #pragma unroll
        for (int rf = 0; rf < RF; ++rf) {
            #pragma unroll
            for (int gt = 0; gt < 4; ++gt) acc[rf][gt] = zz;
            #pragma unroll
            for (int r = 0; r < 4; ++r) c_reg[rf][r] = 0.f;
        }
    }

    for (int t = 0; t < SEQ_T; ++t) {
        // stage emb(t) into cols 0..63 (disjoint from h region)
        #pragma unroll
        for (int i = 0; i < 2; ++i) {
            int idx = tid + 512*i;
            if (idx < ROWS*8) {
                int row = idx >> 3, sl = idx & 7;
                int tok = tok_lds[row*SEQ_T + t];
                *reinterpret_cast<uint4*>(&a_lds[row][sl*8]) =
                    *reinterpret_cast<const uint4*>(&embb[(size_t)tok*EMBD + sl*8]);
            }
        }
        __syncthreads();   // emb(t) + h(t-1) ready

        #pragma unroll
        for (int kc = 0; kc < 6; ++kc)
            #pragma unroll
            for (int rf = 0; rf < RF; ++rf) {
                bf16x8 af = *reinterpret_cast<const bf16x8*>(
                    &a_lds[rf*16 + l15][kc*32 + l4*8]);
                #pragma unroll
                for (int gt = 0; gt < 4; ++gt)
                    acc[rf][gt] = __builtin_amdgcn_mfma_f32_16x16x32_bf16(
                        af, wreg[kc][gt], acc[rf][gt], 0, 0, 0);
            }
        __syncthreads();   // all a_lds reads of step t complete

        // 8-trans epilogue: sig(a)*tanh(b) = (e2b-1)*rcp((1+e^-a)(e2b+1))
        #pragma unroll
        for (int rf = 0; rf < RF; ++rf) {
            f32x4 zi4 = acc[rf][0], zf4 = acc[rf][1];
            f32x4 zg4 = acc[rf][2], zo4 = acc[rf][3];
            #pragma unroll
            for (int r = 0; r < 4; ++r) {
                int row = rf*16 + l4*4 + r;
                float zi = zi4[r] + bias_v[0];
                float zf = zf4[r] + bias_v[1];
                float zg = zg4[r] + bias_v[2];
                float zo = zo4[r] + bias_v[3];
                float ef = __builtin_amdgcn_exp2f(-LOG2E*zf);
                float ei = __builtin_amdgcn_exp2f(-LOG2E*zi);
                float eg = __builtin_amdgcn_exp2f(2.0f*LOG2E*zg);
                float sf  = __builtin_amdgcn_rcpf(1.0f + ef);
                float rig = __builtin_amdgcn_rcpf((1.0f + ei)*(eg + 1.0f));
                float cc = sf*c_reg[rf][r] + (eg - 1.0f)*rig;
                c_reg[rf][r] = cc;
                float eo = __builtin_amdgcn_exp2f(-LOG2E*zo);
                float ec = __builtin_amdgcn_exp2f(2.0f*LOG2E*cc);
                float rh = __builtin_amdgcn_rcpf((1.0f + eo)*(ec + 1.0f));
                float h = (ec - 1.0f)*rh;
                int j = w*16 + l15;
                a_lds[row][EMBD + j] = (__bf16)h;
                if (len_lds[row] == t + 1)
                    __builtin_nontemporal_store(h, &hlast[(size_t)(n0 + row)*HL + j]);
            }
            f32x4 zz = {0.f,0.f,0.f,0.f};
            acc[rf][0] = zz; acc[rf][1] = zz; acc[rf][2] = zz; acc[rf][3] = zz;
        }
    }
}

// ---------------- CSR build ----------------

__global__ __launch_bounds__(256) void count_deg(const int* __restrict__ dst,
                                                 const float* __restrict__ w,
                                                 int* __restrict__ cnt,
                                                 float* __restrict__ deg, int E)
{
    int e = blockIdx.x*256 + threadIdx.x;
    if (e < E) {
        int d = dst[e];
        atomicAdd(&cnt[d], 1);
        atomicAdd(&deg[d], w[e]);
    }
}

// scan (exclusive prefix over cnt) + dinv in one launch (single block)
__global__ __launch_bounds__(1024) void scan_dinv(const int* __restrict__ cnt,
                                                  const float* __restrict__ deg,
                                                  int* __restrict__ row_start,
                                                  float* __restrict__ dinv)
{
    __shared__ int part[1024];
    const int t = threadIdx.x;
    const int CH = (N_NODES + 1023) / 1024;   // 20
    int beg = t*CH, end = min(beg + CH, N_NODES);
    int s = 0;
    for (int i = beg; i < end; ++i) {
        s += cnt[i];
        dinv[i] = rsqrtf(deg[i] + 1.0f);
    }
    part[t] = s;
    __syncthreads();
    for (int off = 1; off < 1024; off <<= 1) {
        int v = (t >= off) ? part[t - off] : 0;
        __syncthreads();
        part[t] += v;
        __syncthreads();
    }
    int base = (t == 0) ? 0 : part[t - 1];
    for (int i = beg; i < end; ++i) { row_start[i] = base; base += cnt[i]; }
    if (t == 1023) row_start[N_NODES] = part[1023];
}

// fill: pos via atomicSub on cnt (cnt ends at zero; re-zeroed by memset each call)
__global__ __launch_bounds__(256) void fill_csr(const int* __restrict__ src,
                                                const int* __restrict__ dst,
                                                const float* __restrict__ w,
                                                const float* __restrict__ dinv,
                                                const int* __restrict__ row_start,
                                                int* __restrict__ cnt,
                                                int* __restrict__ src_s,
                                                float* __restrict__ norm_s, int E)
{
    int e = blockIdx.x*256 + threadIdx.x;
    if (e >= E) return;
    int d = dst[e];
    int pos = row_start[d] + atomicSub(&cnt[d], 1) - 1;
    int s = src[e];
    src_s[pos]  = s;
    norm_s[pos] = dinv[s] * w[e] * dinv[d];
}

// ---------------- conv GEMM: y_bf16[N][128] = bf16(x[N][128]) @ Wb ----------------
// 512 thr = 8 waves; wave w owns cols [w*16,w*16+16); B-frags in 16 regs.
__global__ __launch_bounds__(512) void gemm_mfma(const float* __restrict__ x,
                                                 const __bf16* __restrict__ Wb,
                                                 __bf16* __restrict__ y, int N)
{
    __shared__ __align__(16) __bf16 a_lds[CROWS][CPAD];
    const int tid = threadIdx.x;
    const int n0 = blockIdx.x * CROWS;
    const int w = tid >> 6, l = tid & 63;
    const int l15 = l & 15, l4 = l >> 4;

    // stage x -> bf16: thread = (row, 16-elem slot)
    {
        int row = tid >> 3, sl = tid & 7;
        int n = n0 + row;
        __bf16 tmp[16];
        if (n < N) {
            #pragma unroll
            for (int q = 0; q < 4; ++q) {
                float4 v = ld4(x + (size_t)n*HL + sl*16 + q*4);
                tmp[q*4+0] = (__bf16)v.x; tmp[q*4+1] = (__bf16)v.y;
                tmp[q*4+2] = (__bf16)v.z; tmp[q*4+3] = (__bf16)v.w;
            }
        } else {
            #pragma unroll
            for (int q = 0; q < 16; ++q) tmp[q] = (__bf16)0.f;
        }
        *reinterpret_cast<uint4*>(&a_lds[row][sl*16])     = *reinterpret_cast<uint4*>(&tmp[0]);
        *reinterpret_cast<uint4*>(&a_lds[row][sl*16 + 8]) = *reinterpret_cast<uint4*>(&tmp[8]);
    }

    bf16x8 wb[4];
    #pragma unroll
    for (int kc = 0; kc < 4; ++kc)
        wb[kc] = *reinterpret_cast<const bf16x8*>(
            &Wb[(size_t)(((w*4 + kc)*16 + l15)*32) + l4*8]);

    f32x4 acc[CRF];
    {
        f32x4 zz = {0.f,0.f,0.f,0.f};
        #pragma unroll
        for (int rf = 0; rf < CRF; ++rf) acc[rf] = zz;
    }
    __syncthreads();

    #pragma unroll
    for (int kc = 0; kc < 4; ++kc)
        #pragma unroll
        for (int rf = 0; rf < CRF; ++rf) {
            bf16x8 af = *reinterpret_cast<const bf16x8*>(
                &a_lds[rf*16 + l15][kc*32 + l4*8]);
            acc[rf] = __builtin_amdgcn_mfma_f32_16x16x32_bf16(af, wb[kc], acc[rf], 0, 0, 0);
        }

    int j = w*16 + l15;
    #pragma unroll
    for (int rf = 0; rf < CRF; ++rf)
        #pragma unroll
        for (int r = 0; r < 4; ++r) {
            int n = n0 + rf*16 + l4*4 + r;
            if (n < N) y[(size_t)n*HL + j] = (__bf16)acc[rf][r];
        }
}

// ---------------- fused GCN aggregation (bf16 y, fp32 accum) ----------------
__global__ __launch_bounds__(256) void gcn_gather(const int* __restrict__ row_start,
                                                  const int* __restrict__ src_s,
                                                  const float* __restrict__ norm_s,
                                                  const float* __restrict__ dinv,
                                                  const __bf16* __restrict__ y,
                                                  const float* __restrict__ b,
                                                  float* __restrict__ out, int N)
{
    int gt = blockIdx.x*256 + threadIdx.x;
    int n = gt >> 6, lane = gt & 63;
    if (n >= N) return;
    const int beg = row_start[n], end = row_start[n+1];
    float ax = 0.f, ay = 0.f;
    int p = beg;
    for (; p + 4 <= end; p += 4) {
        int   s0 = src_s[p+0], s1 = src_s[p+1], s2 = src_s[p+2], s3 = src_s[p+3];
        float w0 = norm_s[p+0], w1 = norm_s[p+1], w2 = norm_s[p+2], w3 = norm_s[p+3];
        bf16x2 v0 = *reinterpret_cast<const bf16x2*>(y + (size_t)s0*HL + lane*2);
        bf16x2 v1 = *reinterpret_cast<const bf16x2*>(y + (size_t)s1*HL + lane*2);
        bf16x2 v2 = *reinterpret_cast<const bf16x2*>(y + (size_t)s2*HL + lane*2);
        bf16x2 v3 = *reinterpret_cast<const bf16x2*>(y + (size_t)s3*HL + lane*2);
        ax = fmaf(w0, (float)v0[0], ax); ay = fmaf(w0, (float)v0[1], ay);
        ax = fmaf(w1, (float)v1[0], ax); ay = fmaf(w1, (float)v1[1], ay);
        ax = fmaf(w2, (float)v2[0], ax); ay = fmaf(w2, (float)v2[1], ay);
        ax = fmaf(w3, (float)v3[0], ax); ay = fmaf(w3, (float)v3[1], ay);
    }
    for (; p < end; ++p) {
        int s = src_s[p];
        float nrm = norm_s[p];
        bf16x2 v = *reinterpret_cast<const bf16x2*>(y + (size_t)s*HL + lane*2);
        ax = fmaf(nrm, (float)v[0], ax);
        ay = fmaf(nrm, (float)v[1], ay);
    }
    float di = dinv[n];
    float sl = di*di;
    bf16x2 vs = *reinterpret_cast<const bf16x2*>(y + (size_t)n*HL + lane*2);
    ax = fmaf(sl, (float)vs[0], ax);
    ay = fmaf(sl, (float)vs[1], ay);
    float2 bb = *reinterpret_cast<const float2*>(b + lane*2);
    ax = fmaxf(ax + bb.x, 0.f);
    ay = fmaxf(ay + bb.y, 0.f);
    *reinterpret_cast<float2*>(out + (size_t)n*HL + lane*2) = make_float2(ax, ay);
}

// ---------------- fc ----------------
__global__ __launch_bounds__(256) void fc_kernel(const float* __restrict__ x,
                                                 const float* __restrict__ W,
                                                 const float* __restrict__ b,
                                                 float* __restrict__ out, int N)
{
    __shared__ float xs[64][HL];
    const int tid = threadIdx.x;
    const int n0 = blockIdx.x * 64;
    #pragma unroll
    for (int i = 0; i < 8; ++i) {
        int f = tid + 256*i;
        int row = f >> 5, part = f & 31;
        int n = n0 + row;
        float4 v = make_float4(0.f,0.f,0.f,0.f);
        if (n < N) v = ld4(x + (size_t)n*HL + part*4);
        st4(&xs[row][part*4], v);
    }
    __syncthreads();
    const int o = tid & 15, rg = tid >> 4;
    float acc[4] = {0.f,0.f,0.f,0.f};
    #pragma unroll 4
    for (int k = 0; k < HL; ++k) {
        float wv = W[k*OUTF + o];
        #pragma unroll
        for (int i = 0; i < 4; ++i)
            acc[i] = fmaf(xs[rg + 16*i][k], wv, acc[i]);
    }
    float bb = b[o];
    #pragma unroll
    for (int i = 0; i < 4; ++i) {
        int n = n0 + rg + 16*i;
        if (n < N) out[(size_t)n*OUTF + o] = acc[i] + bb;
    }
}

extern "C" void kernel_launch(void* const* d_in, const int* in_sizes, int n_in,
                              void* d_out, int out_size, void* d_ws, size_t ws_size,
                              hipStream_t stream)
{
    const int*   x_tokens = (const int*)d_in[0];
    const int*   lengths  = (const int*)d_in[1];
    const int*   eidx     = (const int*)d_in[2];
    const float* ew       = (const float*)d_in[3];
    const float* emb      = (const float*)d_in[4];
    const float* W_ih     = (const float*)d_in[5];
    const float* W_hh     = (const float*)d_in[6];
    const float* b_ih     = (const float*)d_in[7];
    const float* b_hh     = (const float*)d_in[8];
    const float* c1W      = (const float*)d_in[9];
    const float* c1b      = (const float*)d_in[10];
    const float* c2W      = (const float*)d_in[11];
    const float* c2b      = (const float*)d_in[12];
    const float* fcW      = (const float*)d_in[13];
    const float* fcb      = (const float*)d_in[14];
    float* out = (float*)d_out;

    const int* esrc = eidx;
    const int* edst = eidx + NEDGE;

    char* ws = (char*)d_ws;
    size_t off = 0;
    auto take = [&](size_t bytes) -> char* {
        char* p = ws + off;
        off = (off + bytes + 255) & ~(size_t)255;
        return p;
    };
    const size_t NH = (size_t)N_NODES * HL * sizeof(float);
    __bf16* embb = (__bf16*)take((size_t)(N_NODES + 1) * EMBD * sizeof(__bf16));
    __bf16* WTp  = (__bf16*)take((size_t)KTOT * G4 * sizeof(__bf16));
    __bf16* wc1b = (__bf16*)take((size_t)HL * HL * sizeof(__bf16));
    __bf16* wc2b = (__bf16*)take((size_t)HL * HL * sizeof(__bf16));
    float* bsum  = (float*)take((size_t)G4 * sizeof(float));
    float* hLst  = (float*)take(NH);
    __bf16* ybf  = (__bf16*)take((size_t)N_NODES * HL * sizeof(__bf16));
    float* x2    = (float*)take(NH);
    float* x3    = (float*)take(NH);
    float* degb  = (float*)take((size_t)N_NODES * sizeof(float));
    float* dinvb = (float*)take((size_t)N_NODES * sizeof(float));
    int*   cntb  = (int*)  take((size_t)N_NODES * sizeof(int));
    int*   rowst = (int*)  take((size_t)(N_NODES + 1) * sizeof(int));
    int*   srcS  = (int*)  take((size_t)NEDGE * sizeof(int));
    float* nrmS  = (float*)take((size_t)NEDGE * sizeof(float));

    hipMemsetAsync(degb, 0, (size_t)N_NODES * sizeof(float), stream);
    hipMemsetAsync(cntb, 0, (size_t)N_NODES * sizeof(int), stream);

    prep_all<<<PREPBLK, 256, 0, stream>>>(emb, embb, W_ih, W_hh, WTp,
                                          c1W, wc1b, c2W, wc2b, b_ih, b_hh, bsum);

    count_deg<<<NEDGE/256, 256, 0, stream>>>(edst, ew, cntb, degb, NEDGE);
    scan_dinv<<<1, 1024, 0, stream>>>(cntb, degb, rowst, dinvb);
    fill_csr<<<NEDGE/256, 256, 0, stream>>>(esrc, edst, ew, dinvb, rowst, cntb,
                                            srcS, nrmS, NEDGE);

    lstm_fused<<<NBLSTM, 512, 0, stream>>>(x_tokens, lengths, embb, WTp, bsum, hLst);

    const int gathBlocks = (N_NODES*64 + 255)/256;

    gemm_mfma<<<NCBLK, 512, 0, stream>>>(hLst, wc1b, ybf, N_NODES);
    gcn_gather<<<gathBlocks, 256, 0, stream>>>(rowst, srcS, nrmS, dinvb, ybf, c1b, x2, N_NODES);
    gemm_mfma<<<NCBLK, 512, 0, stream>>>(x2, wc2b, ybf, N_NODES);
    gcn_gather<<<gathBlocks, 256, 0, stream>>>(rowst, srcS, nrmS, dinvb, ybf, c2b, x3, N_NODES);
    fc_kernel<<<(N_NODES + 63)/64, 256, 0, stream>>>(x3, fcW, fcb, out, N_NODES);
}

// Round 9
// 402.020 us; speedup vs baseline: 11.2757x; 1.0040x over previous
//
#include <hip/hip_runtime.h>
#include <math.h>

#define N_NODES 20000
#define SEQ_T   24
#define EMBD    64
#define HL      128     // H_LSTM
#define OUTF    16
#define NEDGE   640000
#define G4      512     // 4*HL
#define KTOT    192     // EMBD + HL
#define ROWS    80      // rows per LSTM block (250 * 80 = 20000 exactly)
#define RF      5       // ROWS/16 row-fragments
#define NBLSTM  250
#define NBCSR   250
#define EPB     (NEDGE/NBCSR)   // 2560 edges per CSR block
#define NPB     (N_NODES/NBCSR) // 80 nodes per CSR block
#define LDA     232     // LSTM A-tile leading dim (bf16)
#define WSTRIDE 12288   // per-wave LSTM weight chunk (24 KB)

// conv GEMM tiling
#define CROWS   64
#define CRF     4
#define NCBLK   313     // ceil(20000/64)
#define CPAD    136

typedef __bf16 bf16x8 __attribute__((ext_vector_type(8)));
typedef __bf16 bf16x2 __attribute__((ext_vector_type(2)));
typedef float  f32x4  __attribute__((ext_vector_type(4)));

__device__ __forceinline__ float4 ld4(const float* p){ return *reinterpret_cast<const float4*>(p); }
__device__ __forceinline__ void st4(float* p, float4 v){ *reinterpret_cast<float4*>(p) = v; }

#define LOG2E 1.44269504f

// ---------------- fused prep: embb + WTp + conv1/conv2 packs + bias ----------------
#define S_EMB   320016                  // (20001*64)/4 threads, 4 elems each
#define S_WTP   (S_EMB + KTOT*G4)       // + 98304
#define S_C1    (S_WTP + 16384)
#define S_C2    (S_C1 + 16384)
#define S_BIAS  (S_C2 + G4)
#define PREPBLK ((S_BIAS + 255)/256)

__global__ __launch_bounds__(256) void prep_all(
    const float* __restrict__ emb,  __bf16* __restrict__ embb,
    const float* __restrict__ Wih,  const float* __restrict__ Whh,
    __bf16* __restrict__ WTp,
    const float* __restrict__ c1W,  __bf16* __restrict__ wc1b,
    const float* __restrict__ c2W,  __bf16* __restrict__ wc2b,
    const float* __restrict__ bi,   const float* __restrict__ bh,
    float* __restrict__ bs)
{
    int gid = blockIdx.x*256 + threadIdx.x;
    if (gid < S_EMB) {
        int i4 = gid*4;
        float4 v = ld4(emb + i4);
        embb[i4+0] = (__bf16)v.x;
        embb[i4+1] = (__bf16)v.y;
        embb[i4+2] = (__bf16)v.z;
        embb[i4+3] = (__bf16)v.w;
    } else if (gid < S_WTP) {
        int idx = gid - S_EMB;
        int ko = idx & 31;
        int c  = (idx >> 5) & 15;
        int gt = (idx >> 9) & 3;
        int kc = (idx >> 11) % 6;
        int w  = idx / WSTRIDE;
        int g  = gt*HL + w*16 + c;
        int kk = kc*32 + ko;
        float v = (kk < EMBD) ? Wih[g*EMBD + kk] : Whh[g*HL + (kk - EMBD)];
        WTp[idx] = (__bf16)v;
    } else if (gid < S_C2) {
        bool c2 = (gid >= S_C1);
        int idx = gid - (c2 ? S_C1 : S_WTP);
        const float* W = c2 ? c2W : c1W;
        __bf16* dst = c2 ? wc2b : wc1b;
        int ko = idx & 31;
        int c  = (idx >> 5) & 15;
        int kc = (idx >> 9) & 3;
        int w  = idx >> 11;
        int g  = w*16 + c;
        int k  = kc*32 + ko;
        dst[idx] = (__bf16)W[k*HL + g];
    } else if (gid < S_BIAS) {
        int i = gid - S_C2;
        bs[i] = bi[i] + bh[i];
    }
}

// ---------------- merged LSTM + CSR-build kernel ----------------
// Blocks 0..249: LSTM (r5 structure, weights in regs, 8-trans epilogue).
// Blocks 250..499: CSR build with spin barriers among CSR blocks only.
// Deadlock-free: LSTM blocks never wait on CSR; 250 CSR blocks always fit resident.

__device__ __forceinline__ void gbar(int* ctr) {
    __syncthreads();
    if (threadIdx.x == 0) {
        __threadfence();                      // publish prior writes
        atomicAdd(ctr, 1);
        while (atomicAdd(ctr, 0) < NBCSR) __builtin_amdgcn_s_sleep(8);
        __threadfence();                      // acquire others' writes (inval L1)
    }
    __syncthreads();
}

__global__ __launch_bounds__(512, 2) void lstm_csr(
    const int* __restrict__ tokens, const int* __restrict__ lengths,
    const __bf16* __restrict__ embb, const __bf16* __restrict__ WTp,
    const float* __restrict__ bsum, float* __restrict__ hlast,
    const int* __restrict__ esrc, const int* __restrict__ edst,
    const float* __restrict__ ew,
    int* __restrict__ cnt, float* __restrict__ deg, float* __restrict__ dinv,
    int* __restrict__ row_start, int* __restrict__ src_s,
    float* __restrict__ norm_s, int* __restrict__ aux)
{
    __shared__ __align__(16) __bf16 a_lds[ROWS][LDA];
    __shared__ int tok_lds[ROWS*SEQ_T];
    __shared__ int len_lds[ROWS];

    const int tid = threadIdx.x;

    if (blockIdx.x >= NBLSTM) {
        // ================= CSR build path =================
        const int bid = blockIdx.x - NBLSTM;     // 0..249
        int* scratch = tok_lds;                  // 1920 ints of LDS scratch
        const int e0 = bid * EPB;
        const int nodes0 = bid * NPB;

        // P1: count + weighted degree
        for (int i = tid; i < EPB; i += 512) {
            int e = e0 + i;
            int d = edst[e];
            atomicAdd(&cnt[d], 1);
            atomicAdd(&deg[d], ew[e]);
        }
        gbar(&aux[0]);

        // P2: dinv + stash local counts + block partial sum
        if (tid == 0) scratch[255] = 0;
        __syncthreads();
        if (tid < NPB) {
            int n = nodes0 + tid;
            dinv[n] = rsqrtf(deg[n] + 1.0f);
            int lc = cnt[n];
            scratch[256 + tid] = lc;
            atomicAdd(&scratch[255], lc);
        }
        __syncthreads();
        if (tid == 0) aux[3 + bid] = scratch[255];
        gbar(&aux[1]);

        // P3: block base (sum of partials < bid) + local exclusive scan
        if (tid < NBCSR) scratch[tid] = aux[3 + tid];
        __syncthreads();
        if (tid == 0) {
            int base = 0;
            for (int b = 0; b < bid; ++b) base += scratch[b];
            for (int i = 0; i < NPB; ++i) {
                row_start[nodes0 + i] = base;
                base += scratch[256 + i];
            }
            if (bid == NBCSR - 1) row_start[N_NODES] = base;
        }
        gbar(&aux[2]);

        // P4: fill (atomicSub on cnt; cnt ends at 0, re-zeroed next call)
        for (int i = tid; i < EPB; i += 512) {
            int e = e0 + i;
            int d = edst[e];
            int pos = row_start[d] + atomicSub(&cnt[d], 1) - 1;
            int s = esrc[e];
            src_s[pos]  = s;
            norm_s[pos] = dinv[s] * ew[e] * dinv[d];
        }
        return;
    }

    // ================= LSTM path (unchanged r8 structure) =================
    const int n0  = blockIdx.x * ROWS;
    const int w   = tid >> 6;       // 0..7
    const int l   = tid & 63;
    const int l15 = l & 15, l4 = l >> 4;

    #pragma unroll
    for (int i = 0; i < 4; ++i) {
        int idx = tid + 512*i;
        if (idx < ROWS*SEQ_T) tok_lds[idx] = tokens[n0*SEQ_T + idx];
    }
    if (tid < ROWS) len_lds[tid] = lengths[n0 + tid];

    #pragma unroll
    for (int i = 0; i < 3; ++i) {
        int idx = tid + 512*i;
        if (idx < ROWS*16) {
            int row = idx >> 4, s = idx & 15;
            *reinterpret_cast<uint4*>(&a_lds[row][EMBD + s*8]) = make_uint4(0,0,0,0);
        }
    }

    float bias_v[4];
    #pragma unroll
    for (int gt = 0; gt < 4; ++gt)
        bias_v[gt] = bsum[gt*HL + w*16 + l15];

    bf16x8 wreg[6][4];
    {
        const __bf16* wbase = WTp + (size_t)w * WSTRIDE;
        #pragma unroll
        for (int kc = 0; kc < 6; ++kc)
            #pragma unroll
            for (int gt = 0; gt < 4; ++gt)
                wreg[kc][gt] = *reinterpret_cast<const bf16x8*>(
                    &wbase[(size_t)(((kc*4 + gt)*16 + l15)*32) + l4*8]);
    }

    f32x4 acc[RF][4];
    float c_reg[RF][4];
    {
        f32x4 zz = {0.f,0.f,0.f,0.f};
        #pragma unroll
        for (int rf = 0; rf < RF; ++rf) {
            #pragma unroll
            for (int gt = 0; gt < 4; ++gt) acc[rf][gt] = zz;
            #pragma unroll
            for (int r = 0; r < 4; ++r) c_reg[rf][r] = 0.f;
        }
    }

    for (int t = 0; t < SEQ_T; ++t) {
        #pragma unroll
        for (int i = 0; i < 2; ++i) {
            int idx = tid + 512*i;
            if (idx < ROWS*8) {
                int row = idx >> 3, sl = idx & 7;
                int tok = tok_lds[row*SEQ_T + t];
                *reinterpret_cast<uint4*>(&a_lds[row][sl*8]) =
                    *reinterpret_cast<const uint4*>(&embb[(size_t)tok*EMBD + sl*8]);
            }
        }
        __syncthreads();

        #pragma unroll
        for (int kc = 0; kc < 6; ++kc)
            #pragma unroll
            for (int rf = 0; rf < RF; ++rf) {
                bf16x8 af = *reinterpret_cast<const bf16x8*>(
                    &a_lds[rf*16 + l15][kc*32 + l4*8]);
                #pragma unroll
                for (int gt = 0; gt < 4; ++gt)
                    acc[rf][gt] = __builtin_amdgcn_mfma_f32_16x16x32_bf16(
                        af, wreg[kc][gt], acc[rf][gt], 0, 0, 0);
            }
        __syncthreads();

        // 8-trans epilogue
        #pragma unroll
        for (int rf = 0; rf < RF; ++rf) {
            f32x4 zi4 = acc[rf][0], zf4 = acc[rf][1];
            f32x4 zg4 = acc[rf][2], zo4 = acc[rf][3];
            #pragma unroll
            for (int r = 0; r < 4; ++r) {
                int row = rf*16 + l4*4 + r;
                float zi = zi4[r] + bias_v[0];
                float zf = zf4[r] + bias_v[1];
                float zg = zg4[r] + bias_v[2];
                float zo = zo4[r] + bias_v[3];
                float ef = __builtin_amdgcn_exp2f(-LOG2E*zf);
                float ei = __builtin_amdgcn_exp2f(-LOG2E*zi);
                float eg = __builtin_amdgcn_exp2f(2.0f*LOG2E*zg);
                float sf  = __builtin_amdgcn_rcpf(1.0f + ef);
                float rig = __builtin_amdgcn_rcpf((1.0f + ei)*(eg + 1.0f));
                float cc = sf*c_reg[rf][r] + (eg - 1.0f)*rig;
                c_reg[rf][r] = cc;
                float eo = __builtin_amdgcn_exp2f(-LOG2E*zo);
                float ec = __builtin_amdgcn_exp2f(2.0f*LOG2E*cc);
                float rh = __builtin_amdgcn_rcpf((1.0f + eo)*(ec + 1.0f));
                float h = (ec - 1.0f)*rh;
                int j = w*16 + l15;
                a_lds[row][EMBD + j] = (__bf16)h;
                if (len_lds[row] == t + 1)
                    __builtin_nontemporal_store(h, &hlast[(size_t)(n0 + row)*HL + j]);
            }
            f32x4 zz = {0.f,0.f,0.f,0.f};
            acc[rf][0] = zz; acc[rf][1] = zz; acc[rf][2] = zz; acc[rf][3] = zz;
        }
    }
}

// ---------------- conv GEMM: y_bf16[N][128] = bf16(x[N][128]) @ Wb ----------------
template<bool BF16IN>
__global__ __launch_bounds__(512) void gemm_mfma(const void* __restrict__ xin,
                                                 const __bf16* __restrict__ Wb,
                                                 __bf16* __restrict__ y, int N)
{
    __shared__ __align__(16) __bf16 a_lds[CROWS][CPAD];
    const int tid = threadIdx.x;
    const int n0 = blockIdx.x * CROWS;
    const int w = tid >> 6, l = tid & 63;
    const int l15 = l & 15, l4 = l >> 4;

    {
        int row = tid >> 3, sl = tid & 7;   // 16 elems per (row, sl)
        int n = n0 + row;
        if (BF16IN) {
            const __bf16* xb = (const __bf16*)xin;
            uint4 v0 = make_uint4(0,0,0,0), v1 = make_uint4(0,0,0,0);
            if (n < N) {
                v0 = *reinterpret_cast<const uint4*>(xb + (size_t)n*HL + sl*16);
                v1 = *reinterpret_cast<const uint4*>(xb + (size_t)n*HL + sl*16 + 8);
            }
            *reinterpret_cast<uint4*>(&a_lds[row][sl*16])     = v0;
            *reinterpret_cast<uint4*>(&a_lds[row][sl*16 + 8]) = v1;
        } else {
            const float* x = (const float*)xin;
            __bf16 tmp[16];
            if (n < N) {
                #pragma unroll
                for (int q = 0; q < 4; ++q) {
                    float4 v = ld4(x + (size_t)n*HL + sl*16 + q*4);
                    tmp[q*4+0] = (__bf16)v.x; tmp[q*4+1] = (__bf16)v.y;
                    tmp[q*4+2] = (__bf16)v.z; tmp[q*4+3] = (__bf16)v.w;
                }
            } else {
                #pragma unroll
                for (int q = 0; q < 16; ++q) tmp[q] = (__bf16)0.f;
            }
            *reinterpret_cast<uint4*>(&a_lds[row][sl*16])     = *reinterpret_cast<uint4*>(&tmp[0]);
            *reinterpret_cast<uint4*>(&a_lds[row][sl*16 + 8]) = *reinterpret_cast<uint4*>(&tmp[8]);
        }
    }

    bf16x8 wb[4];
    #pragma unroll
    for (int kc = 0; kc < 4; ++kc)
        wb[kc] = *reinterpret_cast<const bf16x8*>(
            &Wb[(size_t)(((w*4 + kc)*16 + l15)*32) + l4*8]);

    f32x4 acc[CRF];
    {
        f32x4 zz = {0.f,0.f,0.f,0.f};
        #pragma unroll
        for (int rf = 0; rf < CRF; ++rf) acc[rf] = zz;
    }
    __syncthreads();

    #pragma unroll
    for (int kc = 0; kc < 4; ++kc)
        #pragma unroll
        for (int rf = 0; rf < CRF; ++rf) {
            bf16x8 af = *reinterpret_cast<const bf16x8*>(
                &a_lds[rf*16 + l15][kc*32 + l4*8]);
            acc[rf] = __builtin_amdgcn_mfma_f32_16x16x32_bf16(af, wb[kc], acc[rf], 0, 0, 0);
        }

    int j = w*16 + l15;
    #pragma unroll
    for (int rf = 0; rf < CRF; ++rf)
        #pragma unroll
        for (int r = 0; r < 4; ++r) {
            int n = n0 + rf*16 + l4*4 + r;
            if (n < N) y[(size_t)n*HL + j] = (__bf16)acc[rf][r];
        }
}

// ---------------- fused GCN aggregation ----------------
// MODE 1: out bf16 (conv1 -> x2b). MODE 2: fused fc epilogue (conv2 -> d_out).
template<int MODE>
__global__ __launch_bounds__(256) void gcn_gather_k(
    const int* __restrict__ row_start, const int* __restrict__ src_s,
    const float* __restrict__ norm_s, const float* __restrict__ dinv,
    const __bf16* __restrict__ y, const float* __restrict__ b,
    __bf16* __restrict__ outb,
    const float* __restrict__ fcW, const float* __restrict__ fcb,
    float* __restrict__ fcout, int N)
{
    __shared__ float xrow[4][HL];
    const int tid = threadIdx.x;
    int gt = blockIdx.x*256 + tid;
    int n = gt >> 6, lane = gt & 63;
    bool act = (n < N);
    float ax = 0.f, ay = 0.f;
    if (act) {
        const int beg = row_start[n], end = row_start[n+1];
        int p = beg;
        for (; p + 4 <= end; p += 4) {
            int   s0 = src_s[p+0], s1 = src_s[p+1], s2 = src_s[p+2], s3 = src_s[p+3];
            float w0 = norm_s[p+0], w1 = norm_s[p+1], w2 = norm_s[p+2], w3 = norm_s[p+3];
            bf16x2 v0 = *reinterpret_cast<const bf16x2*>(y + (size_t)s0*HL + lane*2);
            bf16x2 v1 = *reinterpret_cast<const bf16x2*>(y + (size_t)s1*HL + lane*2);
            bf16x2 v2 = *reinterpret_cast<const bf16x2*>(y + (size_t)s2*HL + lane*2);
            bf16x2 v3 = *reinterpret_cast<const bf16x2*>(y + (size_t)s3*HL + lane*2);
            ax = fmaf(w0, (float)v0[0], ax); ay = fmaf(w0, (float)v0[1], ay);
            ax = fmaf(w1, (float)v1[0], ax); ay = fmaf(w1, (float)v1[1], ay);
            ax = fmaf(w2, (float)v2[0], ax); ay = fmaf(w2, (float)v2[1], ay);
            ax = fmaf(w3, (float)v3[0], ax); ay = fmaf(w3, (float)v3[1], ay);
        }
        for (; p < end; ++p) {
            int s = src_s[p];
            float nrm = norm_s[p];
            bf16x2 v = *reinterpret_cast<const bf16x2*>(y + (size_t)s*HL + lane*2);
            ax = fmaf(nrm, (float)v[0], ax);
            ay = fmaf(nrm, (float)v[1], ay);
        }
        float di = dinv[n];
        float sl = di*di;
        bf16x2 vs = *reinterpret_cast<const bf16x2*>(y + (size_t)n*HL + lane*2);
        ax = fmaf(sl, (float)vs[0], ax);
        ay = fmaf(sl, (float)vs[1], ay);
        float2 bb = *reinterpret_cast<const float2*>(b + lane*2);
        ax = fmaxf(ax + bb.x, 0.f);
        ay = fmaxf(ay + bb.y, 0.f);
    }
    if (MODE == 1) {
        if (act) {
            bf16x2 o;
            o[0] = (__bf16)ax; o[1] = (__bf16)ay;
            *reinterpret_cast<bf16x2*>(outb + (size_t)n*HL + lane*2) = o;
        }
    } else {
        int nq = tid >> 6;
        xrow[nq][lane*2]     = ax;
        xrow[nq][lane*2 + 1] = ay;
        __syncthreads();
        if (tid < 64) {
            int q = tid >> 4, o = tid & 15;
            int nn = blockIdx.x*4 + q;
            if (nn < N) {
                float a = fcb[o];
                #pragma unroll 8
                for (int k = 0; k < HL; ++k)
                    a = fmaf(xrow[q][k], fcW[k*OUTF + o], a);
                fcout[(size_t)nn*OUTF + o] = a;
            }
        }
    }
}

extern "C" void kernel_launch(void* const* d_in, const int* in_sizes, int n_in,
                              void* d_out, int out_size, void* d_ws, size_t ws_size,
                              hipStream_t stream)
{
    const int*   x_tokens = (const int*)d_in[0];
    const int*   lengths  = (const int*)d_in[1];
    const int*   eidx     = (const int*)d_in[2];
    const float* ew       = (const float*)d_in[3];
    const float* emb      = (const float*)d_in[4];
    const float* W_ih     = (const float*)d_in[5];
    const float* W_hh     = (const float*)d_in[6];
    const float* b_ih     = (const float*)d_in[7];
    const float* b_hh     = (const float*)d_in[8];
    const float* c1W      = (const float*)d_in[9];
    const float* c1b      = (const float*)d_in[10];
    const float* c2W      = (const float*)d_in[11];
    const float* c2b      = (const float*)d_in[12];
    const float* fcW      = (const float*)d_in[13];
    const float* fcb      = (const float*)d_in[14];
    float* out = (float*)d_out;

    const int* esrc = eidx;
    const int* edst = eidx + NEDGE;

    char* ws = (char*)d_ws;
    size_t off = 0;
    auto take = [&](size_t bytes) -> char* {
        char* p = ws + off;
        off = (off + bytes + 255) & ~(size_t)255;
        return p;
    };
    const size_t NH = (size_t)N_NODES * HL * sizeof(float);
    __bf16* embb = (__bf16*)take((size_t)(N_NODES + 1) * EMBD * sizeof(__bf16));
    __bf16* WTp  = (__bf16*)take((size_t)KTOT * G4 * sizeof(__bf16));
    __bf16* wc1b = (__bf16*)take((size_t)HL * HL * sizeof(__bf16));
    __bf16* wc2b = (__bf16*)take((size_t)HL * HL * sizeof(__bf16));
    float* bsum  = (float*)take((size_t)G4 * sizeof(float));
    float* hLst  = (float*)take(NH);
    __bf16* ybf  = (__bf16*)take((size_t)N_NODES * HL * sizeof(__bf16));
    __bf16* x2b  = (__bf16*)take((size_t)N_NODES * HL * sizeof(__bf16));
    float* degb  = (float*)take((size_t)N_NODES * sizeof(float));
    float* dinvb = (float*)take((size_t)N_NODES * sizeof(float));
    int*   cntb  = (int*)  take((size_t)N_NODES * sizeof(int));
    int*   rowst = (int*)  take((size_t)(N_NODES + 1) * sizeof(int));
    int*   srcS  = (int*)  take((size_t)NEDGE * sizeof(int));
    float* nrmS  = (float*)take((size_t)NEDGE * sizeof(float));
    int*   auxb  = (int*)  take((size_t)(3 + NBCSR) * sizeof(int));

    hipMemsetAsync(degb, 0, (size_t)N_NODES * sizeof(float), stream);
    hipMemsetAsync(cntb, 0, (size_t)N_NODES * sizeof(int), stream);
    hipMemsetAsync(auxb, 0, (size_t)(3 + NBCSR) * sizeof(int), stream);

    prep_all<<<PREPBLK, 256, 0, stream>>>(emb, embb, W_ih, W_hh, WTp,
                                          c1W, wc1b, c2W, wc2b, b_ih, b_hh, bsum);

    // LSTM (blocks 0-249) + CSR build (blocks 250-499) in one launch
    lstm_csr<<<NBLSTM + NBCSR, 512, 0, stream>>>(
        x_tokens, lengths, embb, WTp, bsum, hLst,
        esrc, edst, ew, cntb, degb, dinvb, rowst, srcS, nrmS, auxb);

    const int gathBlocks = (N_NODES*64 + 255)/256;   // 5000

    gemm_mfma<false><<<NCBLK, 512, 0, stream>>>(hLst, wc1b, ybf, N_NODES);
    gcn_gather_k<1><<<gathBlocks, 256, 0, stream>>>(rowst, srcS, nrmS, dinvb, ybf,
                                                    c1b, x2b, nullptr, nullptr, nullptr, N_NODES);
    gemm_mfma<true><<<NCBLK, 512, 0, stream>>>(x2b, wc2b, ybf, N_NODES);
    gcn_gather_k<2><<<gathBlocks, 256, 0, stream>>>(rowst, srcS, nrmS, dinvb, ybf,
                                                    c2b, nullptr, fcW, fcb, out, N_NODES);
}

// Round 10
// 392.744 us; speedup vs baseline: 11.5420x; 1.0236x over previous
//
#include <hip/hip_runtime.h>
#include <math.h>

#define N_NODES 20000
#define SEQ_T   24
#define EMBD    64
#define HL      128     // H_LSTM
#define OUTF    16
#define NEDGE   640000
#define G4      512     // 4*HL
#define KTOT    192     // EMBD + HL
#define ROWS    80      // rows per LSTM block (250 * 80 = 20000 exactly, 1 block/CU)
#define RF      5       // ROWS/16 row-fragments
#define NBLSTM  250
#define LDA     232     // LSTM A-tile leading dim (bf16)
#define WSTRIDE 12288   // per-wave LSTM weight chunk (24 KB)

// conv GEMM tiling
#define CROWS   64
#define CRF     4
#define NCBLK   313     // ceil(20000/64)
#define CPAD    136

typedef __bf16 bf16x8 __attribute__((ext_vector_type(8)));
typedef __bf16 bf16x2 __attribute__((ext_vector_type(2)));
typedef float  f32x4  __attribute__((ext_vector_type(4)));

__device__ __forceinline__ float4 ld4(const float* p){ return *reinterpret_cast<const float4*>(p); }
__device__ __forceinline__ void st4(float* p, float4 v){ *reinterpret_cast<float4*>(p) = v; }

#define LOG2E 1.44269504f

// ---------------- fused prep: embb + WTp + conv1/conv2 packs + bias ----------------
#define S_EMB   320016                  // (20001*64)/4 threads, 4 elems each
#define S_WTP   (S_EMB + KTOT*G4)       // + 98304
#define S_C1    (S_WTP + 16384)
#define S_C2    (S_C1 + 16384)
#define S_BIAS  (S_C2 + G4)
#define PREPBLK ((S_BIAS + 255)/256)

__global__ __launch_bounds__(256) void prep_all(
    const float* __restrict__ emb,  __bf16* __restrict__ embb,
    const float* __restrict__ Wih,  const float* __restrict__ Whh,
    __bf16* __restrict__ WTp,
    const float* __restrict__ c1W,  __bf16* __restrict__ wc1b,
    const float* __restrict__ c2W,  __bf16* __restrict__ wc2b,
    const float* __restrict__ bi,   const float* __restrict__ bh,
    float* __restrict__ bs)
{
    int gid = blockIdx.x*256 + threadIdx.x;
    if (gid < S_EMB) {
        int i4 = gid*4;
        float4 v = ld4(emb + i4);
        embb[i4+0] = (__bf16)v.x;
        embb[i4+1] = (__bf16)v.y;
        embb[i4+2] = (__bf16)v.z;
        embb[i4+3] = (__bf16)v.w;
    } else if (gid < S_WTP) {
        int idx = gid - S_EMB;
        int ko = idx & 31;
        int c  = (idx >> 5) & 15;
        int gt = (idx >> 9) & 3;
        int kc = (idx >> 11) % 6;
        int w  = idx / WSTRIDE;
        int g  = gt*HL + w*16 + c;
        int kk = kc*32 + ko;
        float v = (kk < EMBD) ? Wih[g*EMBD + kk] : Whh[g*HL + (kk - EMBD)];
        WTp[idx] = (__bf16)v;
    } else if (gid < S_C2) {
        bool c2 = (gid >= S_C1);
        int idx = gid - (c2 ? S_C1 : S_WTP);
        const float* W = c2 ? c2W : c1W;
        __bf16* dst = c2 ? wc2b : wc1b;
        int ko = idx & 31;
        int c  = (idx >> 5) & 15;
        int kc = (idx >> 9) & 3;
        int w  = idx >> 11;
        int g  = w*16 + c;
        int k  = kc*32 + ko;
        dst[idx] = (__bf16)W[k*HL + g];
    } else if (gid < S_BIAS) {
        int i = gid - S_C2;
        bs[i] = bi[i] + bh[i];
    }
}

// ---------------- fused LSTM (r8 measured-best: 180 us) ----------------
// 512 thr = 8 waves; wave w owns cols [w*16, w*16+16) of all 4 gates; weights in regs
// (96 VGPR/lane). A-tile [80][232] bf16: cols 0..63 emb(t), 64..191 h(t-1) in place.
__global__ __launch_bounds__(512, 2) void lstm_fused(
    const int* __restrict__ tokens, const int* __restrict__ lengths,
    const __bf16* __restrict__ embb, const __bf16* __restrict__ WTp,
    const float* __restrict__ bsum, float* __restrict__ hlast)
{
    __shared__ __align__(16) __bf16 a_lds[ROWS][LDA];
    __shared__ int tok_lds[ROWS*SEQ_T];
    __shared__ int len_lds[ROWS];

    const int tid = threadIdx.x;
    const int n0  = blockIdx.x * ROWS;
    const int w   = tid >> 6;       // 0..7
    const int l   = tid & 63;
    const int l15 = l & 15, l4 = l >> 4;

    #pragma unroll
    for (int i = 0; i < 4; ++i) {
        int idx = tid + 512*i;
        if (idx < ROWS*SEQ_T) tok_lds[idx] = tokens[n0*SEQ_T + idx];
    }
    if (tid < ROWS) len_lds[tid] = lengths[n0 + tid];

    // zero h region (cols 64..191)
    #pragma unroll
    for (int i = 0; i < 3; ++i) {
        int idx = tid + 512*i;
        if (idx < ROWS*16) {
            int row = idx >> 4, s = idx & 15;
            *reinterpret_cast<uint4*>(&a_lds[row][EMBD + s*8]) = make_uint4(0,0,0,0);
        }
    }

    float bias_v[4];
    #pragma unroll
    for (int gt = 0; gt < 4; ++gt)
        bias_v[gt] = bsum[gt*HL + w*16 + l15];

    bf16x8 wreg[6][4];
    {
        const __bf16* wbase = WTp + (size_t)w * WSTRIDE;
        #pragma unroll
        for (int kc = 0; kc < 6; ++kc)
            #pragma unroll
            for (int gt = 0; gt < 4; ++gt)
                wreg[kc][gt] = *reinterpret_cast<const bf16x8*>(
                    &wbase[(size_t)(((kc*4 + gt)*16 + l15)*32) + l4*8]);
    }

    f32x4 acc[RF][4];
    float c_reg[RF][4];
    {
        f32x4 zz = {0.f,0.f,0.f,0.f};
        #pragma unroll
        for (int rf = 0; rf < RF; ++rf) {
            #pragma unroll
            for (int gt = 0; gt < 4; ++gt) acc[rf][gt] = zz;
            #pragma unroll
            for (int r = 0; r < 4; ++r) c_reg[rf][r] = 0.f;
        }
    }

    for (int t = 0; t < SEQ_T; ++t) {
        #pragma unroll
        for (int i = 0; i < 2; ++i) {
            int idx = tid + 512*i;
            if (idx < ROWS*8) {
                int row = idx >> 3, sl = idx & 7;
                int tok = tok_lds[row*SEQ_T + t];
                *reinterpret_cast<uint4*>(&a_lds[row][sl*8]) =
                    *reinterpret_cast<const uint4*>(&embb[(size_t)tok*EMBD + sl*8]);
            }
        }
        __syncthreads();

        #pragma unroll
        for (int kc = 0; kc < 6; ++kc)
            #pragma unroll
            for (int rf = 0; rf < RF; ++rf) {
                bf16x8 af = *reinterpret_cast<const bf16x8*>(
                    &a_lds[rf*16 + l15][kc*32 + l4*8]);
                #pragma unroll
                for (int gt = 0; gt < 4; ++gt)
                    acc[rf][gt] = __builtin_amdgcn_mfma_f32_16x16x32_bf16(
                        af, wreg[kc][gt], acc[rf][gt], 0, 0, 0);
            }
        __syncthreads();

        // 8-trans epilogue: sig(a)*tanh(b) = (e2b-1)*rcp((1+e^-a)(e2b+1))
        #pragma unroll
        for (int rf = 0; rf < RF; ++rf) {
            f32x4 zi4 = acc[rf][0], zf4 = acc[rf][1];
            f32x4 zg4 = acc[rf][2], zo4 = acc[rf][3];
            #pragma unroll
            for (int r = 0; r < 4; ++r) {
                int row = rf*16 + l4*4 + r;
                float zi = zi4[r] + bias_v[0];
                float zf = zf4[r] + bias_v[1];
                float zg = zg4[r] + bias_v[2];
                float zo = zo4[r] + bias_v[3];
                float ef = __builtin_amdgcn_exp2f(-LOG2E*zf);
                float ei = __builtin_amdgcn_exp2f(-LOG2E*zi);
                float eg = __builtin_amdgcn_exp2f(2.0f*LOG2E*zg);
                float sf  = __builtin_amdgcn_rcpf(1.0f + ef);
                float rig = __builtin_amdgcn_rcpf((1.0f + ei)*(eg + 1.0f));
                float cc = sf*c_reg[rf][r] + (eg - 1.0f)*rig;
                c_reg[rf][r] = cc;
                float eo = __builtin_amdgcn_exp2f(-LOG2E*zo);
                float ec = __builtin_amdgcn_exp2f(2.0f*LOG2E*cc);
                float rh = __builtin_amdgcn_rcpf((1.0f + eo)*(ec + 1.0f));
                float h = (ec - 1.0f)*rh;
                int j = w*16 + l15;
                a_lds[row][EMBD + j] = (__bf16)h;
                if (len_lds[row] == t + 1)
                    __builtin_nontemporal_store(h, &hlast[(size_t)(n0 + row)*HL + j]);
            }
            f32x4 zz = {0.f,0.f,0.f,0.f};
            acc[rf][0] = zz; acc[rf][1] = zz; acc[rf][2] = zz; acc[rf][3] = zz;
        }
    }
}

// ---------------- CSR build (separate kernels, r8 measured ~45 us) ----------------

__global__ __launch_bounds__(256) void count_deg(const int* __restrict__ dst,
                                                 const float* __restrict__ w,
                                                 int* __restrict__ cnt,
                                                 float* __restrict__ deg, int E)
{
    int e = blockIdx.x*256 + threadIdx.x;
    if (e < E) {
        int d = dst[e];
        atomicAdd(&cnt[d], 1);
        atomicAdd(&deg[d], w[e]);
    }
}

__global__ __launch_bounds__(1024) void scan_dinv(const int* __restrict__ cnt,
                                                  const float* __restrict__ deg,
                                                  int* __restrict__ row_start,
                                                  float* __restrict__ dinv)
{
    __shared__ int part[1024];
    const int t = threadIdx.x;
    const int CH = (N_NODES + 1023) / 1024;   // 20
    int beg = t*CH, end = min(beg + CH, N_NODES);
    int s = 0;
    for (int i = beg; i < end; ++i) {
        s += cnt[i];
        dinv[i] = rsqrtf(deg[i] + 1.0f);
    }
    part[t] = s;
    __syncthreads();
    for (int off = 1; off < 1024; off <<= 1) {
        int v = (t >= off) ? part[t - off] : 0;
        __syncthreads();
        part[t] += v;
        __syncthreads();
    }
    int base = (t == 0) ? 0 : part[t - 1];
    for (int i = beg; i < end; ++i) { row_start[i] = base; base += cnt[i]; }
    if (t == 1023) row_start[N_NODES] = part[1023];
}

__global__ __launch_bounds__(256) void fill_csr(const int* __restrict__ src,
                                                const int* __restrict__ dst,
                                                const float* __restrict__ w,
                                                const float* __restrict__ dinv,
                                                const int* __restrict__ row_start,
                                                int* __restrict__ cnt,
                                                int* __restrict__ src_s,
                                                float* __restrict__ norm_s, int E)
{
    int e = blockIdx.x*256 + threadIdx.x;
    if (e >= E) return;
    int d = dst[e];
    int pos = row_start[d] + atomicSub(&cnt[d], 1) - 1;
    int s = src[e];
    src_s[pos]  = s;
    norm_s[pos] = dinv[s] * w[e] * dinv[d];
}

// ---------------- conv GEMM: y_bf16[N][128] = bf16(x[N][128]) @ Wb ----------------
template<bool BF16IN>
__global__ __launch_bounds__(512) void gemm_mfma(const void* __restrict__ xin,
                                                 const __bf16* __restrict__ Wb,
                                                 __bf16* __restrict__ y, int N)
{
    __shared__ __align__(16) __bf16 a_lds[CROWS][CPAD];
    const int tid = threadIdx.x;
    const int n0 = blockIdx.x * CROWS;
    const int w = tid >> 6, l = tid & 63;
    const int l15 = l & 15, l4 = l >> 4;

    {
        int row = tid >> 3, sl = tid & 7;   // 16 elems per (row, sl)
        int n = n0 + row;
        if (BF16IN) {
            const __bf16* xb = (const __bf16*)xin;
            uint4 v0 = make_uint4(0,0,0,0), v1 = make_uint4(0,0,0,0);
            if (n < N) {
                v0 = *reinterpret_cast<const uint4*>(xb + (size_t)n*HL + sl*16);
                v1 = *reinterpret_cast<const uint4*>(xb + (size_t)n*HL + sl*16 + 8);
            }
            *reinterpret_cast<uint4*>(&a_lds[row][sl*16])     = v0;
            *reinterpret_cast<uint4*>(&a_lds[row][sl*16 + 8]) = v1;
        } else {
            const float* x = (const float*)xin;
            __bf16 tmp[16];
            if (n < N) {
                #pragma unroll
                for (int q = 0; q < 4; ++q) {
                    float4 v = ld4(x + (size_t)n*HL + sl*16 + q*4);
                    tmp[q*4+0] = (__bf16)v.x; tmp[q*4+1] = (__bf16)v.y;
                    tmp[q*4+2] = (__bf16)v.z; tmp[q*4+3] = (__bf16)v.w;
                }
            } else {
                #pragma unroll
                for (int q = 0; q < 16; ++q) tmp[q] = (__bf16)0.f;
            }
            *reinterpret_cast<uint4*>(&a_lds[row][sl*16])     = *reinterpret_cast<uint4*>(&tmp[0]);
            *reinterpret_cast<uint4*>(&a_lds[row][sl*16 + 8]) = *reinterpret_cast<uint4*>(&tmp[8]);
        }
    }

    bf16x8 wb[4];
    #pragma unroll
    for (int kc = 0; kc < 4; ++kc)
        wb[kc] = *reinterpret_cast<const bf16x8*>(
            &Wb[(size_t)(((w*4 + kc)*16 + l15)*32) + l4*8]);

    f32x4 acc[CRF];
    {
        f32x4 zz = {0.f,0.f,0.f,0.f};
        #pragma unroll
        for (int rf = 0; rf < CRF; ++rf) acc[rf] = zz;
    }
    __syncthreads();

    #pragma unroll
    for (int kc = 0; kc < 4; ++kc)
        #pragma unroll
        for (int rf = 0; rf < CRF; ++rf) {
            bf16x8 af = *reinterpret_cast<const bf16x8*>(
                &a_lds[rf*16 + l15][kc*32 + l4*8]);
            acc[rf] = __builtin_amdgcn_mfma_f32_16x16x32_bf16(af, wb[kc], acc[rf], 0, 0, 0);
        }

    int j = w*16 + l15;
    #pragma unroll
    for (int rf = 0; rf < CRF; ++rf)
        #pragma unroll
        for (int r = 0; r < 4; ++r) {
            int n = n0 + rf*16 + l4*4 + r;
            if (n < N) y[(size_t)n*HL + j] = (__bf16)acc[rf][r];
        }
}

// ---------------- fused GCN aggregation ----------------
// MODE 1: out bf16 (conv1 -> x2b). MODE 2: fused fc epilogue (conv2 -> d_out).
template<int MODE>
__global__ __launch_bounds__(256) void gcn_gather_k(
    const int* __restrict__ row_start, const int* __restrict__ src_s,
    const float* __restrict__ norm_s, const float* __restrict__ dinv,
    const __bf16* __restrict__ y, const float* __restrict__ b,
    __bf16* __restrict__ outb,
    const float* __restrict__ fcW, const float* __restrict__ fcb,
    float* __restrict__ fcout, int N)
{
    __shared__ float xrow[4][HL];
    const int tid = threadIdx.x;
    int gt = blockIdx.x*256 + tid;
    int n = gt >> 6, lane = gt & 63;
    bool act = (n < N);
    float ax = 0.f, ay = 0.f;
    if (act) {
        const int beg = row_start[n], end = row_start[n+1];
        int p = beg;
        for (; p + 4 <= end; p += 4) {
            int   s0 = src_s[p+0], s1 = src_s[p+1], s2 = src_s[p+2], s3 = src_s[p+3];
            float w0 = norm_s[p+0], w1 = norm_s[p+1], w2 = norm_s[p+2], w3 = norm_s[p+3];
            bf16x2 v0 = *reinterpret_cast<const bf16x2*>(y + (size_t)s0*HL + lane*2);
            bf16x2 v1 = *reinterpret_cast<const bf16x2*>(y + (size_t)s1*HL + lane*2);
            bf16x2 v2 = *reinterpret_cast<const bf16x2*>(y + (size_t)s2*HL + lane*2);
            bf16x2 v3 = *reinterpret_cast<const bf16x2*>(y + (size_t)s3*HL + lane*2);
            ax = fmaf(w0, (float)v0[0], ax); ay = fmaf(w0, (float)v0[1], ay);
            ax = fmaf(w1, (float)v1[0], ax); ay = fmaf(w1, (float)v1[1], ay);
            ax = fmaf(w2, (float)v2[0], ax); ay = fmaf(w2, (float)v2[1], ay);
            ax = fmaf(w3, (float)v3[0], ax); ay = fmaf(w3, (float)v3[1], ay);
        }
        for (; p < end; ++p) {
            int s = src_s[p];
            float nrm = norm_s[p];
            bf16x2 v = *reinterpret_cast<const bf16x2*>(y + (size_t)s*HL + lane*2);
            ax = fmaf(nrm, (float)v[0], ax);
            ay = fmaf(nrm, (float)v[1], ay);
        }
        float di = dinv[n];
        float sl = di*di;
        bf16x2 vs = *reinterpret_cast<const bf16x2*>(y + (size_t)n*HL + lane*2);
        ax = fmaf(sl, (float)vs[0], ax);
        ay = fmaf(sl, (float)vs[1], ay);
        float2 bb = *reinterpret_cast<const float2*>(b + lane*2);
        ax = fmaxf(ax + bb.x, 0.f);
        ay = fmaxf(ay + bb.y, 0.f);
    }
    if (MODE == 1) {
        if (act) {
            bf16x2 o;
            o[0] = (__bf16)ax; o[1] = (__bf16)ay;
            *reinterpret_cast<bf16x2*>(outb + (size_t)n*HL + lane*2) = o;
        }
    } else {
        int nq = tid >> 6;
        xrow[nq][lane*2]     = ax;
        xrow[nq][lane*2 + 1] = ay;
        __syncthreads();
        if (tid < 64) {
            int q = tid >> 4, o = tid & 15;
            int nn = blockIdx.x*4 + q;
            if (nn < N) {
                float a = fcb[o];
                #pragma unroll 8
                for (int k = 0; k < HL; ++k)
                    a = fmaf(xrow[q][k], fcW[k*OUTF + o], a);
                fcout[(size_t)nn*OUTF + o] = a;
            }
        }
    }
}

extern "C" void kernel_launch(void* const* d_in, const int* in_sizes, int n_in,
                              void* d_out, int out_size, void* d_ws, size_t ws_size,
                              hipStream_t stream)
{
    const int*   x_tokens = (const int*)d_in[0];
    const int*   lengths  = (const int*)d_in[1];
    const int*   eidx     = (const int*)d_in[2];
    const float* ew       = (const float*)d_in[3];
    const float* emb      = (const float*)d_in[4];
    const float* W_ih     = (const float*)d_in[5];
    const float* W_hh     = (const float*)d_in[6];
    const float* b_ih     = (const float*)d_in[7];
    const float* b_hh     = (const float*)d_in[8];
    const float* c1W      = (const float*)d_in[9];
    const float* c1b      = (const float*)d_in[10];
    const float* c2W      = (const float*)d_in[11];
    const float* c2b      = (const float*)d_in[12];
    const float* fcW      = (const float*)d_in[13];
    const float* fcb      = (const float*)d_in[14];
    float* out = (float*)d_out;

    const int* esrc = eidx;
    const int* edst = eidx + NEDGE;

    char* ws = (char*)d_ws;
    size_t off = 0;
    auto take = [&](size_t bytes) -> char* {
        char* p = ws + off;
        off = (off + bytes + 255) & ~(size_t)255;
        return p;
    };
    const size_t NH = (size_t)N_NODES * HL * sizeof(float);
    __bf16* embb = (__bf16*)take((size_t)(N_NODES + 1) * EMBD * sizeof(__bf16));
    __bf16* WTp  = (__bf16*)take((size_t)KTOT * G4 * sizeof(__bf16));
    __bf16* wc1b = (__bf16*)take((size_t)HL * HL * sizeof(__bf16));
    __bf16* wc2b = (__bf16*)take((size_t)HL * HL * sizeof(__bf16));
    float* bsum  = (float*)take((size_t)G4 * sizeof(float));
    float* hLst  = (float*)take(NH);
    __bf16* ybf  = (__bf16*)take((size_t)N_NODES * HL * sizeof(__bf16));
    __bf16* x2b  = (__bf16*)take((size_t)N_NODES * HL * sizeof(__bf16));
    float* degb  = (float*)take((size_t)N_NODES * sizeof(float));
    float* dinvb = (float*)take((size_t)N_NODES * sizeof(float));
    int*   cntb  = (int*)  take((size_t)N_NODES * sizeof(int));
    int*   rowst = (int*)  take((size_t)(N_NODES + 1) * sizeof(int));
    int*   srcS  = (int*)  take((size_t)NEDGE * sizeof(int));
    float* nrmS  = (float*)take((size_t)NEDGE * sizeof(float));

    hipMemsetAsync(degb, 0, (size_t)N_NODES * sizeof(float), stream);
    hipMemsetAsync(cntb, 0, (size_t)N_NODES * sizeof(int), stream);

    prep_all<<<PREPBLK, 256, 0, stream>>>(emb, embb, W_ih, W_hh, WTp,
                                          c1W, wc1b, c2W, wc2b, b_ih, b_hh, bsum);

    count_deg<<<NEDGE/256, 256, 0, stream>>>(edst, ew, cntb, degb, NEDGE);
    scan_dinv<<<1, 1024, 0, stream>>>(cntb, degb, rowst, dinvb);
    fill_csr<<<NEDGE/256, 256, 0, stream>>>(esrc, edst, ew, dinvb, rowst, cntb,
                                            srcS, nrmS, NEDGE);

    lstm_fused<<<NBLSTM, 512, 0, stream>>>(x_tokens, lengths, embb, WTp, bsum, hLst);

    const int gathBlocks = (N_NODES*64 + 255)/256;   // 5000

    gemm_mfma<false><<<NCBLK, 512, 0, stream>>>(hLst, wc1b, ybf, N_NODES);
    gcn_gather_k<1><<<gathBlocks, 256, 0, stream>>>(rowst, srcS, nrmS, dinvb, ybf,
                                                    c1b, x2b, nullptr, nullptr, nullptr, N_NODES);
    gemm_mfma<true><<<NCBLK, 512, 0, stream>>>(x2b, wc2b, ybf, N_NODES);
    gcn_gather_k<2><<<gathBlocks, 256, 0, stream>>>(rowst, srcS, nrmS, dinvb, ybf,
                                                    c2b, nullptr, fcW, fcb, out, N_NODES);
}

// Round 11
// 381.440 us; speedup vs baseline: 11.8841x; 1.0296x over previous
//
#include <hip/hip_runtime.h>
#include <math.h>

#define N_NODES 20000
#define SEQ_T   24
#define EMBD    64
#define HL      128     // H_LSTM
#define OUTF    16
#define NEDGE   640000
#define G4      512     // 4*HL
#define KTOT    192     // EMBD + HL
#define ROWS    80      // rows per LSTM block (250 * 80 = 20000 exactly, 1 block/CU)
#define RF      5       // ROWS/16 row-fragments
#define NBLSTM  250
#define LDA     232     // LSTM A-tile leading dim (bf16)
#define WSTRIDE 12288   // per-wave LSTM weight chunk (24 KB)

// CSR fused kernel
#define NBCSR   250
#define EPB     (NEDGE/NBCSR)   // 2560 edges/block
#define NPB     (N_NODES/NBCSR) // 80 nodes/block

// conv GEMM tiling
#define CROWS   64
#define CRF     4
#define NCBLK   313     // ceil(20000/64)
#define CPAD    136

typedef __bf16 bf16x8 __attribute__((ext_vector_type(8)));
typedef __bf16 bf16x2 __attribute__((ext_vector_type(2)));
typedef float  f32x4  __attribute__((ext_vector_type(4)));

__device__ __forceinline__ float4 ld4(const float* p){ return *reinterpret_cast<const float4*>(p); }
__device__ __forceinline__ void st4(float* p, float4 v){ *reinterpret_cast<float4*>(p) = v; }

#define LOG2E 1.44269504f

// ---------------- fused prep: embb + WTp + conv1/conv2 packs + bias ----------------
#define S_EMB   320016                  // (20001*64)/4 threads, 4 elems each
#define S_WTP   (S_EMB + KTOT*G4)       // + 98304
#define S_C1    (S_WTP + 16384)
#define S_C2    (S_C1 + 16384)
#define S_BIAS  (S_C2 + G4)
#define PREPBLK ((S_BIAS + 255)/256)

__global__ __launch_bounds__(256) void prep_all(
    const float* __restrict__ emb,  __bf16* __restrict__ embb,
    const float* __restrict__ Wih,  const float* __restrict__ Whh,
    __bf16* __restrict__ WTp,
    const float* __restrict__ c1W,  __bf16* __restrict__ wc1b,
    const float* __restrict__ c2W,  __bf16* __restrict__ wc2b,
    const float* __restrict__ bi,   const float* __restrict__ bh,
    float* __restrict__ bs)
{
    int gid = blockIdx.x*256 + threadIdx.x;
    if (gid < S_EMB) {
        int i4 = gid*4;
        float4 v = ld4(emb + i4);
        embb[i4+0] = (__bf16)v.x;
        embb[i4+1] = (__bf16)v.y;
        embb[i4+2] = (__bf16)v.z;
        embb[i4+3] = (__bf16)v.w;
    } else if (gid < S_WTP) {
        int idx = gid - S_EMB;
        int ko = idx & 31;
        int c  = (idx >> 5) & 15;
        int gt = (idx >> 9) & 3;
        int kc = (idx >> 11) % 6;
        int w  = idx / WSTRIDE;
        int g  = gt*HL + w*16 + c;
        int kk = kc*32 + ko;
        float v = (kk < EMBD) ? Wih[g*EMBD + kk] : Whh[g*HL + (kk - EMBD)];
        WTp[idx] = (__bf16)v;
    } else if (gid < S_C2) {
        bool c2 = (gid >= S_C1);
        int idx = gid - (c2 ? S_C1 : S_WTP);
        const float* W = c2 ? c2W : c1W;
        __bf16* dst = c2 ? wc2b : wc1b;
        int ko = idx & 31;
        int c  = (idx >> 5) & 15;
        int kc = (idx >> 9) & 3;
        int w  = idx >> 11;
        int g  = w*16 + c;
        int k  = kc*32 + ko;
        dst[idx] = (__bf16)W[k*HL + g];
    } else if (gid < S_BIAS) {
        int i = gid - S_C2;
        bs[i] = bi[i] + bh[i];
    }
}

// ---------------- fused CSR build: one launch, 250 co-resident blocks ----------------
// Phase structure validated in r9 (standalone now, no LSTM contention).
__device__ __forceinline__ void gbar(int* ctr) {
    __syncthreads();
    if (threadIdx.x == 0) {
        __threadfence();
        atomicAdd(ctr, 1);
        while (atomicAdd(ctr, 0) < NBCSR) __builtin_amdgcn_s_sleep(8);
        __threadfence();
    }
    __syncthreads();
}

__global__ __launch_bounds__(512) void csr_fused(
    const int* __restrict__ esrc, const int* __restrict__ edst,
    const float* __restrict__ ew,
    int* __restrict__ cnt, float* __restrict__ deg, float* __restrict__ dinv,
    int* __restrict__ rank, int* __restrict__ row_start,
    int* __restrict__ src_s, float* __restrict__ norm_s, int* __restrict__ aux)
{
    __shared__ int scratch[512];
    const int tid = threadIdx.x;
    const int bid = blockIdx.x;
    const int e0 = bid * EPB;
    const int nodes0 = bid * NPB;

    // P1: count (rank saved) + weighted degree
    #pragma unroll
    for (int i = 0; i < EPB/512; ++i) {
        int e = e0 + tid + 512*i;
        int d = edst[e];
        rank[e] = atomicAdd(&cnt[d], 1);
        atomicAdd(&deg[d], ew[e]);
    }
    gbar(&aux[0]);

    // P2: dinv + block partial count
    if (tid == 0) scratch[511] = 0;
    __syncthreads();
    if (tid < NPB) {
        int n = nodes0 + tid;
        dinv[n] = rsqrtf(deg[n] + 1.0f);
        int lc = cnt[n];
        scratch[256 + tid] = lc;
        atomicAdd(&scratch[511], lc);
    }
    __syncthreads();
    if (tid == 0) aux[3 + bid] = scratch[511];
    gbar(&aux[1]);

    // P3: base = sum of partials < bid (from LDS), then serial local scan of 80
    if (tid < NBCSR) scratch[tid] = aux[3 + tid];
    __syncthreads();
    if (tid == 0) {
        int base = 0;
        for (int b = 0; b < bid; ++b) base += scratch[b];
        for (int i = 0; i < NPB; ++i) {
            row_start[nodes0 + i] = base;
            base += scratch[256 + i];
        }
        if (bid == NBCSR - 1) row_start[N_NODES] = base;
    }
    gbar(&aux[2]);

    // P4: fill, no atomics (pos = row_start[d] + rank[e])
    #pragma unroll
    for (int i = 0; i < EPB/512; ++i) {
        int e = e0 + tid + 512*i;
        int d = edst[e];
        int pos = row_start[d] + rank[e];
        int s = esrc[e];
        src_s[pos]  = s;
        norm_s[pos] = dinv[s] * ew[e] * dinv[d];
    }
}

// ---------------- fused LSTM (r8 measured-best: ~178 us) ----------------
__global__ __launch_bounds__(512, 2) void lstm_fused(
    const int* __restrict__ tokens, const int* __restrict__ lengths,
    const __bf16* __restrict__ embb, const __bf16* __restrict__ WTp,
    const float* __restrict__ bsum, float* __restrict__ hlast)
{
    __shared__ __align__(16) __bf16 a_lds[ROWS][LDA];
    __shared__ int tok_lds[ROWS*SEQ_T];
    __shared__ int len_lds[ROWS];

    const int tid = threadIdx.x;
    const int n0  = blockIdx.x * ROWS;
    const int w   = tid >> 6;       // 0..7
    const int l   = tid & 63;
    const int l15 = l & 15, l4 = l >> 4;

    #pragma unroll
    for (int i = 0; i < 4; ++i) {
        int idx = tid + 512*i;
        if (idx < ROWS*SEQ_T) tok_lds[idx] = tokens[n0*SEQ_T + idx];
    }
    if (tid < ROWS) len_lds[tid] = lengths[n0 + tid];

    #pragma unroll
    for (int i = 0; i < 3; ++i) {
        int idx = tid + 512*i;
        if (idx < ROWS*16) {
            int row = idx >> 4, s = idx & 15;
            *reinterpret_cast<uint4*>(&a_lds[row][EMBD + s*8]) = make_uint4(0,0,0,0);
        }
    }

    float bias_v[4];
    #pragma unroll
    for (int gt = 0; gt < 4; ++gt)
        bias_v[gt] = bsum[gt*HL + w*16 + l15];

    bf16x8 wreg[6][4];
    {
        const __bf16* wbase = WTp + (size_t)w * WSTRIDE;
        #pragma unroll
        for (int kc = 0; kc < 6; ++kc)
            #pragma unroll
            for (int gt = 0; gt < 4; ++gt)
                wreg[kc][gt] = *reinterpret_cast<const bf16x8*>(
                    &wbase[(size_t)(((kc*4 + gt)*16 + l15)*32) + l4*8]);
    }

    f32x4 acc[RF][4];
    float c_reg[RF][4];
    {
        f32x4 zz = {0.f,0.f,0.f,0.f};
        #pragma unroll
        for (int rf = 0; rf < RF; ++rf) {
            #pragma unroll
            for (int gt = 0; gt < 4; ++gt) acc[rf][gt] = zz;
            #pragma unroll
            for (int r = 0; r < 4; ++r) c_reg[rf][r] = 0.f;
        }
    }

    for (int t = 0; t < SEQ_T; ++t) {
        #pragma unroll
        for (int i = 0; i < 2; ++i) {
            int idx = tid + 512*i;
            if (idx < ROWS*8) {
                int row = idx >> 3, sl = idx & 7;
                int tok = tok_lds[row*SEQ_T + t];
                *reinterpret_cast<uint4*>(&a_lds[row][sl*8]) =
                    *reinterpret_cast<const uint4*>(&embb[(size_t)tok*EMBD + sl*8]);
            }
        }
        __syncthreads();

        #pragma unroll
        for (int kc = 0; kc < 6; ++kc)
            #pragma unroll
            for (int rf = 0; rf < RF; ++rf) {
                bf16x8 af = *reinterpret_cast<const bf16x8*>(
                    &a_lds[rf*16 + l15][kc*32 + l4*8]);
                #pragma unroll
                for (int gt = 0; gt < 4; ++gt)
                    acc[rf][gt] = __builtin_amdgcn_mfma_f32_16x16x32_bf16(
                        af, wreg[kc][gt], acc[rf][gt], 0, 0, 0);
            }
        __syncthreads();

        // 8-trans epilogue: sig(a)*tanh(b) = (e2b-1)*rcp((1+e^-a)(e2b+1))
        #pragma unroll
        for (int rf = 0; rf < RF; ++rf) {
            f32x4 zi4 = acc[rf][0], zf4 = acc[rf][1];
            f32x4 zg4 = acc[rf][2], zo4 = acc[rf][3];
            #pragma unroll
            for (int r = 0; r < 4; ++r) {
                int row = rf*16 + l4*4 + r;
                float zi = zi4[r] + bias_v[0];
                float zf = zf4[r] + bias_v[1];
                float zg = zg4[r] + bias_v[2];
                float zo = zo4[r] + bias_v[3];
                float ef = __builtin_amdgcn_exp2f(-LOG2E*zf);
                float ei = __builtin_amdgcn_exp2f(-LOG2E*zi);
                float eg = __builtin_amdgcn_exp2f(2.0f*LOG2E*zg);
                float sf  = __builtin_amdgcn_rcpf(1.0f + ef);
                float rig = __builtin_amdgcn_rcpf((1.0f + ei)*(eg + 1.0f));
                float cc = sf*c_reg[rf][r] + (eg - 1.0f)*rig;
                c_reg[rf][r] = cc;
                float eo = __builtin_amdgcn_exp2f(-LOG2E*zo);
                float ec = __builtin_amdgcn_exp2f(2.0f*LOG2E*cc);
                float rh = __builtin_amdgcn_rcpf((1.0f + eo)*(ec + 1.0f));
                float h = (ec - 1.0f)*rh;
                int j = w*16 + l15;
                a_lds[row][EMBD + j] = (__bf16)h;
                if (len_lds[row] == t + 1)
                    __builtin_nontemporal_store(h, &hlast[(size_t)(n0 + row)*HL + j]);
            }
            f32x4 zz = {0.f,0.f,0.f,0.f};
            acc[rf][0] = zz; acc[rf][1] = zz; acc[rf][2] = zz; acc[rf][3] = zz;
        }
    }
}

// ---------------- conv GEMM: y_bf16[N][128] = bf16(x[N][128]) @ Wb ----------------
template<bool BF16IN>
__global__ __launch_bounds__(512) void gemm_mfma(const void* __restrict__ xin,
                                                 const __bf16* __restrict__ Wb,
                                                 __bf16* __restrict__ y, int N)
{
    __shared__ __align__(16) __bf16 a_lds[CROWS][CPAD];
    const int tid = threadIdx.x;
    const int n0 = blockIdx.x * CROWS;
    const int w = tid >> 6, l = tid & 63;
    const int l15 = l & 15, l4 = l >> 4;

    {
        int row = tid >> 3, sl = tid & 7;   // 16 elems per (row, sl)
        int n = n0 + row;
        if (BF16IN) {
            const __bf16* xb = (const __bf16*)xin;
            uint4 v0 = make_uint4(0,0,0,0), v1 = make_uint4(0,0,0,0);
            if (n < N) {
                v0 = *reinterpret_cast<const uint4*>(xb + (size_t)n*HL + sl*16);
                v1 = *reinterpret_cast<const uint4*>(xb + (size_t)n*HL + sl*16 + 8);
            }
            *reinterpret_cast<uint4*>(&a_lds[row][sl*16])     = v0;
            *reinterpret_cast<uint4*>(&a_lds[row][sl*16 + 8]) = v1;
        } else {
            const float* x = (const float*)xin;
            __bf16 tmp[16];
            if (n < N) {
                #pragma unroll
                for (int q = 0; q < 4; ++q) {
                    float4 v = ld4(x + (size_t)n*HL + sl*16 + q*4);
                    tmp[q*4+0] = (__bf16)v.x; tmp[q*4+1] = (__bf16)v.y;
                    tmp[q*4+2] = (__bf16)v.z; tmp[q*4+3] = (__bf16)v.w;
                }
            } else {
                #pragma unroll
                for (int q = 0; q < 16; ++q) tmp[q] = (__bf16)0.f;
            }
            *reinterpret_cast<uint4*>(&a_lds[row][sl*16])     = *reinterpret_cast<uint4*>(&tmp[0]);
            *reinterpret_cast<uint4*>(&a_lds[row][sl*16 + 8]) = *reinterpret_cast<uint4*>(&tmp[8]);
        }
    }

    bf16x8 wb[4];
    #pragma unroll
    for (int kc = 0; kc < 4; ++kc)
        wb[kc] = *reinterpret_cast<const bf16x8*>(
            &Wb[(size_t)(((w*4 + kc)*16 + l15)*32) + l4*8]);

    f32x4 acc[CRF];
    {
        f32x4 zz = {0.f,0.f,0.f,0.f};
        #pragma unroll
        for (int rf = 0; rf < CRF; ++rf) acc[rf] = zz;
    }
    __syncthreads();

    #pragma unroll
    for (int kc = 0; kc < 4; ++kc)
        #pragma unroll
        for (int rf = 0; rf < CRF; ++rf) {
            bf16x8 af = *reinterpret_cast<const bf16x8*>(
                &a_lds[rf*16 + l15][kc*32 + l4*8]);
            acc[rf] = __builtin_amdgcn_mfma_f32_16x16x32_bf16(af, wb[kc], acc[rf], 0, 0, 0);
        }

    int j = w*16 + l15;
    #pragma unroll
    for (int rf = 0; rf < CRF; ++rf)
        #pragma unroll
        for (int r = 0; r < 4; ++r) {
            int n = n0 + rf*16 + l4*4 + r;
            if (n < N) y[(size_t)n*HL + j] = (__bf16)acc[rf][r];
        }
}

// ---------------- fused GCN aggregation ----------------
// MODE 1: out bf16 (conv1 -> x2b). MODE 2: fused fc epilogue (conv2 -> d_out).
template<int MODE>
__global__ __launch_bounds__(256) void gcn_gather_k(
    const int* __restrict__ row_start, const int* __restrict__ src_s,
    const float* __restrict__ norm_s, const float* __restrict__ dinv,
    const __bf16* __restrict__ y, const float* __restrict__ b,
    __bf16* __restrict__ outb,
    const float* __restrict__ fcW, const float* __restrict__ fcb,
    float* __restrict__ fcout, int N)
{
    __shared__ float xrow[4][HL];
    const int tid = threadIdx.x;
    int gt = blockIdx.x*256 + tid;
    int n = gt >> 6, lane = gt & 63;
    bool act = (n < N);
    float ax = 0.f, ay = 0.f;
    if (act) {
        const int beg = row_start[n], end = row_start[n+1];
        int p = beg;
        for (; p + 4 <= end; p += 4) {
            int   s0 = src_s[p+0], s1 = src_s[p+1], s2 = src_s[p+2], s3 = src_s[p+3];
            float w0 = norm_s[p+0], w1 = norm_s[p+1], w2 = norm_s[p+2], w3 = norm_s[p+3];
            bf16x2 v0 = *reinterpret_cast<const bf16x2*>(y + (size_t)s0*HL + lane*2);
            bf16x2 v1 = *reinterpret_cast<const bf16x2*>(y + (size_t)s1*HL + lane*2);
            bf16x2 v2 = *reinterpret_cast<const bf16x2*>(y + (size_t)s2*HL + lane*2);
            bf16x2 v3 = *reinterpret_cast<const bf16x2*>(y + (size_t)s3*HL + lane*2);
            ax = fmaf(w0, (float)v0[0], ax); ay = fmaf(w0, (float)v0[1], ay);
            ax = fmaf(w1, (float)v1[0], ax); ay = fmaf(w1, (float)v1[1], ay);
            ax = fmaf(w2, (float)v2[0], ax); ay = fmaf(w2, (float)v2[1], ay);
            ax = fmaf(w3, (float)v3[0], ax); ay = fmaf(w3, (float)v3[1], ay);
        }
        for (; p < end; ++p) {
            int s = src_s[p];
            float nrm = norm_s[p];
            bf16x2 v = *reinterpret_cast<const bf16x2*>(y + (size_t)s*HL + lane*2);
            ax = fmaf(nrm, (float)v[0], ax);
            ay = fmaf(nrm, (float)v[1], ay);
        }
        float di = dinv[n];
        float sl = di*di;
        bf16x2 vs = *reinterpret_cast<const bf16x2*>(y + (size_t)n*HL + lane*2);
        ax = fmaf(sl, (float)vs[0], ax);
        ay = fmaf(sl, (float)vs[1], ay);
        float2 bb = *reinterpret_cast<const float2*>(b + lane*2);
        ax = fmaxf(ax + bb.x, 0.f);
        ay = fmaxf(ay + bb.y, 0.f);
    }
    if (MODE == 1) {
        if (act) {
            bf16x2 o;
            o[0] = (__bf16)ax; o[1] = (__bf16)ay;
            *reinterpret_cast<bf16x2*>(outb + (size_t)n*HL + lane*2) = o;
        }
    } else {
        int nq = tid >> 6;
        xrow[nq][lane*2]     = ax;
        xrow[nq][lane*2 + 1] = ay;
        __syncthreads();
        if (tid < 64) {
            int q = tid >> 4, o = tid & 15;
            int nn = blockIdx.x*4 + q;
            if (nn < N) {
                float a = fcb[o];
                #pragma unroll 8
                for (int k = 0; k < HL; ++k)
                    a = fmaf(xrow[q][k], fcW[k*OUTF + o], a);
                fcout[(size_t)nn*OUTF + o] = a;
            }
        }
    }
}

extern "C" void kernel_launch(void* const* d_in, const int* in_sizes, int n_in,
                              void* d_out, int out_size, void* d_ws, size_t ws_size,
                              hipStream_t stream)
{
    const int*   x_tokens = (const int*)d_in[0];
    const int*   lengths  = (const int*)d_in[1];
    const int*   eidx     = (const int*)d_in[2];
    const float* ew       = (const float*)d_in[3];
    const float* emb      = (const float*)d_in[4];
    const float* W_ih     = (const float*)d_in[5];
    const float* W_hh     = (const float*)d_in[6];
    const float* b_ih     = (const float*)d_in[7];
    const float* b_hh     = (const float*)d_in[8];
    const float* c1W      = (const float*)d_in[9];
    const float* c1b      = (const float*)d_in[10];
    const float* c2W      = (const float*)d_in[11];
    const float* c2b      = (const float*)d_in[12];
    const float* fcW      = (const float*)d_in[13];
    const float* fcb      = (const float*)d_in[14];
    float* out = (float*)d_out;

    const int* esrc = eidx;
    const int* edst = eidx + NEDGE;

    char* ws = (char*)d_ws;
    size_t off = 0;
    auto take = [&](size_t bytes) -> char* {
        char* p = ws + off;
        off = (off + bytes + 255) & ~(size_t)255;
        return p;
    };
    const size_t NH = (size_t)N_NODES * HL * sizeof(float);
    __bf16* embb = (__bf16*)take((size_t)(N_NODES + 1) * EMBD * sizeof(__bf16));
    __bf16* WTp  = (__bf16*)take((size_t)KTOT * G4 * sizeof(__bf16));
    __bf16* wc1b = (__bf16*)take((size_t)HL * HL * sizeof(__bf16));
    __bf16* wc2b = (__bf16*)take((size_t)HL * HL * sizeof(__bf16));
    float* bsum  = (float*)take((size_t)G4 * sizeof(float));
    float* hLst  = (float*)take(NH);
    __bf16* ybf  = (__bf16*)take((size_t)N_NODES * HL * sizeof(__bf16));
    __bf16* x2b  = (__bf16*)take((size_t)N_NODES * HL * sizeof(__bf16));
    // zero-region: degb | cntb | aux  (single memset)
    char*  zbase = take((size_t)N_NODES * 8 + 1024);
    float* degb  = (float*)zbase;
    int*   cntb  = (int*)(zbase + (size_t)N_NODES * 4);
    int*   auxb  = (int*)(zbase + (size_t)N_NODES * 8);
    float* dinvb = (float*)take((size_t)N_NODES * sizeof(float));
    int*   rankb = (int*)  take((size_t)NEDGE * sizeof(int));
    int*   rowst = (int*)  take((size_t)(N_NODES + 1) * sizeof(int));
    int*   srcS  = (int*)  take((size_t)NEDGE * sizeof(int));
    float* nrmS  = (float*)take((size_t)NEDGE * sizeof(float));

    hipMemsetAsync(zbase, 0, (size_t)N_NODES * 8 + 1024, stream);

    prep_all<<<PREPBLK, 256, 0, stream>>>(emb, embb, W_ih, W_hh, WTp,
                                          c1W, wc1b, c2W, wc2b, b_ih, b_hh, bsum);

    csr_fused<<<NBCSR, 512, 0, stream>>>(esrc, edst, ew, cntb, degb, dinvb,
                                         rankb, rowst, srcS, nrmS, auxb);

    lstm_fused<<<NBLSTM, 512, 0, stream>>>(x_tokens, lengths, embb, WTp, bsum, hLst);

    const int gathBlocks = (N_NODES*64 + 255)/256;   // 5000

    gemm_mfma<false><<<NCBLK, 512, 0, stream>>>(hLst, wc1b, ybf, N_NODES);
    gcn_gather_k<1><<<gathBlocks, 256, 0, stream>>>(rowst, srcS, nrmS, dinvb, ybf,
                                                    c1b, x2b, nullptr, nullptr, nullptr, N_NODES);
    gemm_mfma<true><<<NCBLK, 512, 0, stream>>>(x2b, wc2b, ybf, N_NODES);
    gcn_gather_k<2><<<gathBlocks, 256, 0, stream>>>(rowst, srcS, nrmS, dinvb, ybf,
                                                    c2b, nullptr, fcW, fcb, out, N_NODES);
}